// Round 1
// baseline (935.039 us; speedup 1.0000x reference)
//
#include <hip/hip_runtime.h>

// Problem constants (match reference)
#define NN 20000
#define MM 2000
#define EE 320000
// D = C = 128 feature channels everywhere
static constexpr float SLOPE = 0.2f;
static constexpr float EPSBN = 1e-5f;

// ---------------------------------------------------------------------------
// CSR build
// ---------------------------------------------------------------------------
__global__ void k_count(const int* __restrict__ ni, const int* __restrict__ ei,
                        int* ncnt, int* ecnt) {
  int e = blockIdx.x * 256 + threadIdx.x;
  if (e >= EE) return;
  atomicAdd(&ncnt[ni[e]], 1);
  atomicAdd(&ecnt[ei[e]], 1);
}

// single-block exclusive scan (n up to ~20001)
__global__ __launch_bounds__(1024) void k_scan(const int* __restrict__ cnt,
                                               int* __restrict__ off, int n) {
  __shared__ int sd[1024];
  __shared__ int carry;
  if (threadIdx.x == 0) carry = 0;
  __syncthreads();
  for (int base = 0; base < n; base += 1024) {
    int i = base + threadIdx.x;
    int v = (i < n) ? cnt[i] : 0;
    sd[threadIdx.x] = v;
    __syncthreads();
    for (int st = 1; st < 1024; st <<= 1) {
      int t = (threadIdx.x >= st) ? sd[threadIdx.x - st] : 0;
      __syncthreads();
      sd[threadIdx.x] += t;
      __syncthreads();
    }
    if (i < n) off[i] = carry + sd[threadIdx.x] - v;
    int tot = sd[1023];
    __syncthreads();
    if (threadIdx.x == 0) carry += tot;
    __syncthreads();
  }
  if (threadIdx.x == 0) off[n] = carry;
}

__global__ void k_fill(const int* __restrict__ ni, const int* __restrict__ ei,
                       const int* __restrict__ noff, const int* __restrict__ eoff,
                       int* ncur, int* ecur, int* nlist, int* elist) {
  int e = blockIdx.x * 256 + threadIdx.x;
  if (e >= EE) return;
  int n = ni[e];
  int p = atomicAdd(&ncur[n], 1);
  nlist[noff[n] + p] = e;
  int m = ei[e];
  int q = atomicAdd(&ecur[m], 1);
  elist[eoff[m] + q] = e;
}

// ---------------------------------------------------------------------------
// 128x128 GEMM: out = maybe_resid + leaky(A @ W + b). rows % 8 == 0.
// ---------------------------------------------------------------------------
__global__ __launch_bounds__(256) void k_gemm128(const float* __restrict__ A,
                                                 const float* __restrict__ W,
                                                 const float* __restrict__ bias,
                                                 const float* __restrict__ resid,
                                                 float* __restrict__ out, int rows) {
  __shared__ float Wl[128 * 128];
  for (int i = threadIdx.x; i < 128 * 128; i += 256) Wl[i] = W[i];
  __syncthreads();
  int col = threadIdx.x & 127, half = threadIdx.x >> 7;
  int r0 = blockIdx.x * 8 + half * 4;
  float acc[4] = {0.f, 0.f, 0.f, 0.f};
  for (int k = 0; k < 128; k++) {
    float w = Wl[k * 128 + col];
#pragma unroll
    for (int j = 0; j < 4; j++) acc[j] += A[(r0 + j) * 128 + k] * w;
  }
#pragma unroll
  for (int j = 0; j < 4; j++) {
    int r = r0 + j;
    float v = acc[j] + bias[col];
    v = (v > 0.f) ? v : SLOPE * v;
    if (resid) v += resid[r * 128 + col];
    out[r * 128 + col] = v;
  }
}

// ---------------------------------------------------------------------------
// BatchNorm (training-mode batch stats)
// ---------------------------------------------------------------------------
__global__ void k_colstats(const float* __restrict__ X, int rows,
                           float* __restrict__ st) {
  int c = threadIdx.x & 127, half = threadIdx.x >> 7;
  int r0 = blockIdx.x * 160;
  int rend = min(r0 + 160, rows);
  float s = 0.f, q = 0.f;
  for (int r = r0 + half; r < rend; r += 2) {
    float v = X[r * 128 + c];
    s += v;
    q += v * v;
  }
  __shared__ float ls[256], lq[256];
  ls[threadIdx.x] = s;
  lq[threadIdx.x] = q;
  __syncthreads();
  if (half == 0) {
    atomicAdd(&st[c], ls[c] + ls[128 + c]);
    atomicAdd(&st[128 + c], lq[c] + lq[128 + c]);
  }
}

__global__ void k_bnfinal(const float* __restrict__ st, const float* __restrict__ g,
                          const float* __restrict__ be, float rows_inv,
                          float* __restrict__ sc) {
  int c = threadIdx.x;  // 128 threads
  float mu = st[c] * rows_inv;
  float var = st[128 + c] * rows_inv - mu * mu;
  float scale = g[c] * rsqrtf(var + EPSBN);
  sc[c] = scale;
  sc[128 + c] = be[c] - mu * scale;
}

__global__ void k_bnapply(const float* __restrict__ X, const float* __restrict__ sc,
                          float* __restrict__ Y, int total) {
  int i = blockIdx.x * 256 + threadIdx.x;
  if (i >= total) return;
  int c = i & 127;
  Y[i] = X[i] * sc[c] + sc[128 + c];
}

// ---------------------------------------------------------------------------
// attr[m,:] = sum over incidences of edge m of h[node_idx[e],:]
// ---------------------------------------------------------------------------
__global__ void k_attr(const float* __restrict__ hb, const int* __restrict__ eoff,
                       const int* __restrict__ elist, const int* __restrict__ ni,
                       float* __restrict__ attr) {
  int m = blockIdx.x;
  int c = threadIdx.x & 127, half = threadIdx.x >> 7;
  int s = eoff[m], t = eoff[m + 1];
  float acc = 0.f;
  for (int i = s + half; i < t; i += 2) {
    int e = elist[i];
    int n = ni[e];
    acc += hb[n * 128 + c];
  }
  __shared__ float ls[256];
  ls[threadIdx.x] = acc;
  __syncthreads();
  if (half == 0) attr[m * 128 + c] = ls[c] + ls[128 + c];
}

// ---------------------------------------------------------------------------
// U[k,h] = sum_c lin_w[k, h*128+c] * att[h, c]
// V[k,h] = sum_c lin_w[k, h*128+c] * att[h, 128+c]
// ---------------------------------------------------------------------------
template <int H>
__global__ void k_uv(const float* __restrict__ linw, const float* __restrict__ att,
                     float* __restrict__ U, float* __restrict__ V) {
  int idx = blockIdx.x * 256 + threadIdx.x;
  if (idx >= 128 * H) return;
  int k = idx / H, h = idx - k * H;
  float u = 0.f, v = 0.f;
  for (int c = 0; c < 128; c++) {
    float w = linw[k * (128 * H) + h * 128 + c];
    u += w * att[h * 256 + c];
    v += w * att[h * 256 + 128 + c];
  }
  U[k * H + h] = u;
  V[k * H + h] = v;
}

// dot[r,h] = X[r,:] . U[:,h]
template <int H>
__global__ void k_dots(const float* __restrict__ X, int rows,
                       const float* __restrict__ U, float* __restrict__ dot) {
  __shared__ float Ul[128 * H];
  for (int i = threadIdx.x; i < 128 * H; i += 256) Ul[i] = U[i];
  __syncthreads();
  int idx = blockIdx.x * 256 + threadIdx.x;
  if (idx >= rows * H) return;
  int n = idx / H, h = idx - n * H;
  const float* xr = X + n * 128;
  float s = 0.f;
#pragma unroll 8
  for (int k = 0; k < 128; k++) s += xr[k] * Ul[k * H + h];
  dot[idx] = s;
}

// ---------------------------------------------------------------------------
// Per-node segment softmax over incident hyperedges (per head), plus Dinv.
// One wave per node; lane handles pairs p=(i,h) with h = p % H fixed per lane.
// ---------------------------------------------------------------------------
template <int H>
__global__ void k_softmax(const int* __restrict__ noff, const int* __restrict__ nlist,
                          const int* __restrict__ ei, const float* __restrict__ dotx,
                          const float* __restrict__ dota, const float* __restrict__ wedge,
                          float* __restrict__ alpha, float* __restrict__ Dinv) {
  int lane = threadIdx.x & 63;
  int n = blockIdx.x * 4 + (threadIdx.x >> 6);
  int s = noff[n], t = noff[n + 1];
  // Dd = sum of incident hyperedge weights
  float dd = 0.f;
  for (int i = s + lane; i < t; i += 64) dd += wedge[ei[nlist[i]]];
#pragma unroll
  for (int off = 32; off >= 1; off >>= 1) dd += __shfl_xor(dd, off);
  if (lane == 0) Dinv[n] = (dd > 0.f) ? 1.f / dd : 0.f;

  int P = (t - s) * H;
  float mx = -3.0e38f;
  for (int p = lane; p < P; p += 64) {
    int i = s + p / H, h = p - (p / H) * H;
    int e = nlist[i];
    float v = dotx[n * H + h] + dota[ei[e] * H + h];
    v = (v > 0.f) ? v : SLOPE * v;
    mx = fmaxf(mx, v);
  }
#pragma unroll
  for (int off = H; off < 64; off <<= 1) mx = fmaxf(mx, __shfl_xor(mx, off));
  float sm = 0.f;
  for (int p = lane; p < P; p += 64) {
    int i = s + p / H, h = p - (p / H) * H;
    int e = nlist[i];
    float v = dotx[n * H + h] + dota[ei[e] * H + h];
    v = (v > 0.f) ? v : SLOPE * v;
    sm += __expf(v - mx);
  }
#pragma unroll
  for (int off = H; off < 64; off <<= 1) sm += __shfl_xor(sm, off);
  for (int p = lane; p < P; p += 64) {
    int i = s + p / H, h = p - (p / H) * H;
    int e = nlist[i];
    float v = dotx[n * H + h] + dota[ei[e] * H + h];
    v = (v > 0.f) ? v : SLOPE * v;
    alpha[e * H + h] = __expf(v - mx) / (sm + 1e-16f);
  }
}

__global__ void k_binv(const int* __restrict__ eoff, const float* __restrict__ wedge,
                       float* __restrict__ Binv) {
  int m = blockIdx.x * 256 + threadIdx.x;
  if (m >= MM) return;
  int d = eoff[m + 1] - eoff[m];
  Binv[m] = (d > 0) ? wedge[m] / (float)d : 0.f;
}

// ---------------------------------------------------------------------------
// T[h][m][c] = sum over incidences of edge m of alpha[e,h] * h[node,c]
// ---------------------------------------------------------------------------
template <int H>
__global__ void k_T(const float* __restrict__ hb, const int* __restrict__ eoff,
                    const int* __restrict__ elist, const int* __restrict__ ni,
                    const float* __restrict__ alpha, float* __restrict__ T) {
  int m = blockIdx.x;
  int c = threadIdx.x & 127, half = threadIdx.x >> 7;
  float acc[H];
#pragma unroll
  for (int h = 0; h < H; h++) acc[h] = 0.f;
  int s = eoff[m], t = eoff[m + 1];
  for (int i = s + half; i < t; i += 2) {
    int e = elist[i];
    int n = ni[e];
    float v = hb[n * 128 + c];
#pragma unroll
    for (int h = 0; h < H; h++) acc[h] += alpha[e * H + h] * v;
  }
  __shared__ float ls[256];
#pragma unroll
  for (int h = 0; h < H; h++) {
    ls[threadIdx.x] = acc[h];
    __syncthreads();
    if (half == 0) T[(h * MM + m) * 128 + c] = ls[c] + ls[128 + c];
    __syncthreads();
  }
}

// out_e[m][h][c] = Binv[m] * (T[h][m][:] @ lin_w[:, h*128 + c])
template <int H>
__global__ __launch_bounds__(256) void k_oute(const float* __restrict__ T,
                                              const float* __restrict__ linw,
                                              const float* __restrict__ Binv,
                                              float* __restrict__ oute) {
  int h = blockIdx.y;
  __shared__ float Wl[128 * 128];
  for (int i = threadIdx.x; i < 128 * 128; i += 256) {
    int k = i >> 7, c = i & 127;
    Wl[i] = linw[k * (128 * H) + h * 128 + c];
  }
  __syncthreads();
  int col = threadIdx.x & 127, half = threadIdx.x >> 7;
  int r0 = blockIdx.x * 8 + half * 4;
  const float* A = T + h * MM * 128;
  float acc[4] = {0.f, 0.f, 0.f, 0.f};
  for (int k = 0; k < 128; k++) {
    float w = Wl[k * 128 + col];
#pragma unroll
    for (int j = 0; j < 4; j++) acc[j] += A[(r0 + j) * 128 + k] * w;
  }
#pragma unroll
  for (int j = 0; j < 4; j++) {
    int m = r0 + j;
    oute[(m * H + h) * 128 + col] = Binv[m] * acc[j];
  }
}

// ---------------------------------------------------------------------------
// out[n,c] = hres[n,c] + Dinv[n]/H * sum_{e in node n} sum_h alpha[e,h]*oute[m_e,h,c]
//            + bias[c]
// ---------------------------------------------------------------------------
template <int H>
__global__ void k_phase9(const int* __restrict__ noff, const int* __restrict__ nlist,
                         const int* __restrict__ ei, const float* __restrict__ alpha,
                         const float* __restrict__ oute, const float* __restrict__ Dinv,
                         const float* __restrict__ bias, const float* __restrict__ hres,
                         float* __restrict__ out) {
  int n = blockIdx.x;
  int c = threadIdx.x;  // 128 threads
  float acc = 0.f;
  int s = noff[n], t = noff[n + 1];
  for (int i = s; i < t; i++) {
    int e = nlist[i];
    int m = ei[e];
    float ssum = 0.f;
#pragma unroll
    for (int h = 0; h < H; h++) ssum += alpha[e * H + h] * oute[(m * H + h) * 128 + c];
    acc += ssum;
  }
  out[n * 128 + c] = hres[n * 128 + c] + Dinv[n] * acc * (1.f / H) + bias[c];
}

// ---------------------------------------------------------------------------
// Host side
// ---------------------------------------------------------------------------
static inline size_t alignup(size_t x) { return (x + 255) & ~(size_t)255; }

extern "C" void kernel_launch(void* const* d_in, const int* in_sizes, int n_in,
                              void* d_out, int out_size, void* d_ws, size_t ws_size,
                              hipStream_t stream) {
  const float* x = (const float*)d_in[0];
  const int* node_idx = (const int*)d_in[1];
  const int* edge_idx = (const int*)d_in[2];
  const float* wedge = (const float*)d_in[3];
  const float* W1 = (const float*)d_in[4];
  const float* b1 = (const float*)d_in[5];
  const float* g1 = (const float*)d_in[6];
  const float* be1 = (const float*)d_in[7];
  const float* linw1 = (const float*)d_in[8];
  const float* att1 = (const float*)d_in[9];
  const float* bias1 = (const float*)d_in[10];
  const float* g2 = (const float*)d_in[11];
  const float* be2 = (const float*)d_in[12];
  const float* linw2 = (const float*)d_in[13];
  const float* att2 = (const float*)d_in[14];
  const float* bias2 = (const float*)d_in[15];
  const float* g3 = (const float*)d_in[16];
  const float* be3 = (const float*)d_in[17];
  const float* W2 = (const float*)d_in[18];
  const float* b2 = (const float*)d_in[19];
  const float* g4 = (const float*)d_in[20];
  const float* be4 = (const float*)d_in[21];
  float* out = (float*)d_out;

  char* ws = (char*)d_ws;
  size_t off = 0;
  auto alloc = [&](size_t bytes) -> void* {
    void* p = ws + off;
    off = alignup(off + bytes);
    return p;
  };
  float* buf0 = (float*)alloc((size_t)NN * 128 * 4);
  float* buf1 = (float*)alloc((size_t)NN * 128 * 4);
  float* attr = (float*)alloc((size_t)MM * 128 * 4);
  float* Tbuf = (float*)alloc((size_t)4 * MM * 128 * 4);
  float* oute = (float*)alloc((size_t)MM * 4 * 128 * 4);
  float* alpha = (float*)alloc((size_t)EE * 4 * 4);
  float* dotx = (float*)alloc((size_t)NN * 4 * 4);
  float* dota = (float*)alloc((size_t)MM * 4 * 4);
  float* Ubuf = (float*)alloc(128 * 4 * 4);
  float* Vbuf = (float*)alloc(128 * 4 * 4);
  float* Dinv = (float*)alloc((size_t)NN * 4);
  float* Binv = (float*)alloc((size_t)MM * 4);
  int* noff = (int*)alloc((size_t)(NN + 1) * 4);
  int* eoff = (int*)alloc((size_t)(MM + 1) * 4);
  int* nlist = (int*)alloc((size_t)EE * 4);
  int* elist = (int*)alloc((size_t)EE * 4);
  int* zero_region = (int*)alloc((size_t)(2 * NN + 2 * MM) * 4);
  int* ncnt = zero_region;
  int* ecnt = ncnt + NN;
  int* ncur = ecnt + MM;
  int* ecur = ncur + NN;
  float* bnst = (float*)alloc(4 * 256 * 4);  // 4 BN layers x (sum,sumsq)
  float* bnsc = (float*)alloc(4 * 256 * 4);  // 4 BN layers x (scale,shift)
  (void)ws_size;
  (void)in_sizes;
  (void)n_in;
  (void)out_size;

  // zero atomic accumulators
  (void)hipMemsetAsync(zero_region, 0, (size_t)(2 * NN + 2 * MM) * 4, stream);
  (void)hipMemsetAsync(bnst, 0, 4 * 256 * 4, stream);

  // CSR build
  k_count<<<(EE + 255) / 256, 256, 0, stream>>>(node_idx, edge_idx, ncnt, ecnt);
  k_scan<<<1, 1024, 0, stream>>>(ncnt, noff, NN);
  k_scan<<<1, 1024, 0, stream>>>(ecnt, eoff, MM);
  k_fill<<<(EE + 255) / 256, 256, 0, stream>>>(node_idx, edge_idx, noff, eoff, ncur,
                                               ecur, nlist, elist);
  k_binv<<<(MM + 255) / 256, 256, 0, stream>>>(eoff, wedge, Binv);

  const float ninv = 1.f / (float)NN;

  // h = leaky(x@W1+b1); BN1
  k_gemm128<<<NN / 8, 256, 0, stream>>>(x, W1, b1, nullptr, buf0, NN);
  k_colstats<<<(NN + 159) / 160, 256, 0, stream>>>(buf0, NN, bnst + 0 * 256);
  k_bnfinal<<<1, 128, 0, stream>>>(bnst + 0 * 256, g1, be1, ninv, bnsc + 0 * 256);
  k_bnapply<<<(NN * 128 + 255) / 256, 256, 0, stream>>>(buf0, bnsc + 0 * 256, buf1,
                                                        NN * 128);

  // ---- hconv1 (H=4) on buf1 ----
  k_attr<<<MM, 256, 0, stream>>>(buf1, eoff, elist, node_idx, attr);
  k_uv<4><<<(128 * 4 + 255) / 256, 256, 0, stream>>>(linw1, att1, Ubuf, Vbuf);
  k_dots<4><<<(NN * 4 + 255) / 256, 256, 0, stream>>>(buf1, NN, Ubuf, dotx);
  k_dots<4><<<(MM * 4 + 255) / 256, 256, 0, stream>>>(attr, MM, Vbuf, dota);
  k_softmax<4><<<NN / 4, 256, 0, stream>>>(noff, nlist, edge_idx, dotx, dota, wedge,
                                           alpha, Dinv);
  k_T<4><<<MM, 256, 0, stream>>>(buf1, eoff, elist, node_idx, alpha, Tbuf);
  {
    dim3 g(MM / 8, 4);
    k_oute<4><<<g, 256, 0, stream>>>(Tbuf, linw1, Binv, oute);
  }
  k_phase9<4><<<NN, 128, 0, stream>>>(noff, nlist, edge_idx, alpha, oute, Dinv, bias1,
                                      buf1, buf0);
  // BN2
  k_colstats<<<(NN + 159) / 160, 256, 0, stream>>>(buf0, NN, bnst + 1 * 256);
  k_bnfinal<<<1, 128, 0, stream>>>(bnst + 1 * 256, g2, be2, ninv, bnsc + 1 * 256);
  k_bnapply<<<(NN * 128 + 255) / 256, 256, 0, stream>>>(buf0, bnsc + 1 * 256, buf1,
                                                        NN * 128);

  // ---- hconv2 (H=1) on buf1 ----
  k_attr<<<MM, 256, 0, stream>>>(buf1, eoff, elist, node_idx, attr);
  k_uv<1><<<1, 256, 0, stream>>>(linw2, att2, Ubuf, Vbuf);
  k_dots<1><<<(NN + 255) / 256, 256, 0, stream>>>(buf1, NN, Ubuf, dotx);
  k_dots<1><<<(MM + 255) / 256, 256, 0, stream>>>(attr, MM, Vbuf, dota);
  k_softmax<1><<<NN / 4, 256, 0, stream>>>(noff, nlist, edge_idx, dotx, dota, wedge,
                                           alpha, Dinv);
  k_T<1><<<MM, 256, 0, stream>>>(buf1, eoff, elist, node_idx, alpha, Tbuf);
  {
    dim3 g(MM / 8, 1);
    k_oute<1><<<g, 256, 0, stream>>>(Tbuf, linw2, Binv, oute);
  }
  k_phase9<1><<<NN, 128, 0, stream>>>(noff, nlist, edge_idx, alpha, oute, Dinv, bias2,
                                      buf1, buf0);
  // BN3
  k_colstats<<<(NN + 159) / 160, 256, 0, stream>>>(buf0, NN, bnst + 2 * 256);
  k_bnfinal<<<1, 128, 0, stream>>>(bnst + 2 * 256, g3, be3, ninv, bnsc + 2 * 256);
  k_bnapply<<<(NN * 128 + 255) / 256, 256, 0, stream>>>(buf0, bnsc + 2 * 256, buf1,
                                                        NN * 128);

  // final: o = leaky(h@W2+b2); pre = src + o; BN4 -> out
  k_gemm128<<<NN / 8, 256, 0, stream>>>(buf1, W2, b2, x, buf0, NN);
  k_colstats<<<(NN + 159) / 160, 256, 0, stream>>>(buf0, NN, bnst + 3 * 256);
  k_bnfinal<<<1, 128, 0, stream>>>(bnst + 3 * 256, g4, be4, ninv, bnsc + 3 * 256);
  k_bnapply<<<(NN * 128 + 255) / 256, 256, 0, stream>>>(buf0, bnsc + 3 * 256, out,
                                                        NN * 128);
}

// Round 2
// 618.557 us; speedup vs baseline: 1.5116x; 1.5116x over previous
//
#include <hip/hip_runtime.h>

// Problem constants (match reference)
#define NN 20000
#define MM 2000
#define EE 320000
static constexpr float SLOPE = 0.2f;
static constexpr float EPSBN = 1e-5f;

__device__ inline float4 f4add(float4 a, float4 b) {
  return make_float4(a.x + b.x, a.y + b.y, a.z + b.z, a.w + b.w);
}
__device__ inline float4 f4fma(float a, float4 v, float4 c) {
  return make_float4(c.x + a * v.x, c.y + a * v.y, c.z + a * v.z, c.w + a * v.w);
}

// ---------------------------------------------------------------------------
// CSR build
// ---------------------------------------------------------------------------
__global__ void k_count(const int* __restrict__ ni, const int* __restrict__ ei,
                        int* ncnt, int* ecnt) {
  int e = blockIdx.x * 256 + threadIdx.x;
  if (e >= EE) return;
  atomicAdd(&ncnt[ni[e]], 1);
  atomicAdd(&ecnt[ei[e]], 1);
}

// single-block exclusive scan
__global__ __launch_bounds__(1024) void k_scan(const int* __restrict__ cnt,
                                               int* __restrict__ off, int n) {
  __shared__ int sd[1024];
  __shared__ int carry;
  if (threadIdx.x == 0) carry = 0;
  __syncthreads();
  for (int base = 0; base < n; base += 1024) {
    int i = base + threadIdx.x;
    int v = (i < n) ? cnt[i] : 0;
    sd[threadIdx.x] = v;
    __syncthreads();
    for (int st = 1; st < 1024; st <<= 1) {
      int t = (threadIdx.x >= st) ? sd[threadIdx.x - st] : 0;
      __syncthreads();
      sd[threadIdx.x] += t;
      __syncthreads();
    }
    if (i < n) off[i] = carry + sd[threadIdx.x] - v;
    int tot = sd[1023];
    __syncthreads();
    if (threadIdx.x == 0) carry += tot;
    __syncthreads();
  }
  if (threadIdx.x == 0) off[n] = carry;
}

// fill coalesced incidence arrays:
//  em_n[node-CSR pos]  = hyperedge id
//  nn_e[edge-CSR pos]  = node id
//  posn_e[edge-CSR pos] = node-CSR pos of this incidence (for alpha lookup)
__global__ void k_fill(const int* __restrict__ ni, const int* __restrict__ ei,
                       const int* __restrict__ noff, const int* __restrict__ eoff,
                       int* ncur, int* ecur, int* __restrict__ em_n,
                       int* __restrict__ nn_e, int* __restrict__ posn_e) {
  int e = blockIdx.x * 256 + threadIdx.x;
  if (e >= EE) return;
  int n = ni[e];
  int m = ei[e];
  int p = atomicAdd(&ncur[n], 1);
  int pn = noff[n] + p;
  int q = atomicAdd(&ecur[m], 1);
  int pe = eoff[m] + q;
  em_n[pn] = m;
  nn_e[pe] = n;
  posn_e[pe] = pn;
}

// ---------------------------------------------------------------------------
// 128x128 GEMM: out = maybe_resid + leaky(A @ W + b). rows % 8 == 0.
// ---------------------------------------------------------------------------
__global__ __launch_bounds__(256) void k_gemm128(const float* __restrict__ A,
                                                 const float* __restrict__ W,
                                                 const float* __restrict__ bias,
                                                 const float* __restrict__ resid,
                                                 float* __restrict__ out, int rows) {
  __shared__ float Wl[128 * 128];
  for (int i = threadIdx.x; i < 128 * 128; i += 256) Wl[i] = W[i];
  __syncthreads();
  int col = threadIdx.x & 127, half = threadIdx.x >> 7;
  int r0 = blockIdx.x * 8 + half * 4;
  float acc[4] = {0.f, 0.f, 0.f, 0.f};
  for (int k = 0; k < 128; k++) {
    float w = Wl[k * 128 + col];
#pragma unroll
    for (int j = 0; j < 4; j++) acc[j] += A[(r0 + j) * 128 + k] * w;
  }
#pragma unroll
  for (int j = 0; j < 4; j++) {
    int r = r0 + j;
    float v = acc[j] + bias[col];
    v = (v > 0.f) ? v : SLOPE * v;
    if (resid) v += resid[r * 128 + col];
    out[r * 128 + col] = v;
  }
}

// ---------------------------------------------------------------------------
// BatchNorm (training-mode batch stats)
// ---------------------------------------------------------------------------
__global__ void k_colstats(const float* __restrict__ X, int rows,
                           float* __restrict__ st) {
  int c = threadIdx.x & 127, half = threadIdx.x >> 7;
  int r0 = blockIdx.x * 160;
  int rend = min(r0 + 160, rows);
  float s = 0.f, q = 0.f;
  for (int r = r0 + half; r < rend; r += 2) {
    float v = X[r * 128 + c];
    s += v;
    q += v * v;
  }
  __shared__ float ls[256], lq[256];
  ls[threadIdx.x] = s;
  lq[threadIdx.x] = q;
  __syncthreads();
  if (half == 0) {
    atomicAdd(&st[c], ls[c] + ls[128 + c]);
    atomicAdd(&st[128 + c], lq[c] + lq[128 + c]);
  }
}

__global__ void k_bnfinal(const float* __restrict__ st, const float* __restrict__ g,
                          const float* __restrict__ be, float rows_inv,
                          float* __restrict__ sc) {
  int c = threadIdx.x;  // 128 threads
  float mu = st[c] * rows_inv;
  float var = st[128 + c] * rows_inv - mu * mu;
  float scale = g[c] * rsqrtf(var + EPSBN);
  sc[c] = scale;
  sc[128 + c] = be[c] - mu * scale;
}

__global__ void k_bnapply(const float* __restrict__ X, const float* __restrict__ sc,
                          float* __restrict__ Y, int total) {
  int i = blockIdx.x * 256 + threadIdx.x;
  if (i >= total) return;
  int c = i & 127;
  Y[i] = X[i] * sc[c] + sc[128 + c];
}

// ---------------------------------------------------------------------------
// UV[k][0..H-1] = U (x-side att), UV[k][H..2H-1] = V (attr-side att)
// ---------------------------------------------------------------------------
template <int H>
__global__ void k_uv(const float* __restrict__ linw, const float* __restrict__ att,
                     float* __restrict__ UV) {
  int idx = blockIdx.x * 256 + threadIdx.x;
  if (idx >= 128 * H) return;
  int k = idx / H, h = idx - k * H;
  float u = 0.f, v = 0.f;
  for (int c = 0; c < 128; c++) {
    float w = linw[k * (128 * H) + h * 128 + c];
    u += w * att[h * 256 + c];
    v += w * att[h * 256 + 128 + c];
  }
  UV[k * 2 * H + h] = u;
  UV[k * 2 * H + H + h] = v;
}

// dotx[n,h] = X[n,:] . U[:,h] ; hv[n,h] = X[n,:] . V[:,h]
template <int H>
__global__ void k_dots(const float* __restrict__ X, int rows,
                       const float* __restrict__ UV, float* __restrict__ dotx,
                       float* __restrict__ hv) {
  __shared__ float Ul[128 * 2 * H];
  for (int i = threadIdx.x; i < 128 * 2 * H; i += 256) Ul[i] = UV[i];
  __syncthreads();
  int idx = blockIdx.x * 256 + threadIdx.x;
  if (idx >= rows * 2 * H) return;
  int n = idx / (2 * H), h2 = idx - n * (2 * H);
  const float* xr = X + n * 128;
  float s = 0.f;
#pragma unroll 8
  for (int k = 0; k < 128; k++) s += xr[k] * Ul[k * 2 * H + h2];
  if (h2 < H)
    dotx[n * H + h2] = s;
  else
    hv[n * H + (h2 - H)] = s;
}

// dota[m,h] = sum over incidences of edge m of hv[node, h]
template <int H>
__global__ void k_dota(const float* __restrict__ hv, const int* __restrict__ eoff,
                       const int* __restrict__ nn_e, float* __restrict__ dota) {
  int lane = threadIdx.x & 63;
  int m = blockIdx.x * 4 + (threadIdx.x >> 6);
  int s = eoff[m], t = eoff[m + 1];
  int P = (t - s) * H;
  float acc = 0.f;
  for (int p = lane; p < P; p += 64) {
    int j = s + p / H, h = lane & (H - 1);
    acc += hv[nn_e[j] * H + h];
  }
#pragma unroll
  for (int o = H; o < 64; o <<= 1) acc += __shfl_xor(acc, o);
  if (lane < H) dota[m * H + lane] = acc;
}

// ---------------------------------------------------------------------------
// Per-node segment softmax; alpha stored in node-CSR order (coalesced).
// ---------------------------------------------------------------------------
template <int H>
__global__ void k_softmax(const int* __restrict__ noff, const int* __restrict__ em_n,
                          const float* __restrict__ dotx, const float* __restrict__ dota,
                          const float* __restrict__ wedge, float* __restrict__ alpha,
                          float* __restrict__ Dinv) {
  int lane = threadIdx.x & 63;
  int n = blockIdx.x * 4 + (threadIdx.x >> 6);
  int s = noff[n], t = noff[n + 1];
  float dd = 0.f;
  for (int i = s + lane; i < t; i += 64) dd += wedge[em_n[i]];
#pragma unroll
  for (int o = 32; o >= 1; o >>= 1) dd += __shfl_xor(dd, o);
  if (lane == 0) Dinv[n] = (dd > 0.f) ? 1.f / dd : 0.f;

  int P = (t - s) * H;
  int h = lane & (H - 1);
  float dx = dotx[n * H + h];
  float mx = -3.0e38f;
  for (int p = lane; p < P; p += 64) {
    int i = s + p / H;
    float v = dx + dota[em_n[i] * H + h];
    v = (v > 0.f) ? v : SLOPE * v;
    mx = fmaxf(mx, v);
  }
#pragma unroll
  for (int o = H; o < 64; o <<= 1) mx = fmaxf(mx, __shfl_xor(mx, o));
  float sm = 0.f;
  for (int p = lane; p < P; p += 64) {
    int i = s + p / H;
    float v = dx + dota[em_n[i] * H + h];
    v = (v > 0.f) ? v : SLOPE * v;
    sm += __expf(v - mx);
  }
#pragma unroll
  for (int o = H; o < 64; o <<= 1) sm += __shfl_xor(sm, o);
  float inv = 1.f / (sm + 1e-16f);
  for (int p = lane; p < P; p += 64) {
    int i = s + p / H;
    float v = dx + dota[em_n[i] * H + h];
    v = (v > 0.f) ? v : SLOPE * v;
    alpha[i * H + h] = __expf(v - mx) * inv;  // coalesced write
  }
}

__global__ void k_binv(const int* __restrict__ eoff, const float* __restrict__ wedge,
                       float* __restrict__ Binv) {
  int m = blockIdx.x * 256 + threadIdx.x;
  if (m >= MM) return;
  int d = eoff[m + 1] - eoff[m];
  Binv[m] = (d > 0) ? wedge[m] / (float)d : 0.f;
}

// ---------------------------------------------------------------------------
// T[h][m][c] = sum over incidences of edge m of alpha * h[node,c]
// 256 threads = 8 row-slots x 32 lanes (float4 per lane).
// ---------------------------------------------------------------------------
template <int H>
__global__ __launch_bounds__(256) void k_T(const float4* __restrict__ h4,
                                           const int* __restrict__ eoff,
                                           const int* __restrict__ nn_e,
                                           const int* __restrict__ posn_e,
                                           const float* __restrict__ alpha,
                                           float4* __restrict__ T4) {
  int m = blockIdx.x;
  int slot = threadIdx.x >> 5, lane = threadIdx.x & 31;
  int s = eoff[m], t = eoff[m + 1];
  float4 acc[H];
#pragma unroll
  for (int h = 0; h < H; h++) acc[h] = make_float4(0.f, 0.f, 0.f, 0.f);
  for (int j = s + slot; j < t; j += 8) {
    int n = nn_e[j];
    int pos = posn_e[j];
    float4 v = h4[n * 32 + lane];
    if (H == 4) {
      float4 a4 = ((const float4*)alpha)[pos];
      acc[0] = f4fma(a4.x, v, acc[0]);
      acc[1 % H] = f4fma(a4.y, v, acc[1 % H]);
      acc[2 % H] = f4fma(a4.z, v, acc[2 % H]);
      acc[3 % H] = f4fma(a4.w, v, acc[3 % H]);
    } else {
      float a = alpha[pos];
      acc[0] = f4fma(a, v, acc[0]);
    }
  }
  __shared__ float4 red[8][32];
#pragma unroll
  for (int h = 0; h < H; h++) {
    red[slot][lane] = acc[h];
    __syncthreads();
    if (slot < 4) red[slot][lane] = f4add(red[slot][lane], red[slot + 4][lane]);
    __syncthreads();
    if (slot < 2) red[slot][lane] = f4add(red[slot][lane], red[slot + 2][lane]);
    __syncthreads();
    if (slot == 0)
      T4[(h * MM + m) * 32 + lane] = f4add(red[0][lane], red[1][lane]);
    __syncthreads();
  }
}

// out_e[m][h][c] = Binv[m] * (T[h][m][:] @ lin_w[:, h*128 + c])
template <int H>
__global__ __launch_bounds__(256) void k_oute(const float* __restrict__ T,
                                              const float* __restrict__ linw,
                                              const float* __restrict__ Binv,
                                              float* __restrict__ oute) {
  int h = blockIdx.y;
  __shared__ float Wl[128 * 128];
  for (int i = threadIdx.x; i < 128 * 128; i += 256) {
    int k = i >> 7, c = i & 127;
    Wl[i] = linw[k * (128 * H) + h * 128 + c];
  }
  __syncthreads();
  int col = threadIdx.x & 127, half = threadIdx.x >> 7;
  int r0 = blockIdx.x * 8 + half * 4;
  const float* A = T + h * MM * 128;
  float acc[4] = {0.f, 0.f, 0.f, 0.f};
  for (int k = 0; k < 128; k++) {
    float w = Wl[k * 128 + col];
#pragma unroll
    for (int j = 0; j < 4; j++) acc[j] += A[(r0 + j) * 128 + k] * w;
  }
#pragma unroll
  for (int j = 0; j < 4; j++) {
    int m = r0 + j;
    oute[(m * H + h) * 128 + col] = Binv[m] * acc[j];
  }
}

// ---------------------------------------------------------------------------
// out[n,c] = hres[n,c] + Dinv[n]/H * sum_{i in node} sum_h alpha*oute[m,h,c] + bias
// One node per block; 8 (i,h)-slots x 32 lanes (float4).
// ---------------------------------------------------------------------------
template <int H>
__global__ __launch_bounds__(256) void k_phase9(
    const int* __restrict__ noff, const int* __restrict__ em_n,
    const float* __restrict__ alpha, const float4* __restrict__ oute4,
    const float* __restrict__ Dinv, const float* __restrict__ bias,
    const float4* __restrict__ hres4, float4* __restrict__ out4) {
  int n = blockIdx.x;
  int slot = threadIdx.x >> 5, lane = threadIdx.x & 31;
  int s = noff[n], t = noff[n + 1];
  int P = (t - s) * H;
  float4 acc = make_float4(0.f, 0.f, 0.f, 0.f);
  for (int p = slot; p < P; p += 8) {
    int i = s + p / H;
    int h = p - (p / H) * H;
    int m = em_n[i];
    float a = alpha[i * H + h];
    float4 v = oute4[(m * H + h) * 32 + lane];
    acc = f4fma(a, v, acc);
  }
  __shared__ float4 red[8][32];
  red[slot][lane] = acc;
  __syncthreads();
  if (slot < 4) red[slot][lane] = f4add(red[slot][lane], red[slot + 4][lane]);
  __syncthreads();
  if (slot < 2) red[slot][lane] = f4add(red[slot][lane], red[slot + 2][lane]);
  __syncthreads();
  if (slot == 0) {
    float4 a2 = f4add(red[0][lane], red[1][lane]);
    float sc = Dinv[n] * (1.f / H);
    float4 hr = hres4[n * 32 + lane];
    float4 bi = ((const float4*)bias)[lane];
    out4[n * 32 + lane] = make_float4(hr.x + sc * a2.x + bi.x, hr.y + sc * a2.y + bi.y,
                                      hr.z + sc * a2.z + bi.z, hr.w + sc * a2.w + bi.w);
  }
}

// ---------------------------------------------------------------------------
// Host side
// ---------------------------------------------------------------------------
static inline size_t alignup(size_t x) { return (x + 255) & ~(size_t)255; }

extern "C" void kernel_launch(void* const* d_in, const int* in_sizes, int n_in,
                              void* d_out, int out_size, void* d_ws, size_t ws_size,
                              hipStream_t stream) {
  const float* x = (const float*)d_in[0];
  const int* node_idx = (const int*)d_in[1];
  const int* edge_idx = (const int*)d_in[2];
  const float* wedge = (const float*)d_in[3];
  const float* W1 = (const float*)d_in[4];
  const float* b1 = (const float*)d_in[5];
  const float* g1 = (const float*)d_in[6];
  const float* be1 = (const float*)d_in[7];
  const float* linw1 = (const float*)d_in[8];
  const float* att1 = (const float*)d_in[9];
  const float* bias1 = (const float*)d_in[10];
  const float* g2 = (const float*)d_in[11];
  const float* be2 = (const float*)d_in[12];
  const float* linw2 = (const float*)d_in[13];
  const float* att2 = (const float*)d_in[14];
  const float* bias2 = (const float*)d_in[15];
  const float* g3 = (const float*)d_in[16];
  const float* be3 = (const float*)d_in[17];
  const float* W2 = (const float*)d_in[18];
  const float* b2 = (const float*)d_in[19];
  const float* g4 = (const float*)d_in[20];
  const float* be4 = (const float*)d_in[21];
  float* out = (float*)d_out;

  char* ws = (char*)d_ws;
  size_t off = 0;
  auto alloc = [&](size_t bytes) -> void* {
    void* p = ws + off;
    off = alignup(off + bytes);
    return p;
  };
  float* buf0 = (float*)alloc((size_t)NN * 128 * 4);
  float* buf1 = (float*)alloc((size_t)NN * 128 * 4);
  float* Tbuf = (float*)alloc((size_t)4 * MM * 128 * 4);
  float* oute = (float*)alloc((size_t)MM * 4 * 128 * 4);
  float* alpha = (float*)alloc((size_t)EE * 4 * 4);
  float* dotx = (float*)alloc((size_t)NN * 4 * 4);
  float* hv = (float*)alloc((size_t)NN * 4 * 4);
  float* dota = (float*)alloc((size_t)MM * 4 * 4);
  float* UVbuf = (float*)alloc(128 * 8 * 4);
  float* Dinv = (float*)alloc((size_t)NN * 4);
  float* Binv = (float*)alloc((size_t)MM * 4);
  int* noff = (int*)alloc((size_t)(NN + 1) * 4);
  int* eoff = (int*)alloc((size_t)(MM + 1) * 4);
  int* em_n = (int*)alloc((size_t)EE * 4);
  int* nn_e = (int*)alloc((size_t)EE * 4);
  int* posn_e = (int*)alloc((size_t)EE * 4);
  int* zero_region = (int*)alloc((size_t)(2 * NN + 2 * MM) * 4);
  int* ncnt = zero_region;
  int* ecnt = ncnt + NN;
  int* ncur = ecnt + MM;
  int* ecur = ncur + NN;
  float* bnst = (float*)alloc(4 * 256 * 4);
  float* bnsc = (float*)alloc(4 * 256 * 4);
  (void)ws_size;
  (void)in_sizes;
  (void)n_in;
  (void)out_size;

  (void)hipMemsetAsync(zero_region, 0, (size_t)(2 * NN + 2 * MM) * 4, stream);
  (void)hipMemsetAsync(bnst, 0, 4 * 256 * 4, stream);

  // CSR build
  k_count<<<(EE + 255) / 256, 256, 0, stream>>>(node_idx, edge_idx, ncnt, ecnt);
  k_scan<<<1, 1024, 0, stream>>>(ncnt, noff, NN);
  k_scan<<<1, 1024, 0, stream>>>(ecnt, eoff, MM);
  k_fill<<<(EE + 255) / 256, 256, 0, stream>>>(node_idx, edge_idx, noff, eoff, ncur,
                                               ecur, em_n, nn_e, posn_e);
  k_binv<<<(MM + 255) / 256, 256, 0, stream>>>(eoff, wedge, Binv);

  const float ninv = 1.f / (float)NN;

  // h = leaky(x@W1+b1); BN1
  k_gemm128<<<NN / 8, 256, 0, stream>>>(x, W1, b1, nullptr, buf0, NN);
  k_colstats<<<(NN + 159) / 160, 256, 0, stream>>>(buf0, NN, bnst + 0 * 256);
  k_bnfinal<<<1, 128, 0, stream>>>(bnst + 0 * 256, g1, be1, ninv, bnsc + 0 * 256);
  k_bnapply<<<(NN * 128 + 255) / 256, 256, 0, stream>>>(buf0, bnsc + 0 * 256, buf1,
                                                        NN * 128);

  // ---- hconv1 (H=4) on buf1 ----
  k_uv<4><<<(128 * 4 + 255) / 256, 256, 0, stream>>>(linw1, att1, UVbuf);
  k_dots<4><<<(NN * 8 + 255) / 256, 256, 0, stream>>>(buf1, NN, UVbuf, dotx, hv);
  k_dota<4><<<MM / 4, 256, 0, stream>>>(hv, eoff, nn_e, dota);
  k_softmax<4><<<NN / 4, 256, 0, stream>>>(noff, em_n, dotx, dota, wedge, alpha, Dinv);
  k_T<4><<<MM, 256, 0, stream>>>((const float4*)buf1, eoff, nn_e, posn_e, alpha,
                                 (float4*)Tbuf);
  {
    dim3 g(MM / 8, 4);
    k_oute<4><<<g, 256, 0, stream>>>(Tbuf, linw1, Binv, oute);
  }
  k_phase9<4><<<NN, 256, 0, stream>>>(noff, em_n, alpha, (const float4*)oute, Dinv,
                                      bias1, (const float4*)buf1, (float4*)buf0);
  // BN2
  k_colstats<<<(NN + 159) / 160, 256, 0, stream>>>(buf0, NN, bnst + 1 * 256);
  k_bnfinal<<<1, 128, 0, stream>>>(bnst + 1 * 256, g2, be2, ninv, bnsc + 1 * 256);
  k_bnapply<<<(NN * 128 + 255) / 256, 256, 0, stream>>>(buf0, bnsc + 1 * 256, buf1,
                                                        NN * 128);

  // ---- hconv2 (H=1) on buf1 ----
  k_uv<1><<<1, 256, 0, stream>>>(linw2, att2, UVbuf);
  k_dots<1><<<(NN * 2 + 255) / 256, 256, 0, stream>>>(buf1, NN, UVbuf, dotx, hv);
  k_dota<1><<<MM / 4, 256, 0, stream>>>(hv, eoff, nn_e, dota);
  k_softmax<1><<<NN / 4, 256, 0, stream>>>(noff, em_n, dotx, dota, wedge, alpha, Dinv);
  k_T<1><<<MM, 256, 0, stream>>>((const float4*)buf1, eoff, nn_e, posn_e, alpha,
                                 (float4*)Tbuf);
  {
    dim3 g(MM / 8, 1);
    k_oute<1><<<g, 256, 0, stream>>>(Tbuf, linw2, Binv, oute);
  }
  k_phase9<1><<<NN, 256, 0, stream>>>(noff, em_n, alpha, (const float4*)oute, Dinv,
                                      bias2, (const float4*)buf1, (float4*)buf0);
  // BN3
  k_colstats<<<(NN + 159) / 160, 256, 0, stream>>>(buf0, NN, bnst + 2 * 256);
  k_bnfinal<<<1, 128, 0, stream>>>(bnst + 2 * 256, g3, be3, ninv, bnsc + 2 * 256);
  k_bnapply<<<(NN * 128 + 255) / 256, 256, 0, stream>>>(buf0, bnsc + 2 * 256, buf1,
                                                        NN * 128);

  // final: o = leaky(h@W2+b2); pre = src + o; BN4 -> out
  k_gemm128<<<NN / 8, 256, 0, stream>>>(buf1, W2, b2, x, buf0, NN);
  k_colstats<<<(NN + 159) / 160, 256, 0, stream>>>(buf0, NN, bnst + 3 * 256);
  k_bnfinal<<<1, 128, 0, stream>>>(bnst + 3 * 256, g4, be4, ninv, bnsc + 3 * 256);
  k_bnapply<<<(NN * 128 + 255) / 256, 256, 0, stream>>>(buf0, bnsc + 3 * 256, out,
                                                        NN * 128);
}

// Round 3
// 476.155 us; speedup vs baseline: 1.9637x; 1.2991x over previous
//
#include <hip/hip_runtime.h>

// Problem constants (match reference)
#define NN 20000
#define MM 2000
#define EE 320000
static constexpr float SLOPE = 0.2f;
static constexpr float EPSBN = 1e-5f;

__device__ inline float4 f4add(float4 a, float4 b) {
  return make_float4(a.x + b.x, a.y + b.y, a.z + b.z, a.w + b.w);
}
__device__ inline float4 f4fma(float a, float4 v, float4 c) {
  return make_float4(c.x + a * v.x, c.y + a * v.y, c.z + a * v.z, c.w + a * v.w);
}
__device__ inline float4 f4shfl_xor32(float4 v) {
  return make_float4(__shfl_xor(v.x, 32), __shfl_xor(v.y, 32), __shfl_xor(v.z, 32),
                     __shfl_xor(v.w, 32));
}
__device__ inline float leaky(float v) { return (v > 0.f) ? v : SLOPE * v; }

// ---------------------------------------------------------------------------
// CSR build
// ---------------------------------------------------------------------------
__global__ void k_count(const int* __restrict__ ni, const int* __restrict__ ei,
                        int* ncnt, int* ecnt) {
  int e = blockIdx.x * 256 + threadIdx.x;
  if (e >= EE) return;
  atomicAdd(&ncnt[ni[e]], 1);
  atomicAdd(&ecnt[ei[e]], 1);
}

__global__ __launch_bounds__(1024) void k_scan(const int* __restrict__ cnt,
                                               int* __restrict__ off, int n) {
  __shared__ int sd[1024];
  __shared__ int carry;
  if (threadIdx.x == 0) carry = 0;
  __syncthreads();
  for (int base = 0; base < n; base += 1024) {
    int i = base + threadIdx.x;
    int v = (i < n) ? cnt[i] : 0;
    sd[threadIdx.x] = v;
    __syncthreads();
    for (int st = 1; st < 1024; st <<= 1) {
      int t = (threadIdx.x >= st) ? sd[threadIdx.x - st] : 0;
      __syncthreads();
      sd[threadIdx.x] += t;
      __syncthreads();
    }
    if (i < n) off[i] = carry + sd[threadIdx.x] - v;
    int tot = sd[1023];
    __syncthreads();
    if (threadIdx.x == 0) carry += tot;
    __syncthreads();
  }
  if (threadIdx.x == 0) off[n] = carry;
}

__global__ void k_fill(const int* __restrict__ ni, const int* __restrict__ ei,
                       const int* __restrict__ noff, const int* __restrict__ eoff,
                       int* ncur, int* ecur, int* __restrict__ em_n,
                       int* __restrict__ nn_e, int* __restrict__ posn_e) {
  int e = blockIdx.x * 256 + threadIdx.x;
  if (e >= EE) return;
  int n = ni[e];
  int m = ei[e];
  int p = atomicAdd(&ncur[n], 1);
  int pn = noff[n] + p;
  int q = atomicAdd(&ecur[m], 1);
  int pe = eoff[m] + q;
  em_n[pn] = m;
  nn_e[pe] = n;
  posn_e[pe] = pn;
}

__global__ void k_binv(const int* __restrict__ eoff, const float* __restrict__ wedge,
                       float* __restrict__ Binv) {
  int m = blockIdx.x * 256 + threadIdx.x;
  if (m >= MM) return;
  int d = eoff[m + 1] - eoff[m];
  Binv[m] = (d > 0) ? wedge[m] / (float)d : 0.f;
}

// ---------------------------------------------------------------------------
// Tiled GEMM: out = maybe_resid + leaky(A[rows,128] @ W[128,128] + b)
// 64-row x 128-col tile per block, K-panels of 32, 4x8 per-thread outputs.
// ---------------------------------------------------------------------------
__global__ __launch_bounds__(256) void k_gemm128(const float* __restrict__ A,
                                                 const float* __restrict__ W,
                                                 const float* __restrict__ bias,
                                                 const float* __restrict__ resid,
                                                 float* __restrict__ out, int rows) {
  __shared__ float As[32][68];   // [k][row], padded
  __shared__ float Ws[32][132];  // [k][col], padded
  int tx = threadIdx.x & 15, ty = threadIdx.x >> 4;
  int r0 = blockIdx.x * 64;
  float4 acc[4][2];
#pragma unroll
  for (int j = 0; j < 4; j++) acc[j][0] = acc[j][1] = make_float4(0.f, 0.f, 0.f, 0.f);

  for (int k0 = 0; k0 < 128; k0 += 32) {
    __syncthreads();
    {
      int row = threadIdx.x >> 2, kq = threadIdx.x & 3;
      int rr = r0 + row;
      float4 a0 = make_float4(0.f, 0.f, 0.f, 0.f), a1 = a0;
      if (rr < rows) {
        const float* ap = A + (size_t)rr * 128 + k0 + kq * 8;
        a0 = ((const float4*)ap)[0];
        a1 = ((const float4*)ap)[1];
      }
      int kb = kq * 8;
      As[kb + 0][row] = a0.x;
      As[kb + 1][row] = a0.y;
      As[kb + 2][row] = a0.z;
      As[kb + 3][row] = a0.w;
      As[kb + 4][row] = a1.x;
      As[kb + 5][row] = a1.y;
      As[kb + 6][row] = a1.z;
      As[kb + 7][row] = a1.w;
    }
    {
      int kk = threadIdx.x >> 3, cq = threadIdx.x & 7;
      const float* wp = W + (size_t)(k0 + kk) * 128 + cq * 16;
#pragma unroll
      for (int f = 0; f < 4; f++)
        *(float4*)&Ws[kk][cq * 16 + f * 4] = ((const float4*)wp)[f];
    }
    __syncthreads();
#pragma unroll
    for (int kk = 0; kk < 32; kk++) {
      float4 a = *(const float4*)&As[kk][ty * 4];
      float4 w0 = *(const float4*)&Ws[kk][tx * 8];
      float4 w1 = *(const float4*)&Ws[kk][tx * 8 + 4];
      acc[0][0] = f4fma(a.x, w0, acc[0][0]);
      acc[0][1] = f4fma(a.x, w1, acc[0][1]);
      acc[1][0] = f4fma(a.y, w0, acc[1][0]);
      acc[1][1] = f4fma(a.y, w1, acc[1][1]);
      acc[2][0] = f4fma(a.z, w0, acc[2][0]);
      acc[2][1] = f4fma(a.z, w1, acc[2][1]);
      acc[3][0] = f4fma(a.w, w0, acc[3][0]);
      acc[3][1] = f4fma(a.w, w1, acc[3][1]);
    }
  }
  float4 b0 = ((const float4*)bias)[tx * 2];
  float4 b1 = ((const float4*)bias)[tx * 2 + 1];
#pragma unroll
  for (int j = 0; j < 4; j++) {
    int r = r0 + ty * 4 + j;
    if (r >= rows) break;
    float4 o0 = acc[j][0], o1 = acc[j][1];
    o0 = make_float4(leaky(o0.x + b0.x), leaky(o0.y + b0.y), leaky(o0.z + b0.z),
                     leaky(o0.w + b0.w));
    o1 = make_float4(leaky(o1.x + b1.x), leaky(o1.y + b1.y), leaky(o1.z + b1.z),
                     leaky(o1.w + b1.w));
    if (resid) {
      float4 r0v = ((const float4*)resid)[(size_t)r * 32 + tx * 2];
      float4 r1v = ((const float4*)resid)[(size_t)r * 32 + tx * 2 + 1];
      o0 = f4add(o0, r0v);
      o1 = f4add(o1, r1v);
    }
    ((float4*)out)[(size_t)r * 32 + tx * 2] = o0;
    ((float4*)out)[(size_t)r * 32 + tx * 2 + 1] = o1;
  }
}

// out_e[m][h][c] = Binv[m] * (T[h][m][:] @ lin_w[:, h*128 + c]) -- same tiling
template <int H>
__global__ __launch_bounds__(256) void k_oute64(const float* __restrict__ T,
                                                const float* __restrict__ linw,
                                                const float* __restrict__ Binv,
                                                float* __restrict__ oute) {
  int h = blockIdx.y;
  __shared__ float As[32][68];
  __shared__ float Ws[32][132];
  int tx = threadIdx.x & 15, ty = threadIdx.x >> 4;
  int r0 = blockIdx.x * 64;
  const float* A = T + (size_t)h * MM * 128;
  float4 acc[4][2];
#pragma unroll
  for (int j = 0; j < 4; j++) acc[j][0] = acc[j][1] = make_float4(0.f, 0.f, 0.f, 0.f);

  for (int k0 = 0; k0 < 128; k0 += 32) {
    __syncthreads();
    {
      int row = threadIdx.x >> 2, kq = threadIdx.x & 3;
      int rr = r0 + row;
      float4 a0 = make_float4(0.f, 0.f, 0.f, 0.f), a1 = a0;
      if (rr < MM) {
        const float* ap = A + (size_t)rr * 128 + k0 + kq * 8;
        a0 = ((const float4*)ap)[0];
        a1 = ((const float4*)ap)[1];
      }
      int kb = kq * 8;
      As[kb + 0][row] = a0.x;
      As[kb + 1][row] = a0.y;
      As[kb + 2][row] = a0.z;
      As[kb + 3][row] = a0.w;
      As[kb + 4][row] = a1.x;
      As[kb + 5][row] = a1.y;
      As[kb + 6][row] = a1.z;
      As[kb + 7][row] = a1.w;
    }
    {
      int kk = threadIdx.x >> 3, cq = threadIdx.x & 7;
      const float* wp = linw + (size_t)(k0 + kk) * (128 * H) + h * 128 + cq * 16;
#pragma unroll
      for (int f = 0; f < 4; f++)
        *(float4*)&Ws[kk][cq * 16 + f * 4] = ((const float4*)wp)[f];
    }
    __syncthreads();
#pragma unroll
    for (int kk = 0; kk < 32; kk++) {
      float4 a = *(const float4*)&As[kk][ty * 4];
      float4 w0 = *(const float4*)&Ws[kk][tx * 8];
      float4 w1 = *(const float4*)&Ws[kk][tx * 8 + 4];
      acc[0][0] = f4fma(a.x, w0, acc[0][0]);
      acc[0][1] = f4fma(a.x, w1, acc[0][1]);
      acc[1][0] = f4fma(a.y, w0, acc[1][0]);
      acc[1][1] = f4fma(a.y, w1, acc[1][1]);
      acc[2][0] = f4fma(a.z, w0, acc[2][0]);
      acc[2][1] = f4fma(a.z, w1, acc[2][1]);
      acc[3][0] = f4fma(a.w, w0, acc[3][0]);
      acc[3][1] = f4fma(a.w, w1, acc[3][1]);
    }
  }
#pragma unroll
  for (int j = 0; j < 4; j++) {
    int m = r0 + ty * 4 + j;
    if (m >= MM) break;
    float bv = Binv[m];
    float4 o0 = acc[j][0], o1 = acc[j][1];
    o0 = make_float4(bv * o0.x, bv * o0.y, bv * o0.z, bv * o0.w);
    o1 = make_float4(bv * o1.x, bv * o1.y, bv * o1.z, bv * o1.w);
    ((float4*)oute)[((size_t)m * H + h) * 32 + tx * 2] = o0;
    ((float4*)oute)[((size_t)m * H + h) * 32 + tx * 2 + 1] = o1;
  }
}

// ---------------------------------------------------------------------------
// BatchNorm (training-mode batch stats)
// ---------------------------------------------------------------------------
__global__ __launch_bounds__(256) void k_colstats(const float4* __restrict__ X4,
                                                  int rows, float* __restrict__ st) {
  int c4 = threadIdx.x & 31, rs = threadIdx.x >> 5, wid = threadIdx.x >> 6;
  int r0 = blockIdx.x * 256;
  int rend = min(r0 + 256, rows);
  float4 s = make_float4(0.f, 0.f, 0.f, 0.f), q = s;
  for (int r = r0 + rs; r < rend; r += 8) {
    float4 v = X4[(size_t)r * 32 + c4];
    s = f4add(s, v);
    q = make_float4(q.x + v.x * v.x, q.y + v.y * v.y, q.z + v.z * v.z, q.w + v.w * v.w);
  }
  s = f4add(s, f4shfl_xor32(s));
  q = f4add(q, f4shfl_xor32(q));
  __shared__ float4 red[4][32][2];
  if ((threadIdx.x & 63) < 32) {
    red[wid][c4][0] = s;
    red[wid][c4][1] = q;
  }
  __syncthreads();
  if (threadIdx.x < 32) {
    float4 S = f4add(f4add(red[0][threadIdx.x][0], red[1][threadIdx.x][0]),
                     f4add(red[2][threadIdx.x][0], red[3][threadIdx.x][0]));
    float4 Q = f4add(f4add(red[0][threadIdx.x][1], red[1][threadIdx.x][1]),
                     f4add(red[2][threadIdx.x][1], red[3][threadIdx.x][1]));
    int c = threadIdx.x * 4;
    atomicAdd(&st[c + 0], S.x);
    atomicAdd(&st[c + 1], S.y);
    atomicAdd(&st[c + 2], S.z);
    atomicAdd(&st[c + 3], S.w);
    atomicAdd(&st[128 + c + 0], Q.x);
    atomicAdd(&st[128 + c + 1], Q.y);
    atomicAdd(&st[128 + c + 2], Q.z);
    atomicAdd(&st[128 + c + 3], Q.w);
  }
}

__global__ void k_bnfinal(const float* __restrict__ st, const float* __restrict__ g,
                          const float* __restrict__ be, float rows_inv,
                          float* __restrict__ sc) {
  int c = threadIdx.x;  // 128 threads
  float mu = st[c] * rows_inv;
  float var = st[128 + c] * rows_inv - mu * mu;
  float scale = g[c] * rsqrtf(var + EPSBN);
  sc[c] = scale;
  sc[128 + c] = be[c] - mu * scale;
}

__global__ void k_bnapply(const float4* __restrict__ X4, const float* __restrict__ sc,
                          float4* __restrict__ Y4, int total4) {
  int i = blockIdx.x * 256 + threadIdx.x;
  if (i >= total4) return;
  int c4 = i & 31;
  float4 scale = ((const float4*)sc)[c4];
  float4 shift = ((const float4*)sc)[32 + c4];
  float4 v = X4[i];
  Y4[i] = make_float4(v.x * scale.x + shift.x, v.y * scale.y + shift.y,
                      v.z * scale.z + shift.z, v.w * scale.w + shift.w);
}

// ---------------------------------------------------------------------------
// UVT[h2][k]: h2<H -> U (x-side att), h2>=H -> V (attr-side att)
// ---------------------------------------------------------------------------
template <int H>
__global__ void k_uv(const float* __restrict__ linw, const float* __restrict__ att,
                     float* __restrict__ UVT) {
  int idx = blockIdx.x * 256 + threadIdx.x;
  if (idx >= 128 * H) return;
  int h = idx >> 7, k = idx & 127;
  float u = 0.f, v = 0.f;
  for (int c = 0; c < 128; c++) {
    float w = linw[(size_t)k * (128 * H) + h * 128 + c];
    u += w * att[h * 256 + c];
    v += w * att[h * 256 + 128 + c];
  }
  UVT[h * 128 + k] = u;
  UVT[(H + h) * 128 + k] = v;
}

// dotx[n,h] = X[n,:] . U[:,h] ; hv[n,h] = X[n,:] . V[:,h]
template <int H>
__global__ void k_dots(const float4* __restrict__ X4, int rows,
                       const float* __restrict__ UVT, float* __restrict__ dotx,
                       float* __restrict__ hv) {
  __shared__ float4 Ut[2 * H * 32];
  for (int i = threadIdx.x; i < 2 * H * 32; i += 256) Ut[i] = ((const float4*)UVT)[i];
  __syncthreads();
  int idx = blockIdx.x * 256 + threadIdx.x;
  if (idx >= rows * 2 * H) return;
  int n = idx / (2 * H), h2 = idx - n * (2 * H);
  const float4* xr = X4 + (size_t)n * 32;
  const float4* ur = Ut + h2 * 32;
  float s = 0.f;
#pragma unroll 8
  for (int q = 0; q < 32; q++) {
    float4 a = xr[q], b = ur[q];
    s += a.x * b.x + a.y * b.y + a.z * b.z + a.w * b.w;
  }
  if (h2 < H)
    dotx[n * H + h2] = s;
  else
    hv[n * H + (h2 - H)] = s;
}

// dota[m,h] = sum over incidences of edge m of hv[node, h]
template <int H>
__global__ void k_dota(const float* __restrict__ hv, const int* __restrict__ eoff,
                       const int* __restrict__ nn_e, float* __restrict__ dota) {
  int lane = threadIdx.x & 63;
  int m = blockIdx.x * 4 + (threadIdx.x >> 6);
  int s = eoff[m], t = eoff[m + 1];
  if (H == 4) {
    float4 acc = make_float4(0.f, 0.f, 0.f, 0.f);
    const float4* hv4 = (const float4*)hv;
    for (int j = s + lane; j < t; j += 64) acc = f4add(acc, hv4[nn_e[j]]);
#pragma unroll
    for (int o = 32; o >= 1; o >>= 1) {
      acc.x += __shfl_xor(acc.x, o);
      acc.y += __shfl_xor(acc.y, o);
      acc.z += __shfl_xor(acc.z, o);
      acc.w += __shfl_xor(acc.w, o);
    }
    if (lane == 0) ((float4*)dota)[m] = acc;
  } else {
    float acc = 0.f;
    for (int j = s + lane; j < t; j += 64) acc += hv[nn_e[j]];
#pragma unroll
    for (int o = 32; o >= 1; o >>= 1) acc += __shfl_xor(acc, o);
    if (lane == 0) dota[m] = acc;
  }
}

// ---------------------------------------------------------------------------
// Per-node segment softmax; alpha stored in node-CSR order.
// Fast path: deg<=64 — em via one load + shfl redistribute, v cached in regs.
// ---------------------------------------------------------------------------
template <int H>
__global__ void k_softmax(const int* __restrict__ noff, const int* __restrict__ em_n,
                          const float* __restrict__ dotx, const float* __restrict__ dota,
                          const float* __restrict__ wedge, float* __restrict__ alpha,
                          float* __restrict__ Dinv) {
  int lane = threadIdx.x & 63;
  int n = blockIdx.x * 4 + (threadIdx.x >> 6);
  int s = noff[n], t = noff[n + 1];
  int deg = t - s;
  int h = lane & (H - 1);
  float dx = dotx[n * H + h];
  if (deg <= 64) {
    int em0 = 0;
    float dd = 0.f;
    if (lane < deg) {
      em0 = em_n[s + lane];
      dd = wedge[em0];
    }
#pragma unroll
    for (int o = 32; o >= 1; o >>= 1) dd += __shfl_xor(dd, o);
    if (lane == 0) Dinv[n] = (dd > 0.f) ? 1.f / dd : 0.f;

    constexpr int KMAX = (H == 4) ? 4 : 1;
    int P = deg * H;
    float vc[KMAX];
    float mx = -3.0e38f;
#pragma unroll
    for (int k = 0; k < KMAX; k++) {
      int p = lane + 64 * k;
      int idx = (H == 4) ? (p >> 2) : p;
      int em = __shfl(em0, idx);
      float v = dx + dota[em * H + h];
      v = leaky(v);
      vc[k] = v;
      if (p < P) mx = fmaxf(mx, v);
    }
#pragma unroll
    for (int o = H; o < 64; o <<= 1) mx = fmaxf(mx, __shfl_xor(mx, o));
    float sm = 0.f;
#pragma unroll
    for (int k = 0; k < KMAX; k++) {
      int p = lane + 64 * k;
      float e = __expf(vc[k] - mx);
      vc[k] = e;
      if (p < P) sm += e;
    }
#pragma unroll
    for (int o = H; o < 64; o <<= 1) sm += __shfl_xor(sm, o);
    float inv = 1.f / (sm + 1e-16f);
#pragma unroll
    for (int k = 0; k < KMAX; k++) {
      int p = lane + 64 * k;
      if (p < P) alpha[s * H + p] = vc[k] * inv;
    }
  } else {
    // slow path (rare): 3-pass recompute
    float dd = 0.f;
    for (int i = s + lane; i < t; i += 64) dd += wedge[em_n[i]];
#pragma unroll
    for (int o = 32; o >= 1; o >>= 1) dd += __shfl_xor(dd, o);
    if (lane == 0) Dinv[n] = (dd > 0.f) ? 1.f / dd : 0.f;
    int P = deg * H;
    float mx = -3.0e38f;
    for (int p = lane; p < P; p += 64) {
      int i = s + ((H == 4) ? (p >> 2) : p);
      float v = leaky(dx + dota[em_n[i] * H + h]);
      mx = fmaxf(mx, v);
    }
#pragma unroll
    for (int o = H; o < 64; o <<= 1) mx = fmaxf(mx, __shfl_xor(mx, o));
    float sm = 0.f;
    for (int p = lane; p < P; p += 64) {
      int i = s + ((H == 4) ? (p >> 2) : p);
      float v = leaky(dx + dota[em_n[i] * H + h]);
      sm += __expf(v - mx);
    }
#pragma unroll
    for (int o = H; o < 64; o <<= 1) sm += __shfl_xor(sm, o);
    float inv = 1.f / (sm + 1e-16f);
    for (int p = lane; p < P; p += 64) {
      int i = s + ((H == 4) ? (p >> 2) : p);
      float v = leaky(dx + dota[em_n[i] * H + h]);
      alpha[s * H + p] = __expf(v - mx) * inv;
    }
  }
}

// ---------------------------------------------------------------------------
// T[h][m][c] = sum over incidences of edge m of alpha * h[node,c]
// Stage nn/pos in LDS first, then independent row gathers.
// ---------------------------------------------------------------------------
template <int H>
__global__ __launch_bounds__(256) void k_T(const float4* __restrict__ h4,
                                           const int* __restrict__ eoff,
                                           const int* __restrict__ nn_e,
                                           const int* __restrict__ posn_e,
                                           const float* __restrict__ alpha,
                                           float4* __restrict__ T4) {
  int m = blockIdx.x;
  int slot = threadIdx.x >> 5, lane = threadIdx.x & 31;
  int wid = threadIdx.x >> 6;
  int s = eoff[m], t = eoff[m + 1];
  __shared__ int snn[256], spos[256];
  __shared__ float4 red[4][H][32];
  float4 acc[H];
#pragma unroll
  for (int hh = 0; hh < H; hh++) acc[hh] = make_float4(0.f, 0.f, 0.f, 0.f);

  for (int c0 = s; c0 < t; c0 += 256) {
    int cnt = min(256, t - c0);
    __syncthreads();
    if (threadIdx.x < cnt) {
      snn[threadIdx.x] = nn_e[c0 + threadIdx.x];
      spos[threadIdx.x] = posn_e[c0 + threadIdx.x];
    }
    __syncthreads();
#pragma unroll 2
    for (int j = slot; j < cnt; j += 8) {
      int nd = snn[j];
      int pos = spos[j];
      float4 v = h4[(size_t)nd * 32 + lane];
      if (H == 4) {
        float4 a4 = *(const float4*)(alpha + (size_t)pos * 4);
        acc[0] = f4fma(a4.x, v, acc[0]);
        acc[1 % H] = f4fma(a4.y, v, acc[1 % H]);
        acc[2 % H] = f4fma(a4.z, v, acc[2 % H]);
        acc[3 % H] = f4fma(a4.w, v, acc[3 % H]);
      } else {
        float a = alpha[pos];
        acc[0] = f4fma(a, v, acc[0]);
      }
    }
  }
#pragma unroll
  for (int hh = 0; hh < H; hh++) acc[hh] = f4add(acc[hh], f4shfl_xor32(acc[hh]));
  if ((threadIdx.x & 63) < 32) {
#pragma unroll
    for (int hh = 0; hh < H; hh++) red[wid][hh][lane] = acc[hh];
  }
  __syncthreads();
  if (threadIdx.x < 32) {
#pragma unroll
    for (int hh = 0; hh < H; hh++) {
      float4 r = f4add(f4add(red[0][hh][threadIdx.x], red[1][hh][threadIdx.x]),
                       f4add(red[2][hh][threadIdx.x], red[3][hh][threadIdx.x]));
      T4[((size_t)hh * MM + m) * 32 + threadIdx.x] = r;
    }
  }
}

// ---------------------------------------------------------------------------
// out[n,c] = hres[n,c] + Dinv[n]/H * sum_{i in node} sum_h alpha*oute[m,h,c] + bias
// Stage em/alpha in LDS first, then independent row gathers.
// ---------------------------------------------------------------------------
template <int H>
__global__ __launch_bounds__(256) void k_phase9(
    const int* __restrict__ noff, const int* __restrict__ em_n,
    const float* __restrict__ alpha, const float4* __restrict__ oute4,
    const float* __restrict__ Dinv, const float* __restrict__ bias,
    const float4* __restrict__ hres4, float4* __restrict__ out4) {
  int n = blockIdx.x;
  int slot = threadIdx.x >> 5, lane = threadIdx.x & 31;
  int wid = threadIdx.x >> 6;
  int s = noff[n], t = noff[n + 1];
  __shared__ int sem[128];
  __shared__ float sal[128 * H];
  __shared__ float4 red[4][32];
  float4 acc = make_float4(0.f, 0.f, 0.f, 0.f);

  for (int c0 = s; c0 < t; c0 += 128) {
    int cnt = min(128, t - c0);
    __syncthreads();
    if (threadIdx.x < cnt) sem[threadIdx.x] = em_n[c0 + threadIdx.x];
    for (int j = threadIdx.x; j < cnt * H; j += 256) sal[j] = alpha[(size_t)c0 * H + j];
    __syncthreads();
    int P = cnt * H;
#pragma unroll 2
    for (int p = slot; p < P; p += 8) {
      int il = (H == 4) ? (p >> 2) : p;
      int hh = (H == 4) ? (p & 3) : 0;
      int mm = sem[il];
      float a = sal[p];
      acc = f4fma(a, oute4[((size_t)mm * H + hh) * 32 + lane], acc);
    }
  }
  acc = f4add(acc, f4shfl_xor32(acc));
  if ((threadIdx.x & 63) < 32) red[wid][lane] = acc;
  __syncthreads();
  if (threadIdx.x < 32) {
    float4 a2 = f4add(f4add(red[0][threadIdx.x], red[1][threadIdx.x]),
                      f4add(red[2][threadIdx.x], red[3][threadIdx.x]));
    float sc = Dinv[n] * (1.f / H);
    float4 hr = hres4[(size_t)n * 32 + threadIdx.x];
    float4 bi = ((const float4*)bias)[threadIdx.x];
    out4[(size_t)n * 32 + threadIdx.x] =
        make_float4(hr.x + sc * a2.x + bi.x, hr.y + sc * a2.y + bi.y,
                    hr.z + sc * a2.z + bi.z, hr.w + sc * a2.w + bi.w);
  }
}

// ---------------------------------------------------------------------------
// Host side
// ---------------------------------------------------------------------------
static inline size_t alignup(size_t x) { return (x + 255) & ~(size_t)255; }

extern "C" void kernel_launch(void* const* d_in, const int* in_sizes, int n_in,
                              void* d_out, int out_size, void* d_ws, size_t ws_size,
                              hipStream_t stream) {
  const float* x = (const float*)d_in[0];
  const int* node_idx = (const int*)d_in[1];
  const int* edge_idx = (const int*)d_in[2];
  const float* wedge = (const float*)d_in[3];
  const float* W1 = (const float*)d_in[4];
  const float* b1 = (const float*)d_in[5];
  const float* g1 = (const float*)d_in[6];
  const float* be1 = (const float*)d_in[7];
  const float* linw1 = (const float*)d_in[8];
  const float* att1 = (const float*)d_in[9];
  const float* bias1 = (const float*)d_in[10];
  const float* g2 = (const float*)d_in[11];
  const float* be2 = (const float*)d_in[12];
  const float* linw2 = (const float*)d_in[13];
  const float* att2 = (const float*)d_in[14];
  const float* bias2 = (const float*)d_in[15];
  const float* g3 = (const float*)d_in[16];
  const float* be3 = (const float*)d_in[17];
  const float* W2 = (const float*)d_in[18];
  const float* b2 = (const float*)d_in[19];
  const float* g4 = (const float*)d_in[20];
  const float* be4 = (const float*)d_in[21];
  float* out = (float*)d_out;

  char* ws = (char*)d_ws;
  size_t off = 0;
  auto alloc = [&](size_t bytes) -> void* {
    void* p = ws + off;
    off = alignup(off + bytes);
    return p;
  };
  float* buf0 = (float*)alloc((size_t)NN * 128 * 4);
  float* buf1 = (float*)alloc((size_t)NN * 128 * 4);
  float* Tbuf = (float*)alloc((size_t)4 * MM * 128 * 4);
  float* oute = (float*)alloc((size_t)MM * 4 * 128 * 4);
  float* alpha = (float*)alloc((size_t)EE * 4 * 4);
  float* dotx = (float*)alloc((size_t)NN * 4 * 4);
  float* hv = (float*)alloc((size_t)NN * 4 * 4);
  float* dota = (float*)alloc((size_t)MM * 4 * 4);
  float* UVT = (float*)alloc(128 * 8 * 4);
  float* Dinv = (float*)alloc((size_t)NN * 4);
  float* Binv = (float*)alloc((size_t)MM * 4);
  int* noff = (int*)alloc((size_t)(NN + 1) * 4);
  int* eoff = (int*)alloc((size_t)(MM + 1) * 4);
  int* em_n = (int*)alloc((size_t)EE * 4);
  int* nn_e = (int*)alloc((size_t)EE * 4);
  int* posn_e = (int*)alloc((size_t)EE * 4);
  int* zero_region = (int*)alloc((size_t)(2 * NN + 2 * MM) * 4);
  int* ncnt = zero_region;
  int* ecnt = ncnt + NN;
  int* ncur = ecnt + MM;
  int* ecur = ncur + NN;
  float* bnst = (float*)alloc(4 * 256 * 4);
  float* bnsc = (float*)alloc(4 * 256 * 4);
  (void)ws_size;
  (void)in_sizes;
  (void)n_in;
  (void)out_size;

  (void)hipMemsetAsync(zero_region, 0, (size_t)(2 * NN + 2 * MM) * 4, stream);
  (void)hipMemsetAsync(bnst, 0, 4 * 256 * 4, stream);

  // CSR build
  k_count<<<(EE + 255) / 256, 256, 0, stream>>>(node_idx, edge_idx, ncnt, ecnt);
  k_scan<<<1, 1024, 0, stream>>>(ncnt, noff, NN);
  k_scan<<<1, 1024, 0, stream>>>(ecnt, eoff, MM);
  k_fill<<<(EE + 255) / 256, 256, 0, stream>>>(node_idx, edge_idx, noff, eoff, ncur,
                                               ecur, em_n, nn_e, posn_e);
  k_binv<<<(MM + 255) / 256, 256, 0, stream>>>(eoff, wedge, Binv);

  const float ninv = 1.f / (float)NN;
  const int gemm_grid = (NN + 63) / 64;
  const int cs_grid = (NN + 255) / 256;
  const int bn_grid = (NN * 32 + 255) / 256;

  // h = leaky(x@W1+b1); BN1
  k_gemm128<<<gemm_grid, 256, 0, stream>>>(x, W1, b1, nullptr, buf0, NN);
  k_colstats<<<cs_grid, 256, 0, stream>>>((const float4*)buf0, NN, bnst + 0 * 256);
  k_bnfinal<<<1, 128, 0, stream>>>(bnst + 0 * 256, g1, be1, ninv, bnsc + 0 * 256);
  k_bnapply<<<bn_grid, 256, 0, stream>>>((const float4*)buf0, bnsc + 0 * 256,
                                         (float4*)buf1, NN * 32);

  // ---- hconv1 (H=4) on buf1 ----
  k_uv<4><<<2, 256, 0, stream>>>(linw1, att1, UVT);
  k_dots<4><<<(NN * 8 + 255) / 256, 256, 0, stream>>>((const float4*)buf1, NN, UVT,
                                                      dotx, hv);
  k_dota<4><<<MM / 4, 256, 0, stream>>>(hv, eoff, nn_e, dota);
  k_softmax<4><<<NN / 4, 256, 0, stream>>>(noff, em_n, dotx, dota, wedge, alpha, Dinv);
  k_T<4><<<MM, 256, 0, stream>>>((const float4*)buf1, eoff, nn_e, posn_e, alpha,
                                 (float4*)Tbuf);
  {
    dim3 g((MM + 63) / 64, 4);
    k_oute64<4><<<g, 256, 0, stream>>>(Tbuf, linw1, Binv, oute);
  }
  k_phase9<4><<<NN, 256, 0, stream>>>(noff, em_n, alpha, (const float4*)oute, Dinv,
                                      bias1, (const float4*)buf1, (float4*)buf0);
  // BN2
  k_colstats<<<cs_grid, 256, 0, stream>>>((const float4*)buf0, NN, bnst + 1 * 256);
  k_bnfinal<<<1, 128, 0, stream>>>(bnst + 1 * 256, g2, be2, ninv, bnsc + 1 * 256);
  k_bnapply<<<bn_grid, 256, 0, stream>>>((const float4*)buf0, bnsc + 1 * 256,
                                         (float4*)buf1, NN * 32);

  // ---- hconv2 (H=1) on buf1 ----
  k_uv<1><<<1, 256, 0, stream>>>(linw2, att2, UVT);
  k_dots<1><<<(NN * 2 + 255) / 256, 256, 0, stream>>>((const float4*)buf1, NN, UVT,
                                                      dotx, hv);
  k_dota<1><<<MM / 4, 256, 0, stream>>>(hv, eoff, nn_e, dota);
  k_softmax<1><<<NN / 4, 256, 0, stream>>>(noff, em_n, dotx, dota, wedge, alpha, Dinv);
  k_T<1><<<MM, 256, 0, stream>>>((const float4*)buf1, eoff, nn_e, posn_e, alpha,
                                 (float4*)Tbuf);
  {
    dim3 g((MM + 63) / 64, 1);
    k_oute64<1><<<g, 256, 0, stream>>>(Tbuf, linw2, Binv, oute);
  }
  k_phase9<1><<<NN, 256, 0, stream>>>(noff, em_n, alpha, (const float4*)oute, Dinv,
                                      bias2, (const float4*)buf1, (float4*)buf0);
  // BN3
  k_colstats<<<cs_grid, 256, 0, stream>>>((const float4*)buf0, NN, bnst + 2 * 256);
  k_bnfinal<<<1, 128, 0, stream>>>(bnst + 2 * 256, g3, be3, ninv, bnsc + 2 * 256);
  k_bnapply<<<bn_grid, 256, 0, stream>>>((const float4*)buf0, bnsc + 2 * 256,
                                         (float4*)buf1, NN * 32);

  // final: o = leaky(h@W2+b2); pre = src + o; BN4 -> out
  k_gemm128<<<gemm_grid, 256, 0, stream>>>(buf1, W2, b2, x, buf0, NN);
  k_colstats<<<cs_grid, 256, 0, stream>>>((const float4*)buf0, NN, bnst + 3 * 256);
  k_bnfinal<<<1, 128, 0, stream>>>(bnst + 3 * 256, g4, be4, ninv, bnsc + 3 * 256);
  k_bnapply<<<bn_grid, 256, 0, stream>>>((const float4*)buf0, bnsc + 3 * 256,
                                         (float4*)out, NN * 32);
}

// Round 4
// 469.838 us; speedup vs baseline: 1.9901x; 1.0134x over previous
//
#include <hip/hip_runtime.h>

// Problem constants (match reference)
#define NN 20000
#define MM 2000
#define EE 320000
static constexpr float SLOPE = 0.2f;
static constexpr float EPSBN = 1e-5f;

__device__ inline float4 f4add(float4 a, float4 b) {
  return make_float4(a.x + b.x, a.y + b.y, a.z + b.z, a.w + b.w);
}
__device__ inline float4 f4fma(float a, float4 v, float4 c) {
  return make_float4(c.x + a * v.x, c.y + a * v.y, c.z + a * v.z, c.w + a * v.w);
}
__device__ inline float leaky(float v) { return (v > 0.f) ? v : SLOPE * v; }

// per-thread BN scale/shift for 4 channels (f4 index c4)
__device__ inline void bn_sc4(const float* __restrict__ st, const float* __restrict__ g,
                              const float* __restrict__ be, float ninv, int c4,
                              float4& sc, float4& sh) {
  float* scp = &sc.x;
  float* shp = &sh.x;
#pragma unroll
  for (int j = 0; j < 4; j++) {
    int c = c4 * 4 + j;
    float mu = st[c] * ninv;
    float var = st[128 + c] * ninv - mu * mu;
    float s = g[c] * rsqrtf(var + EPSBN);
    scp[j] = s;
    shp[j] = be[c] - mu * s;
  }
}

// ---------------------------------------------------------------------------
// CSR build
// ---------------------------------------------------------------------------
__global__ void k_count(const int* __restrict__ ni, const int* __restrict__ ei,
                        int* ncnt, int* ecnt) {
  int e = blockIdx.x * 256 + threadIdx.x;
  if (e >= EE) return;
  atomicAdd(&ncnt[ni[e]], 1);
  atomicAdd(&ecnt[ei[e]], 1);
}

// single-block exclusive scan, shfl-based
__global__ __launch_bounds__(1024) void k_scan(const int* __restrict__ cnt,
                                               int* __restrict__ off, int n) {
  __shared__ int swav[16];
  __shared__ int sCarry;
  int t = threadIdx.x;
  int lane = t & 63, wid = t >> 6;
  if (t == 0) sCarry = 0;
  __syncthreads();
  for (int base = 0; base < n; base += 1024) {
    int i = base + t;
    int v = (i < n) ? cnt[i] : 0;
    int x = v;
#pragma unroll
    for (int o = 1; o < 64; o <<= 1) {
      int y = __shfl_up(x, o);
      if (lane >= o) x += y;
    }
    if (lane == 63) swav[wid] = x;
    __syncthreads();
    if (wid == 0) {
      int s = (lane < 16) ? swav[lane] : 0;
#pragma unroll
      for (int o = 1; o < 16; o <<= 1) {
        int y = __shfl_up(s, o);
        if (lane >= o) s += y;
      }
      if (lane < 16) swav[lane] = s;
    }
    __syncthreads();
    int wpre = wid ? swav[wid - 1] : 0;
    int total = swav[15];
    if (i < n) off[i] = sCarry + wpre + x - v;
    __syncthreads();
    if (t == 0) sCarry += total;
    __syncthreads();
  }
  if (t == 0) off[n] = sCarry;
}

// em_n[node-CSR pos] = edge id; npos_e[edge-CSR pos] = {node id, node-CSR pos}
__global__ void k_fill(const int* __restrict__ ni, const int* __restrict__ ei,
                       const int* __restrict__ noff, const int* __restrict__ eoff,
                       int* ncur, int* ecur, int* __restrict__ em_n,
                       int2* __restrict__ npos_e) {
  int e = blockIdx.x * 256 + threadIdx.x;
  if (e >= EE) return;
  int n = ni[e];
  int m = ei[e];
  int p = atomicAdd(&ncur[n], 1);
  int pn = noff[n] + p;
  int q = atomicAdd(&ecur[m], 1);
  int pe = eoff[m] + q;
  em_n[pn] = m;
  npos_e[pe] = make_int2(n, pn);
}

// ---------------------------------------------------------------------------
// Tiled GEMM: out = maybe_resid + leaky(BNopt(A)[rows,128] @ W[128,128] + b)
// ---------------------------------------------------------------------------
__global__ __launch_bounds__(256) void k_gemm128(
    const float* __restrict__ A, const float* __restrict__ W,
    const float* __restrict__ bias, const float* __restrict__ resid,
    const float* __restrict__ st, const float* __restrict__ g,
    const float* __restrict__ be, float ninv, float* __restrict__ out, int rows) {
  __shared__ float As[32][68];
  __shared__ float Ws[32][132];
  __shared__ float scs[128], shs[128];
  if (st && threadIdx.x < 128) {
    int c = threadIdx.x;
    float mu = st[c] * ninv;
    float var = st[128 + c] * ninv - mu * mu;
    float s = g[c] * rsqrtf(var + EPSBN);
    scs[c] = s;
    shs[c] = be[c] - mu * s;
  }
  if (st) __syncthreads();
  int tx = threadIdx.x & 15, ty = threadIdx.x >> 4;
  int r0 = blockIdx.x * 64;
  float4 acc[4][2];
#pragma unroll
  for (int j = 0; j < 4; j++) acc[j][0] = acc[j][1] = make_float4(0.f, 0.f, 0.f, 0.f);

  for (int k0 = 0; k0 < 128; k0 += 32) {
    __syncthreads();
    {
      int row = threadIdx.x >> 2, kq = threadIdx.x & 3;
      int rr = r0 + row;
      float4 a0 = make_float4(0.f, 0.f, 0.f, 0.f), a1 = a0;
      if (rr < rows) {
        const float* ap = A + (size_t)rr * 128 + k0 + kq * 8;
        a0 = ((const float4*)ap)[0];
        a1 = ((const float4*)ap)[1];
      }
      int kb = k0 + kq * 8;
      if (st) {
        a0.x = a0.x * scs[kb + 0] + shs[kb + 0];
        a0.y = a0.y * scs[kb + 1] + shs[kb + 1];
        a0.z = a0.z * scs[kb + 2] + shs[kb + 2];
        a0.w = a0.w * scs[kb + 3] + shs[kb + 3];
        a1.x = a1.x * scs[kb + 4] + shs[kb + 4];
        a1.y = a1.y * scs[kb + 5] + shs[kb + 5];
        a1.z = a1.z * scs[kb + 6] + shs[kb + 6];
        a1.w = a1.w * scs[kb + 7] + shs[kb + 7];
      }
      int kl = kq * 8;
      As[kl + 0][row] = a0.x;
      As[kl + 1][row] = a0.y;
      As[kl + 2][row] = a0.z;
      As[kl + 3][row] = a0.w;
      As[kl + 4][row] = a1.x;
      As[kl + 5][row] = a1.y;
      As[kl + 6][row] = a1.z;
      As[kl + 7][row] = a1.w;
    }
    {
      int kk = threadIdx.x >> 3, cq = threadIdx.x & 7;
      const float* wp = W + (size_t)(k0 + kk) * 128 + cq * 16;
#pragma unroll
      for (int f = 0; f < 4; f++)
        *(float4*)&Ws[kk][cq * 16 + f * 4] = ((const float4*)wp)[f];
    }
    __syncthreads();
#pragma unroll
    for (int kk = 0; kk < 32; kk++) {
      float4 a = *(const float4*)&As[kk][ty * 4];
      float4 w0 = *(const float4*)&Ws[kk][tx * 8];
      float4 w1 = *(const float4*)&Ws[kk][tx * 8 + 4];
      acc[0][0] = f4fma(a.x, w0, acc[0][0]);
      acc[0][1] = f4fma(a.x, w1, acc[0][1]);
      acc[1][0] = f4fma(a.y, w0, acc[1][0]);
      acc[1][1] = f4fma(a.y, w1, acc[1][1]);
      acc[2][0] = f4fma(a.z, w0, acc[2][0]);
      acc[2][1] = f4fma(a.z, w1, acc[2][1]);
      acc[3][0] = f4fma(a.w, w0, acc[3][0]);
      acc[3][1] = f4fma(a.w, w1, acc[3][1]);
    }
  }
  float4 b0 = ((const float4*)bias)[tx * 2];
  float4 b1 = ((const float4*)bias)[tx * 2 + 1];
#pragma unroll
  for (int j = 0; j < 4; j++) {
    int r = r0 + ty * 4 + j;
    if (r >= rows) break;
    float4 o0 = acc[j][0], o1 = acc[j][1];
    o0 = make_float4(leaky(o0.x + b0.x), leaky(o0.y + b0.y), leaky(o0.z + b0.z),
                     leaky(o0.w + b0.w));
    o1 = make_float4(leaky(o1.x + b1.x), leaky(o1.y + b1.y), leaky(o1.z + b1.z),
                     leaky(o1.w + b1.w));
    if (resid) {
      float4 r0v = ((const float4*)resid)[(size_t)r * 32 + tx * 2];
      float4 r1v = ((const float4*)resid)[(size_t)r * 32 + tx * 2 + 1];
      o0 = f4add(o0, r0v);
      o1 = f4add(o1, r1v);
    }
    ((float4*)out)[(size_t)r * 32 + tx * 2] = o0;
    ((float4*)out)[(size_t)r * 32 + tx * 2 + 1] = o1;
  }
}

// out_e[m][h][c] = (wedge[m]/deg) * (T[h][m][:] @ lin_w[:, h*128 + c])
template <int H>
__global__ __launch_bounds__(256) void k_oute64(const float* __restrict__ T,
                                                const float* __restrict__ linw,
                                                const int* __restrict__ eoff,
                                                const float* __restrict__ wedge,
                                                float* __restrict__ oute) {
  int h = blockIdx.y;
  __shared__ float As[32][68];
  __shared__ float Ws[32][132];
  int tx = threadIdx.x & 15, ty = threadIdx.x >> 4;
  int r0 = blockIdx.x * 64;
  const float* A = T + (size_t)h * MM * 128;
  float4 acc[4][2];
#pragma unroll
  for (int j = 0; j < 4; j++) acc[j][0] = acc[j][1] = make_float4(0.f, 0.f, 0.f, 0.f);

  for (int k0 = 0; k0 < 128; k0 += 32) {
    __syncthreads();
    {
      int row = threadIdx.x >> 2, kq = threadIdx.x & 3;
      int rr = r0 + row;
      float4 a0 = make_float4(0.f, 0.f, 0.f, 0.f), a1 = a0;
      if (rr < MM) {
        const float* ap = A + (size_t)rr * 128 + k0 + kq * 8;
        a0 = ((const float4*)ap)[0];
        a1 = ((const float4*)ap)[1];
      }
      int kb = kq * 8;
      As[kb + 0][row] = a0.x;
      As[kb + 1][row] = a0.y;
      As[kb + 2][row] = a0.z;
      As[kb + 3][row] = a0.w;
      As[kb + 4][row] = a1.x;
      As[kb + 5][row] = a1.y;
      As[kb + 6][row] = a1.z;
      As[kb + 7][row] = a1.w;
    }
    {
      int kk = threadIdx.x >> 3, cq = threadIdx.x & 7;
      const float* wp = linw + (size_t)(k0 + kk) * (128 * H) + h * 128 + cq * 16;
#pragma unroll
      for (int f = 0; f < 4; f++)
        *(float4*)&Ws[kk][cq * 16 + f * 4] = ((const float4*)wp)[f];
    }
    __syncthreads();
#pragma unroll
    for (int kk = 0; kk < 32; kk++) {
      float4 a = *(const float4*)&As[kk][ty * 4];
      float4 w0 = *(const float4*)&Ws[kk][tx * 8];
      float4 w1 = *(const float4*)&Ws[kk][tx * 8 + 4];
      acc[0][0] = f4fma(a.x, w0, acc[0][0]);
      acc[0][1] = f4fma(a.x, w1, acc[0][1]);
      acc[1][0] = f4fma(a.y, w0, acc[1][0]);
      acc[1][1] = f4fma(a.y, w1, acc[1][1]);
      acc[2][0] = f4fma(a.z, w0, acc[2][0]);
      acc[2][1] = f4fma(a.z, w1, acc[2][1]);
      acc[3][0] = f4fma(a.w, w0, acc[3][0]);
      acc[3][1] = f4fma(a.w, w1, acc[3][1]);
    }
  }
#pragma unroll
  for (int j = 0; j < 4; j++) {
    int m = r0 + ty * 4 + j;
    if (m >= MM) break;
    int d = eoff[m + 1] - eoff[m];
    float bv = (d > 0) ? wedge[m] / (float)d : 0.f;
    float4 o0 = acc[j][0], o1 = acc[j][1];
    o0 = make_float4(bv * o0.x, bv * o0.y, bv * o0.z, bv * o0.w);
    o1 = make_float4(bv * o1.x, bv * o1.y, bv * o1.z, bv * o1.w);
    ((float4*)oute)[((size_t)m * H + h) * 32 + tx * 2] = o0;
    ((float4*)oute)[((size_t)m * H + h) * 32 + tx * 2 + 1] = o1;
  }
}

// ---------------------------------------------------------------------------
// BatchNorm column stats (sum, sumsq)
// ---------------------------------------------------------------------------
__global__ __launch_bounds__(256) void k_colstats(const float4* __restrict__ X4,
                                                  int rows, float* __restrict__ st) {
  int c4 = threadIdx.x & 31, rs = threadIdx.x >> 5, wid = threadIdx.x >> 6;
  int r0 = blockIdx.x * 256;
  int rend = min(r0 + 256, rows);
  float4 s = make_float4(0.f, 0.f, 0.f, 0.f), q = s;
  for (int r = r0 + rs; r < rend; r += 8) {
    float4 v = X4[(size_t)r * 32 + c4];
    s = f4add(s, v);
    q = make_float4(q.x + v.x * v.x, q.y + v.y * v.y, q.z + v.z * v.z, q.w + v.w * v.w);
  }
  s.x += __shfl_xor(s.x, 32); s.y += __shfl_xor(s.y, 32);
  s.z += __shfl_xor(s.z, 32); s.w += __shfl_xor(s.w, 32);
  q.x += __shfl_xor(q.x, 32); q.y += __shfl_xor(q.y, 32);
  q.z += __shfl_xor(q.z, 32); q.w += __shfl_xor(q.w, 32);
  __shared__ float4 red[4][32][2];
  if ((threadIdx.x & 63) < 32) {
    red[wid][c4][0] = s;
    red[wid][c4][1] = q;
  }
  __syncthreads();
  if (threadIdx.x < 32) {
    float4 S = f4add(f4add(red[0][threadIdx.x][0], red[1][threadIdx.x][0]),
                     f4add(red[2][threadIdx.x][0], red[3][threadIdx.x][0]));
    float4 Q = f4add(f4add(red[0][threadIdx.x][1], red[1][threadIdx.x][1]),
                     f4add(red[2][threadIdx.x][1], red[3][threadIdx.x][1]));
    int c = threadIdx.x * 4;
    atomicAdd(&st[c + 0], S.x);
    atomicAdd(&st[c + 1], S.y);
    atomicAdd(&st[c + 2], S.z);
    atomicAdd(&st[c + 3], S.w);
    atomicAdd(&st[128 + c + 0], Q.x);
    atomicAdd(&st[128 + c + 1], Q.y);
    atomicAdd(&st[128 + c + 2], Q.z);
    atomicAdd(&st[128 + c + 3], Q.w);
  }
}

// final: out = BN(X) computed from raw stats
__global__ void k_bnapply_final(const float4* __restrict__ X4,
                                const float* __restrict__ st,
                                const float* __restrict__ g,
                                const float* __restrict__ be, float ninv,
                                float4* __restrict__ Y4, int total4) {
  int i = blockIdx.x * 256 + threadIdx.x;
  if (i >= total4) return;
  int c4 = i & 31;
  float4 sc, sh;
  bn_sc4(st, g, be, ninv, c4, sc, sh);
  float4 v = X4[i];
  Y4[i] = make_float4(v.x * sc.x + sh.x, v.y * sc.y + sh.y, v.z * sc.z + sh.z,
                      v.w * sc.w + sh.w);
}

// ---------------------------------------------------------------------------
// UVT[h2][k]: h2<H -> U (x-side att), h2>=H -> V (attr-side att)
// ---------------------------------------------------------------------------
template <int H>
__global__ void k_uv(const float* __restrict__ linw, const float* __restrict__ att,
                     float* __restrict__ UVT) {
  int idx = blockIdx.x * 256 + threadIdx.x;
  if (idx >= 128 * H) return;
  int h = idx >> 7, k = idx & 127;
  float u = 0.f, v = 0.f;
  for (int c = 0; c < 128; c++) {
    float w = linw[(size_t)k * (128 * H) + h * 128 + c];
    u += w * att[h * 256 + c];
    v += w * att[h * 256 + 128 + c];
  }
  UVT[h * 128 + k] = u;
  UVT[(H + h) * 128 + k] = v;
}

// dotx[n,h] = BN(X)[n,:] . U[:,h] ; hv[n,h] = BN(X)[n,:] . V[:,h]
template <int H>
__global__ void k_dots(const float4* __restrict__ X4, int rows,
                       const float* __restrict__ UVT, const float* __restrict__ st,
                       const float* __restrict__ g, const float* __restrict__ be,
                       float ninv, float* __restrict__ dotx, float* __restrict__ hv) {
  __shared__ float4 Ut[2 * H * 32];
  __shared__ float4 scl[32], shl[32];
  if (threadIdx.x < 32) {
    float4 sc, sh;
    bn_sc4(st, g, be, ninv, threadIdx.x, sc, sh);
    scl[threadIdx.x] = sc;
    shl[threadIdx.x] = sh;
  }
  for (int i = threadIdx.x; i < 2 * H * 32; i += 256) Ut[i] = ((const float4*)UVT)[i];
  __syncthreads();
  int idx = blockIdx.x * 256 + threadIdx.x;
  if (idx >= rows * 2 * H) return;
  int n = idx / (2 * H), h2 = idx - n * (2 * H);
  const float4* xr = X4 + (size_t)n * 32;
  const float4* ur = Ut + h2 * 32;
  float s = 0.f;
#pragma unroll 8
  for (int q = 0; q < 32; q++) {
    float4 a = xr[q], b = ur[q], c = scl[q], d = shl[q];
    float ax = a.x * c.x + d.x, ay = a.y * c.y + d.y;
    float az = a.z * c.z + d.z, aw = a.w * c.w + d.w;
    s += ax * b.x + ay * b.y + az * b.z + aw * b.w;
  }
  if (h2 < H)
    dotx[n * H + h2] = s;
  else
    hv[n * H + (h2 - H)] = s;
}

// dota[m,h] = sum over incidences of edge m of hv[node, h]
template <int H>
__global__ void k_dota(const float* __restrict__ hv, const int* __restrict__ eoff,
                       const int2* __restrict__ npos_e, float* __restrict__ dota) {
  int lane = threadIdx.x & 63;
  int m = blockIdx.x * 4 + (threadIdx.x >> 6);
  int s = eoff[m], t = eoff[m + 1];
  if (H == 4) {
    float4 acc = make_float4(0.f, 0.f, 0.f, 0.f);
    const float4* hv4 = (const float4*)hv;
    for (int j = s + lane; j < t; j += 64) acc = f4add(acc, hv4[npos_e[j].x]);
#pragma unroll
    for (int o = 32; o >= 1; o >>= 1) {
      acc.x += __shfl_xor(acc.x, o);
      acc.y += __shfl_xor(acc.y, o);
      acc.z += __shfl_xor(acc.z, o);
      acc.w += __shfl_xor(acc.w, o);
    }
    if (lane == 0) ((float4*)dota)[m] = acc;
  } else {
    float acc = 0.f;
    for (int j = s + lane; j < t; j += 64) acc += hv[npos_e[j].x];
#pragma unroll
    for (int o = 32; o >= 1; o >>= 1) acc += __shfl_xor(acc, o);
    if (lane == 0) dota[m] = acc;
  }
}

// ---------------------------------------------------------------------------
// Per-node segment softmax; alpha stored in node-CSR order.
// ---------------------------------------------------------------------------
template <int H>
__global__ void k_softmax(const int* __restrict__ noff, const int* __restrict__ em_n,
                          const float* __restrict__ dotx, const float* __restrict__ dota,
                          const float* __restrict__ wedge, float* __restrict__ alpha,
                          float* __restrict__ Dinv) {
  int lane = threadIdx.x & 63;
  int n = blockIdx.x * 4 + (threadIdx.x >> 6);
  int s = noff[n], t = noff[n + 1];
  int deg = t - s;
  int h = lane & (H - 1);
  float dx = dotx[n * H + h];
  if (deg <= 64) {
    int em0 = 0;
    float dd = 0.f;
    if (lane < deg) {
      em0 = em_n[s + lane];
      dd = wedge[em0];
    }
#pragma unroll
    for (int o = 32; o >= 1; o >>= 1) dd += __shfl_xor(dd, o);
    if (lane == 0) Dinv[n] = (dd > 0.f) ? 1.f / dd : 0.f;

    constexpr int KMAX = (H == 4) ? 4 : 1;
    int P = deg * H;
    float vc[KMAX];
    float mx = -3.0e38f;
#pragma unroll
    for (int k = 0; k < KMAX; k++) {
      int p = lane + 64 * k;
      int idx = (H == 4) ? (p >> 2) : p;
      int em = __shfl(em0, idx);
      float v = dx + dota[em * H + h];
      v = leaky(v);
      vc[k] = v;
      if (p < P) mx = fmaxf(mx, v);
    }
#pragma unroll
    for (int o = H; o < 64; o <<= 1) mx = fmaxf(mx, __shfl_xor(mx, o));
    float sm = 0.f;
#pragma unroll
    for (int k = 0; k < KMAX; k++) {
      int p = lane + 64 * k;
      float e = __expf(vc[k] - mx);
      vc[k] = e;
      if (p < P) sm += e;
    }
#pragma unroll
    for (int o = H; o < 64; o <<= 1) sm += __shfl_xor(sm, o);
    float inv = 1.f / (sm + 1e-16f);
#pragma unroll
    for (int k = 0; k < KMAX; k++) {
      int p = lane + 64 * k;
      if (p < P) alpha[s * H + p] = vc[k] * inv;
    }
  } else {
    float dd = 0.f;
    for (int i = s + lane; i < t; i += 64) dd += wedge[em_n[i]];
#pragma unroll
    for (int o = 32; o >= 1; o >>= 1) dd += __shfl_xor(dd, o);
    if (lane == 0) Dinv[n] = (dd > 0.f) ? 1.f / dd : 0.f;
    int P = deg * H;
    float mx = -3.0e38f;
    for (int p = lane; p < P; p += 64) {
      int i = s + ((H == 4) ? (p >> 2) : p);
      float v = leaky(dx + dota[em_n[i] * H + h]);
      mx = fmaxf(mx, v);
    }
#pragma unroll
    for (int o = H; o < 64; o <<= 1) mx = fmaxf(mx, __shfl_xor(mx, o));
    float sm = 0.f;
    for (int p = lane; p < P; p += 64) {
      int i = s + ((H == 4) ? (p >> 2) : p);
      float v = leaky(dx + dota[em_n[i] * H + h]);
      sm += __expf(v - mx);
    }
#pragma unroll
    for (int o = H; o < 64; o <<= 1) sm += __shfl_xor(sm, o);
    float inv = 1.f / (sm + 1e-16f);
    for (int p = lane; p < P; p += 64) {
      int i = s + ((H == 4) ? (p >> 2) : p);
      float v = leaky(dx + dota[em_n[i] * H + h]);
      alpha[s * H + p] = __expf(v - mx) * inv;
    }
  }
}

// ---------------------------------------------------------------------------
// T[h][m][c] = sum over incidences of edge m of alpha * BN(h)[node,c]
// block = (edge m, channel-half); 16 slots x 16 lanes.
// ---------------------------------------------------------------------------
template <int H>
__global__ __launch_bounds__(256) void k_T(const float4* __restrict__ h4,
                                           const int* __restrict__ eoff,
                                           const int2* __restrict__ npos_e,
                                           const float* __restrict__ alpha,
                                           const float* __restrict__ st,
                                           const float* __restrict__ g,
                                           const float* __restrict__ be, float ninv,
                                           float4* __restrict__ T4) {
  int m = blockIdx.x;
  int half = blockIdx.y;
  int slot = threadIdx.x >> 4, lane = threadIdx.x & 15;
  int wid = threadIdx.x >> 6;
  int c4 = half * 16 + lane;
  float4 scB, shB;
  bn_sc4(st, g, be, ninv, c4, scB, shB);
  int s = eoff[m], t = eoff[m + 1];
  __shared__ int2 snp[256];
  __shared__ float4 red[4][H][16];
  float4 acc[H];
#pragma unroll
  for (int hh = 0; hh < H; hh++) acc[hh] = make_float4(0.f, 0.f, 0.f, 0.f);

  for (int c0 = s; c0 < t; c0 += 256) {
    int cnt = min(256, t - c0);
    __syncthreads();
    if (threadIdx.x < cnt) snp[threadIdx.x] = npos_e[c0 + threadIdx.x];
    __syncthreads();
#pragma unroll 4
    for (int j = slot; j < cnt; j += 16) {
      int2 np = snp[j];
      float4 v = h4[(size_t)np.x * 32 + c4];
      v = make_float4(v.x * scB.x + shB.x, v.y * scB.y + shB.y, v.z * scB.z + shB.z,
                      v.w * scB.w + shB.w);
      if (H == 4) {
        float4 a4 = *(const float4*)(alpha + (size_t)np.y * 4);
        acc[0] = f4fma(a4.x, v, acc[0]);
        acc[1 % H] = f4fma(a4.y, v, acc[1 % H]);
        acc[2 % H] = f4fma(a4.z, v, acc[2 % H]);
        acc[3 % H] = f4fma(a4.w, v, acc[3 % H]);
      } else {
        float a = alpha[np.y];
        acc[0] = f4fma(a, v, acc[0]);
      }
    }
  }
#pragma unroll
  for (int hh = 0; hh < H; hh++) {
    float4 a = acc[hh];
    a.x += __shfl_xor(a.x, 16); a.y += __shfl_xor(a.y, 16);
    a.z += __shfl_xor(a.z, 16); a.w += __shfl_xor(a.w, 16);
    a.x += __shfl_xor(a.x, 32); a.y += __shfl_xor(a.y, 32);
    a.z += __shfl_xor(a.z, 32); a.w += __shfl_xor(a.w, 32);
    acc[hh] = a;
  }
  if ((threadIdx.x & 63) < 16) {
#pragma unroll
    for (int hh = 0; hh < H; hh++) red[wid][hh][lane] = acc[hh];
  }
  __syncthreads();
  if (threadIdx.x < 16 * H) {
    int hh = threadIdx.x >> 4, c = threadIdx.x & 15;
    float4 r = f4add(f4add(red[0][hh][c], red[1][hh][c]),
                     f4add(red[2][hh][c], red[3][hh][c]));
    T4[((size_t)hh * MM + m) * 32 + half * 16 + c] = r;
  }
}

// ---------------------------------------------------------------------------
// out[n,c] = BN(hres)[n,c] + Dinv[n]/H * sum alpha*oute[m,h,c] + bias
// block = (node n, channel-half); 16 slots x 16 lanes.
// ---------------------------------------------------------------------------
template <int H>
__global__ __launch_bounds__(256) void k_phase9(
    const int* __restrict__ noff, const int* __restrict__ em_n,
    const float* __restrict__ alpha, const float4* __restrict__ oute4,
    const float* __restrict__ Dinv, const float* __restrict__ bias,
    const float4* __restrict__ hres4, const float* __restrict__ st,
    const float* __restrict__ g, const float* __restrict__ be, float ninv,
    float4* __restrict__ out4) {
  int n = blockIdx.x;
  int half = blockIdx.y;
  int slot = threadIdx.x >> 4, lane = threadIdx.x & 15;
  int wid = threadIdx.x >> 6;
  int s = noff[n], t = noff[n + 1];
  __shared__ int sem[128];
  __shared__ float sal[128 * H];
  __shared__ float4 red[4][16];
  float4 acc = make_float4(0.f, 0.f, 0.f, 0.f);

  for (int c0 = s; c0 < t; c0 += 128) {
    int cnt = min(128, t - c0);
    __syncthreads();
    if (threadIdx.x < cnt) sem[threadIdx.x] = em_n[c0 + threadIdx.x];
    for (int j = threadIdx.x; j < cnt * H; j += 256) sal[j] = alpha[(size_t)c0 * H + j];
    __syncthreads();
    int P = cnt * H;
#pragma unroll 4
    for (int p = slot; p < P; p += 16) {
      int il = (H == 4) ? (p >> 2) : p;
      int hh = (H == 4) ? (p & 3) : 0;
      int mm = sem[il];
      float a = sal[p];
      acc = f4fma(a, oute4[((size_t)mm * H + hh) * 32 + half * 16 + lane], acc);
    }
  }
  acc.x += __shfl_xor(acc.x, 16); acc.y += __shfl_xor(acc.y, 16);
  acc.z += __shfl_xor(acc.z, 16); acc.w += __shfl_xor(acc.w, 16);
  acc.x += __shfl_xor(acc.x, 32); acc.y += __shfl_xor(acc.y, 32);
  acc.z += __shfl_xor(acc.z, 32); acc.w += __shfl_xor(acc.w, 32);
  if ((threadIdx.x & 63) < 16) red[wid][lane] = acc;
  __syncthreads();
  if (threadIdx.x < 16) {
    int c4 = half * 16 + threadIdx.x;
    float4 a2 = f4add(f4add(red[0][threadIdx.x], red[1][threadIdx.x]),
                      f4add(red[2][threadIdx.x], red[3][threadIdx.x]));
    float scn = Dinv[n] * (1.f / H);
    float4 scB, shB;
    bn_sc4(st, g, be, ninv, c4, scB, shB);
    float4 hr = hres4[(size_t)n * 32 + c4];
    hr = make_float4(hr.x * scB.x + shB.x, hr.y * scB.y + shB.y, hr.z * scB.z + shB.z,
                     hr.w * scB.w + shB.w);
    float4 bi = ((const float4*)bias)[c4];
    out4[(size_t)n * 32 + c4] =
        make_float4(hr.x + scn * a2.x + bi.x, hr.y + scn * a2.y + bi.y,
                    hr.z + scn * a2.z + bi.z, hr.w + scn * a2.w + bi.w);
  }
}

// ---------------------------------------------------------------------------
// Host side
// ---------------------------------------------------------------------------
static inline size_t alignup(size_t x) { return (x + 255) & ~(size_t)255; }

extern "C" void kernel_launch(void* const* d_in, const int* in_sizes, int n_in,
                              void* d_out, int out_size, void* d_ws, size_t ws_size,
                              hipStream_t stream) {
  const float* x = (const float*)d_in[0];
  const int* node_idx = (const int*)d_in[1];
  const int* edge_idx = (const int*)d_in[2];
  const float* wedge = (const float*)d_in[3];
  const float* W1 = (const float*)d_in[4];
  const float* b1 = (const float*)d_in[5];
  const float* g1 = (const float*)d_in[6];
  const float* be1 = (const float*)d_in[7];
  const float* linw1 = (const float*)d_in[8];
  const float* att1 = (const float*)d_in[9];
  const float* bias1 = (const float*)d_in[10];
  const float* g2 = (const float*)d_in[11];
  const float* be2 = (const float*)d_in[12];
  const float* linw2 = (const float*)d_in[13];
  const float* att2 = (const float*)d_in[14];
  const float* bias2 = (const float*)d_in[15];
  const float* g3 = (const float*)d_in[16];
  const float* be3 = (const float*)d_in[17];
  const float* W2 = (const float*)d_in[18];
  const float* b2 = (const float*)d_in[19];
  const float* g4 = (const float*)d_in[20];
  const float* be4 = (const float*)d_in[21];
  float* out = (float*)d_out;

  char* ws = (char*)d_ws;
  size_t off = 0;
  auto alloc = [&](size_t bytes) -> void* {
    void* p = ws + off;
    off = alignup(off + bytes);
    return p;
  };
  float* buf0 = (float*)alloc((size_t)NN * 128 * 4);
  float* buf1 = (float*)alloc((size_t)NN * 128 * 4);
  float* Tbuf = (float*)alloc((size_t)4 * MM * 128 * 4);
  float* oute = (float*)alloc((size_t)MM * 4 * 128 * 4);
  float* alpha = (float*)alloc((size_t)EE * 4 * 4);
  float* dotx = (float*)alloc((size_t)NN * 4 * 4);
  float* hv = (float*)alloc((size_t)NN * 4 * 4);
  float* dota = (float*)alloc((size_t)MM * 4 * 4);
  float* UVT = (float*)alloc(128 * 8 * 4);
  float* Dinv = (float*)alloc((size_t)NN * 4);
  int* noff = (int*)alloc((size_t)(NN + 1) * 4);
  int* eoff = (int*)alloc((size_t)(MM + 1) * 4);
  int* em_n = (int*)alloc((size_t)EE * 4);
  int2* npos_e = (int2*)alloc((size_t)EE * 8);
  // one contiguous zero region: ncnt, ecnt, ncur, ecur, bnst(4x256)
  size_t zero_bytes = ((size_t)(2 * NN + 2 * MM) + 4 * 256) * 4;
  int* zero_region = (int*)alloc(zero_bytes);
  int* ncnt = zero_region;
  int* ecnt = ncnt + NN;
  int* ncur = ecnt + MM;
  int* ecur = ncur + NN;
  float* bnst = (float*)(ecur + MM);
  (void)ws_size;
  (void)in_sizes;
  (void)n_in;
  (void)out_size;

  (void)hipMemsetAsync(zero_region, 0, zero_bytes, stream);

  // CSR build
  k_count<<<(EE + 255) / 256, 256, 0, stream>>>(node_idx, edge_idx, ncnt, ecnt);
  k_scan<<<1, 1024, 0, stream>>>(ncnt, noff, NN);
  k_scan<<<1, 1024, 0, stream>>>(ecnt, eoff, MM);
  k_fill<<<(EE + 255) / 256, 256, 0, stream>>>(node_idx, edge_idx, noff, eoff, ncur,
                                               ecur, em_n, npos_e);

  const float ninv = 1.f / (float)NN;
  const int gemm_grid = (NN + 63) / 64;
  const int cs_grid = (NN + 255) / 256;
  float* st0 = bnst + 0 * 256;
  float* st1 = bnst + 1 * 256;
  float* st2 = bnst + 2 * 256;
  float* st3 = bnst + 3 * 256;

  // buf0 = leaky(x@W1+b1) (raw pre-BN1)
  k_gemm128<<<gemm_grid, 256, 0, stream>>>(x, W1, b1, nullptr, nullptr, nullptr,
                                           nullptr, 0.f, buf0, NN);
  k_colstats<<<cs_grid, 256, 0, stream>>>((const float4*)buf0, NN, st0);

  // ---- hconv1 (H=4): h1 = BN1(buf0) applied inline ----
  k_uv<4><<<2, 256, 0, stream>>>(linw1, att1, UVT);
  k_dots<4><<<(NN * 8 + 255) / 256, 256, 0, stream>>>((const float4*)buf0, NN, UVT,
                                                      st0, g1, be1, ninv, dotx, hv);
  k_dota<4><<<MM / 4, 256, 0, stream>>>(hv, eoff, npos_e, dota);
  k_softmax<4><<<NN / 4, 256, 0, stream>>>(noff, em_n, dotx, dota, wedge, alpha, Dinv);
  {
    dim3 g(MM, 2);
    k_T<4><<<g, 256, 0, stream>>>((const float4*)buf0, eoff, npos_e, alpha, st0, g1,
                                  be1, ninv, (float4*)Tbuf);
  }
  {
    dim3 g((MM + 63) / 64, 4);
    k_oute64<4><<<g, 256, 0, stream>>>(Tbuf, linw1, eoff, wedge, oute);
  }
  {
    dim3 g(NN, 2);
    k_phase9<4><<<g, 256, 0, stream>>>(noff, em_n, alpha, (const float4*)oute, Dinv,
                                       bias1, (const float4*)buf0, st0, g1, be1, ninv,
                                       (float4*)buf1);
  }
  k_colstats<<<cs_grid, 256, 0, stream>>>((const float4*)buf1, NN, st1);

  // ---- hconv2 (H=1): h2 = BN2(buf1) applied inline ----
  k_uv<1><<<1, 256, 0, stream>>>(linw2, att2, UVT);
  k_dots<1><<<(NN * 2 + 255) / 256, 256, 0, stream>>>((const float4*)buf1, NN, UVT,
                                                      st1, g2, be2, ninv, dotx, hv);
  k_dota<1><<<MM / 4, 256, 0, stream>>>(hv, eoff, npos_e, dota);
  k_softmax<1><<<NN / 4, 256, 0, stream>>>(noff, em_n, dotx, dota, wedge, alpha, Dinv);
  {
    dim3 g(MM, 2);
    k_T<1><<<g, 256, 0, stream>>>((const float4*)buf1, eoff, npos_e, alpha, st1, g2,
                                  be2, ninv, (float4*)Tbuf);
  }
  {
    dim3 g((MM + 63) / 64, 1);
    k_oute64<1><<<g, 256, 0, stream>>>(Tbuf, linw2, eoff, wedge, oute);
  }
  {
    dim3 g(NN, 2);
    k_phase9<1><<<g, 256, 0, stream>>>(noff, em_n, alpha, (const float4*)oute, Dinv,
                                       bias2, (const float4*)buf1, st1, g2, be2, ninv,
                                       (float4*)buf0);
  }
  k_colstats<<<cs_grid, 256, 0, stream>>>((const float4*)buf0, NN, st2);

  // buf1 = leaky(BN3(buf0)@W2+b2) + x  (raw pre-BN4)
  k_gemm128<<<gemm_grid, 256, 0, stream>>>(buf0, W2, b2, x, st2, g3, be3, ninv, buf1,
                                           NN);
  k_colstats<<<cs_grid, 256, 0, stream>>>((const float4*)buf1, NN, st3);
  k_bnapply_final<<<(NN * 32 + 255) / 256, 256, 0, stream>>>(
      (const float4*)buf1, st3, g4, be4, ninv, (float4*)out, NN * 32);
}

// Round 5
// 351.046 us; speedup vs baseline: 2.6636x; 1.3384x over previous
//
#include <hip/hip_runtime.h>

// Problem constants (match reference)
#define NN 20000
#define MM 2000
#define EE 320000
static constexpr float SLOPE = 0.2f;
static constexpr float EPSBN = 1e-5f;

__device__ inline float4 f4add(float4 a, float4 b) {
  return make_float4(a.x + b.x, a.y + b.y, a.z + b.z, a.w + b.w);
}
__device__ inline float4 f4fma(float a, float4 v, float4 c) {
  return make_float4(c.x + a * v.x, c.y + a * v.y, c.z + a * v.z, c.w + a * v.w);
}
__device__ inline float leaky(float v) { return (v > 0.f) ? v : SLOPE * v; }

// per-thread BN scale/shift for 4 channels (f4 index c4)
__device__ inline void bn_sc4(const float* __restrict__ st, const float* __restrict__ g,
                              const float* __restrict__ be, float ninv, int c4,
                              float4& sc, float4& sh) {
  float* scp = &sc.x;
  float* shp = &sh.x;
#pragma unroll
  for (int j = 0; j < 4; j++) {
    int c = c4 * 4 + j;
    float mu = st[c] * ninv;
    float var = st[128 + c] * ninv - mu * mu;
    float s = g[c] * rsqrtf(var + EPSBN);
    scp[j] = s;
    shp[j] = be[c] - mu * s;
  }
}

// ---------------------------------------------------------------------------
// CSR build: count + capture per-incidence rank (atomic return value)
// ---------------------------------------------------------------------------
__global__ void k_count(const int* __restrict__ ni, const int* __restrict__ ei,
                        int* ncnt, int* ecnt, int* __restrict__ rank_n,
                        int* __restrict__ rank_e) {
  int e = blockIdx.x * 256 + threadIdx.x;
  if (e >= EE) return;
  rank_n[e] = atomicAdd(&ncnt[ni[e]], 1);
  rank_e[e] = atomicAdd(&ecnt[ei[e]], 1);
}

// single-block exclusive scan, shfl-based
__global__ __launch_bounds__(1024) void k_scan(const int* __restrict__ cnt,
                                               int* __restrict__ off, int n) {
  __shared__ int swav[16];
  __shared__ int sCarry;
  int t = threadIdx.x;
  int lane = t & 63, wid = t >> 6;
  if (t == 0) sCarry = 0;
  __syncthreads();
  for (int base = 0; base < n; base += 1024) {
    int i = base + t;
    int v = (i < n) ? cnt[i] : 0;
    int x = v;
#pragma unroll
    for (int o = 1; o < 64; o <<= 1) {
      int y = __shfl_up(x, o);
      if (lane >= o) x += y;
    }
    if (lane == 63) swav[wid] = x;
    __syncthreads();
    if (wid == 0) {
      int s = (lane < 16) ? swav[lane] : 0;
#pragma unroll
      for (int o = 1; o < 16; o <<= 1) {
        int y = __shfl_up(s, o);
        if (lane >= o) s += y;
      }
      if (lane < 16) swav[lane] = s;
    }
    __syncthreads();
    int wpre = wid ? swav[wid - 1] : 0;
    int total = swav[15];
    if (i < n) off[i] = sCarry + wpre + x - v;
    __syncthreads();
    if (t == 0) sCarry += total;
    __syncthreads();
  }
  if (t == 0) off[n] = sCarry;
}

// atomic-free fill using precomputed ranks
__global__ void k_fill(const int* __restrict__ ni, const int* __restrict__ ei,
                       const int* __restrict__ noff, const int* __restrict__ eoff,
                       const int* __restrict__ rank_n, const int* __restrict__ rank_e,
                       int* __restrict__ em_n, int2* __restrict__ npos_e) {
  int e = blockIdx.x * 256 + threadIdx.x;
  if (e >= EE) return;
  int n = ni[e];
  int m = ei[e];
  int pn = noff[n] + rank_n[e];
  int pe = eoff[m] + rank_e[e];
  em_n[pn] = m;
  npos_e[pe] = make_int2(n, pn);
}

// ---------------------------------------------------------------------------
// Tiled GEMM: out = maybe_resid + leaky(BNopt(A)[rows,128] @ W[128,128] + b)
// Fused column stats (sum,sumsq) of the OUTPUT -> atomicAdd into stout.
// ---------------------------------------------------------------------------
__global__ __launch_bounds__(256) void k_gemm128(
    const float* __restrict__ A, const float* __restrict__ W,
    const float* __restrict__ bias, const float* __restrict__ resid,
    const float* __restrict__ st, const float* __restrict__ g,
    const float* __restrict__ be, float ninv, float* __restrict__ out,
    float* __restrict__ stout, int rows) {
  __shared__ float As[32][68];
  __shared__ float Ws[32][132];
  __shared__ float scs[128], shs[128];
  if (st && threadIdx.x < 128) {
    int c = threadIdx.x;
    float mu = st[c] * ninv;
    float var = st[128 + c] * ninv - mu * mu;
    float s = g[c] * rsqrtf(var + EPSBN);
    scs[c] = s;
    shs[c] = be[c] - mu * s;
  }
  if (st) __syncthreads();
  int tx = threadIdx.x & 15, ty = threadIdx.x >> 4;
  int r0 = blockIdx.x * 64;
  float4 acc[4][2];
#pragma unroll
  for (int j = 0; j < 4; j++) acc[j][0] = acc[j][1] = make_float4(0.f, 0.f, 0.f, 0.f);

  for (int k0 = 0; k0 < 128; k0 += 32) {
    __syncthreads();
    {
      int row = threadIdx.x >> 2, kq = threadIdx.x & 3;
      int rr = r0 + row;
      float4 a0 = make_float4(0.f, 0.f, 0.f, 0.f), a1 = a0;
      if (rr < rows) {
        const float* ap = A + (size_t)rr * 128 + k0 + kq * 8;
        a0 = ((const float4*)ap)[0];
        a1 = ((const float4*)ap)[1];
      }
      int kb = k0 + kq * 8;
      if (st) {
        a0.x = a0.x * scs[kb + 0] + shs[kb + 0];
        a0.y = a0.y * scs[kb + 1] + shs[kb + 1];
        a0.z = a0.z * scs[kb + 2] + shs[kb + 2];
        a0.w = a0.w * scs[kb + 3] + shs[kb + 3];
        a1.x = a1.x * scs[kb + 4] + shs[kb + 4];
        a1.y = a1.y * scs[kb + 5] + shs[kb + 5];
        a1.z = a1.z * scs[kb + 6] + shs[kb + 6];
        a1.w = a1.w * scs[kb + 7] + shs[kb + 7];
      }
      int kl = kq * 8;
      As[kl + 0][row] = a0.x;
      As[kl + 1][row] = a0.y;
      As[kl + 2][row] = a0.z;
      As[kl + 3][row] = a0.w;
      As[kl + 4][row] = a1.x;
      As[kl + 5][row] = a1.y;
      As[kl + 6][row] = a1.z;
      As[kl + 7][row] = a1.w;
    }
    {
      int kk = threadIdx.x >> 3, cq = threadIdx.x & 7;
      const float* wp = W + (size_t)(k0 + kk) * 128 + cq * 16;
#pragma unroll
      for (int f = 0; f < 4; f++)
        *(float4*)&Ws[kk][cq * 16 + f * 4] = ((const float4*)wp)[f];
    }
    __syncthreads();
#pragma unroll
    for (int kk = 0; kk < 32; kk++) {
      float4 a = *(const float4*)&As[kk][ty * 4];
      float4 w0 = *(const float4*)&Ws[kk][tx * 8];
      float4 w1 = *(const float4*)&Ws[kk][tx * 8 + 4];
      acc[0][0] = f4fma(a.x, w0, acc[0][0]);
      acc[0][1] = f4fma(a.x, w1, acc[0][1]);
      acc[1][0] = f4fma(a.y, w0, acc[1][0]);
      acc[1][1] = f4fma(a.y, w1, acc[1][1]);
      acc[2][0] = f4fma(a.z, w0, acc[2][0]);
      acc[2][1] = f4fma(a.z, w1, acc[2][1]);
      acc[3][0] = f4fma(a.w, w0, acc[3][0]);
      acc[3][1] = f4fma(a.w, w1, acc[3][1]);
    }
  }
  float4 b0 = ((const float4*)bias)[tx * 2];
  float4 b1 = ((const float4*)bias)[tx * 2 + 1];
  float4 cs0 = make_float4(0.f, 0.f, 0.f, 0.f), cs1 = cs0, cq0 = cs0, cq1 = cs0;
#pragma unroll
  for (int j = 0; j < 4; j++) {
    int r = r0 + ty * 4 + j;
    if (r < rows) {
      float4 o0 = acc[j][0], o1 = acc[j][1];
      o0 = make_float4(leaky(o0.x + b0.x), leaky(o0.y + b0.y), leaky(o0.z + b0.z),
                       leaky(o0.w + b0.w));
      o1 = make_float4(leaky(o1.x + b1.x), leaky(o1.y + b1.y), leaky(o1.z + b1.z),
                       leaky(o1.w + b1.w));
      if (resid) {
        float4 r0v = ((const float4*)resid)[(size_t)r * 32 + tx * 2];
        float4 r1v = ((const float4*)resid)[(size_t)r * 32 + tx * 2 + 1];
        o0 = f4add(o0, r0v);
        o1 = f4add(o1, r1v);
      }
      ((float4*)out)[(size_t)r * 32 + tx * 2] = o0;
      ((float4*)out)[(size_t)r * 32 + tx * 2 + 1] = o1;
      cs0 = f4add(cs0, o0);
      cs1 = f4add(cs1, o1);
      cq0 = make_float4(cq0.x + o0.x * o0.x, cq0.y + o0.y * o0.y, cq0.z + o0.z * o0.z,
                        cq0.w + o0.w * o0.w);
      cq1 = make_float4(cq1.x + o1.x * o1.x, cq1.y + o1.y * o1.y, cq1.z + o1.z * o1.z,
                        cq1.w + o1.w * o1.w);
    }
  }
  // fused column stats: reuse As (sum) / Ws (sumsq) LDS as [16][128]
  __syncthreads();
  float* sumb = &As[0][0];
  float* sqb = &Ws[0][0];
  *(float4*)&sumb[ty * 128 + tx * 8] = cs0;
  *(float4*)&sumb[ty * 128 + tx * 8 + 4] = cs1;
  *(float4*)&sqb[ty * 128 + tx * 8] = cq0;
  *(float4*)&sqb[ty * 128 + tx * 8 + 4] = cq1;
  __syncthreads();
  if (threadIdx.x < 128) {
    float S = 0.f, Q = 0.f;
#pragma unroll
    for (int w = 0; w < 16; w++) {
      S += sumb[w * 128 + threadIdx.x];
      Q += sqb[w * 128 + threadIdx.x];
    }
    atomicAdd(&stout[threadIdx.x], S);
    atomicAdd(&stout[128 + threadIdx.x], Q);
  }
}

// out_e[m][h][c] = (wedge[m]/deg) * (T[h][m][:] @ lin_w[:, h*128 + c])
template <int H>
__global__ __launch_bounds__(256) void k_oute64(const float* __restrict__ T,
                                                const float* __restrict__ linw,
                                                const int* __restrict__ eoff,
                                                const float* __restrict__ wedge,
                                                float* __restrict__ oute) {
  int h = blockIdx.y;
  __shared__ float As[32][68];
  __shared__ float Ws[32][132];
  int tx = threadIdx.x & 15, ty = threadIdx.x >> 4;
  int r0 = blockIdx.x * 64;
  const float* A = T + (size_t)h * MM * 128;
  float4 acc[4][2];
#pragma unroll
  for (int j = 0; j < 4; j++) acc[j][0] = acc[j][1] = make_float4(0.f, 0.f, 0.f, 0.f);

  for (int k0 = 0; k0 < 128; k0 += 32) {
    __syncthreads();
    {
      int row = threadIdx.x >> 2, kq = threadIdx.x & 3;
      int rr = r0 + row;
      float4 a0 = make_float4(0.f, 0.f, 0.f, 0.f), a1 = a0;
      if (rr < MM) {
        const float* ap = A + (size_t)rr * 128 + k0 + kq * 8;
        a0 = ((const float4*)ap)[0];
        a1 = ((const float4*)ap)[1];
      }
      int kb = kq * 8;
      As[kb + 0][row] = a0.x;
      As[kb + 1][row] = a0.y;
      As[kb + 2][row] = a0.z;
      As[kb + 3][row] = a0.w;
      As[kb + 4][row] = a1.x;
      As[kb + 5][row] = a1.y;
      As[kb + 6][row] = a1.z;
      As[kb + 7][row] = a1.w;
    }
    {
      int kk = threadIdx.x >> 3, cq = threadIdx.x & 7;
      const float* wp = linw + (size_t)(k0 + kk) * (128 * H) + h * 128 + cq * 16;
#pragma unroll
      for (int f = 0; f < 4; f++)
        *(float4*)&Ws[kk][cq * 16 + f * 4] = ((const float4*)wp)[f];
    }
    __syncthreads();
#pragma unroll
    for (int kk = 0; kk < 32; kk++) {
      float4 a = *(const float4*)&As[kk][ty * 4];
      float4 w0 = *(const float4*)&Ws[kk][tx * 8];
      float4 w1 = *(const float4*)&Ws[kk][tx * 8 + 4];
      acc[0][0] = f4fma(a.x, w0, acc[0][0]);
      acc[0][1] = f4fma(a.x, w1, acc[0][1]);
      acc[1][0] = f4fma(a.y, w0, acc[1][0]);
      acc[1][1] = f4fma(a.y, w1, acc[1][1]);
      acc[2][0] = f4fma(a.z, w0, acc[2][0]);
      acc[2][1] = f4fma(a.z, w1, acc[2][1]);
      acc[3][0] = f4fma(a.w, w0, acc[3][0]);
      acc[3][1] = f4fma(a.w, w1, acc[3][1]);
    }
  }
#pragma unroll
  for (int j = 0; j < 4; j++) {
    int m = r0 + ty * 4 + j;
    if (m >= MM) break;
    int d = eoff[m + 1] - eoff[m];
    float bv = (d > 0) ? wedge[m] / (float)d : 0.f;
    float4 o0 = acc[j][0], o1 = acc[j][1];
    o0 = make_float4(bv * o0.x, bv * o0.y, bv * o0.z, bv * o0.w);
    o1 = make_float4(bv * o1.x, bv * o1.y, bv * o1.z, bv * o1.w);
    ((float4*)oute)[((size_t)m * H + h) * 32 + tx * 2] = o0;
    ((float4*)oute)[((size_t)m * H + h) * 32 + tx * 2 + 1] = o1;
  }
}

// ---------------------------------------------------------------------------
// BatchNorm column stats (sum, sumsq) -- standalone (for phase9 outputs)
// ---------------------------------------------------------------------------
__global__ __launch_bounds__(256) void k_colstats(const float4* __restrict__ X4,
                                                  int rows, float* __restrict__ st) {
  int c4 = threadIdx.x & 31, rs = threadIdx.x >> 5, wid = threadIdx.x >> 6;
  int r0 = blockIdx.x * 256;
  int rend = min(r0 + 256, rows);
  float4 s = make_float4(0.f, 0.f, 0.f, 0.f), q = s;
  for (int r = r0 + rs; r < rend; r += 8) {
    float4 v = X4[(size_t)r * 32 + c4];
    s = f4add(s, v);
    q = make_float4(q.x + v.x * v.x, q.y + v.y * v.y, q.z + v.z * v.z, q.w + v.w * v.w);
  }
  s.x += __shfl_xor(s.x, 32); s.y += __shfl_xor(s.y, 32);
  s.z += __shfl_xor(s.z, 32); s.w += __shfl_xor(s.w, 32);
  q.x += __shfl_xor(q.x, 32); q.y += __shfl_xor(q.y, 32);
  q.z += __shfl_xor(q.z, 32); q.w += __shfl_xor(q.w, 32);
  __shared__ float4 red[4][32][2];
  if ((threadIdx.x & 63) < 32) {
    red[wid][c4][0] = s;
    red[wid][c4][1] = q;
  }
  __syncthreads();
  if (threadIdx.x < 32) {
    float4 S = f4add(f4add(red[0][threadIdx.x][0], red[1][threadIdx.x][0]),
                     f4add(red[2][threadIdx.x][0], red[3][threadIdx.x][0]));
    float4 Q = f4add(f4add(red[0][threadIdx.x][1], red[1][threadIdx.x][1]),
                     f4add(red[2][threadIdx.x][1], red[3][threadIdx.x][1]));
    int c = threadIdx.x * 4;
    atomicAdd(&st[c + 0], S.x);
    atomicAdd(&st[c + 1], S.y);
    atomicAdd(&st[c + 2], S.z);
    atomicAdd(&st[c + 3], S.w);
    atomicAdd(&st[128 + c + 0], Q.x);
    atomicAdd(&st[128 + c + 1], Q.y);
    atomicAdd(&st[128 + c + 2], Q.z);
    atomicAdd(&st[128 + c + 3], Q.w);
  }
}

// final: out = BN(X) computed from raw stats
__global__ void k_bnapply_final(const float4* __restrict__ X4,
                                const float* __restrict__ st,
                                const float* __restrict__ g,
                                const float* __restrict__ be, float ninv,
                                float4* __restrict__ Y4, int total4) {
  int i = blockIdx.x * 256 + threadIdx.x;
  if (i >= total4) return;
  int c4 = i & 31;
  float4 sc, sh;
  bn_sc4(st, g, be, ninv, c4, sc, sh);
  float4 v = X4[i];
  Y4[i] = make_float4(v.x * sc.x + sh.x, v.y * sc.y + sh.y, v.z * sc.z + sh.z,
                      v.w * sc.w + sh.w);
}

// ---------------------------------------------------------------------------
// UVT[h2][k]: h2<H -> U (x-side att), h2>=H -> V (attr-side att)
// ---------------------------------------------------------------------------
template <int H>
__global__ void k_uv(const float* __restrict__ linw, const float* __restrict__ att,
                     float* __restrict__ UVT) {
  int idx = blockIdx.x * 256 + threadIdx.x;
  if (idx >= 128 * H) return;
  int h = idx >> 7, k = idx & 127;
  float u = 0.f, v = 0.f;
  for (int c = 0; c < 128; c++) {
    float w = linw[(size_t)k * (128 * H) + h * 128 + c];
    u += w * att[h * 256 + c];
    v += w * att[h * 256 + 128 + c];
  }
  UVT[h * 128 + k] = u;
  UVT[(H + h) * 128 + k] = v;
}

// dotx[n,h] = BN(X)[n,:] . U[:,h] ; hv[n,h] = BN(X)[n,:] . V[:,h]
template <int H>
__global__ void k_dots(const float4* __restrict__ X4, int rows,
                       const float* __restrict__ UVT, const float* __restrict__ st,
                       const float* __restrict__ g, const float* __restrict__ be,
                       float ninv, float* __restrict__ dotx, float* __restrict__ hv) {
  __shared__ float4 Ut[2 * H * 32];
  __shared__ float4 scl[32], shl[32];
  if (threadIdx.x < 32) {
    float4 sc, sh;
    bn_sc4(st, g, be, ninv, threadIdx.x, sc, sh);
    scl[threadIdx.x] = sc;
    shl[threadIdx.x] = sh;
  }
  for (int i = threadIdx.x; i < 2 * H * 32; i += 256) Ut[i] = ((const float4*)UVT)[i];
  __syncthreads();
  int idx = blockIdx.x * 256 + threadIdx.x;
  if (idx >= rows * 2 * H) return;
  int n = idx / (2 * H), h2 = idx - n * (2 * H);
  const float4* xr = X4 + (size_t)n * 32;
  const float4* ur = Ut + h2 * 32;
  float s = 0.f;
#pragma unroll 8
  for (int q = 0; q < 32; q++) {
    float4 a = xr[q], b = ur[q], c = scl[q], d = shl[q];
    float ax = a.x * c.x + d.x, ay = a.y * c.y + d.y;
    float az = a.z * c.z + d.z, aw = a.w * c.w + d.w;
    s += ax * b.x + ay * b.y + az * b.z + aw * b.w;
  }
  if (h2 < H)
    dotx[n * H + h2] = s;
  else
    hv[n * H + (h2 - H)] = s;
}

// dota[m,h] = sum over incidences of edge m of hv[node, h]
template <int H>
__global__ void k_dota(const float* __restrict__ hv, const int* __restrict__ eoff,
                       const int2* __restrict__ npos_e, float* __restrict__ dota) {
  int lane = threadIdx.x & 63;
  int m = blockIdx.x * 4 + (threadIdx.x >> 6);
  int s = eoff[m], t = eoff[m + 1];
  if (H == 4) {
    float4 acc = make_float4(0.f, 0.f, 0.f, 0.f);
    const float4* hv4 = (const float4*)hv;
    for (int j = s + lane; j < t; j += 64) acc = f4add(acc, hv4[npos_e[j].x]);
#pragma unroll
    for (int o = 32; o >= 1; o >>= 1) {
      acc.x += __shfl_xor(acc.x, o);
      acc.y += __shfl_xor(acc.y, o);
      acc.z += __shfl_xor(acc.z, o);
      acc.w += __shfl_xor(acc.w, o);
    }
    if (lane == 0) ((float4*)dota)[m] = acc;
  } else {
    float acc = 0.f;
    for (int j = s + lane; j < t; j += 64) acc += hv[npos_e[j].x];
#pragma unroll
    for (int o = 32; o >= 1; o >>= 1) acc += __shfl_xor(acc, o);
    if (lane == 0) dota[m] = acc;
  }
}

// ---------------------------------------------------------------------------
// Per-node segment softmax; alpha stored in node-CSR order.
// ---------------------------------------------------------------------------
template <int H>
__global__ void k_softmax(const int* __restrict__ noff, const int* __restrict__ em_n,
                          const float* __restrict__ dotx, const float* __restrict__ dota,
                          const float* __restrict__ wedge, float* __restrict__ alpha,
                          float* __restrict__ Dinv) {
  int lane = threadIdx.x & 63;
  int n = blockIdx.x * 4 + (threadIdx.x >> 6);
  int s = noff[n], t = noff[n + 1];
  int deg = t - s;
  int h = lane & (H - 1);
  float dx = dotx[n * H + h];
  if (deg <= 64) {
    int em0 = 0;
    float dd = 0.f;
    if (lane < deg) {
      em0 = em_n[s + lane];
      dd = wedge[em0];
    }
#pragma unroll
    for (int o = 32; o >= 1; o >>= 1) dd += __shfl_xor(dd, o);
    if (lane == 0) Dinv[n] = (dd > 0.f) ? 1.f / dd : 0.f;

    constexpr int KMAX = (H == 4) ? 4 : 1;
    int P = deg * H;
    float vc[KMAX];
    float mx = -3.0e38f;
#pragma unroll
    for (int k = 0; k < KMAX; k++) {
      int p = lane + 64 * k;
      int idx = (H == 4) ? (p >> 2) : p;
      int em = __shfl(em0, idx);
      float v = dx + dota[em * H + h];
      v = leaky(v);
      vc[k] = v;
      if (p < P) mx = fmaxf(mx, v);
    }
#pragma unroll
    for (int o = H; o < 64; o <<= 1) mx = fmaxf(mx, __shfl_xor(mx, o));
    float sm = 0.f;
#pragma unroll
    for (int k = 0; k < KMAX; k++) {
      int p = lane + 64 * k;
      float e = __expf(vc[k] - mx);
      vc[k] = e;
      if (p < P) sm += e;
    }
#pragma unroll
    for (int o = H; o < 64; o <<= 1) sm += __shfl_xor(sm, o);
    float inv = 1.f / (sm + 1e-16f);
#pragma unroll
    for (int k = 0; k < KMAX; k++) {
      int p = lane + 64 * k;
      if (p < P) alpha[s * H + p] = vc[k] * inv;
    }
  } else {
    float dd = 0.f;
    for (int i = s + lane; i < t; i += 64) dd += wedge[em_n[i]];
#pragma unroll
    for (int o = 32; o >= 1; o >>= 1) dd += __shfl_xor(dd, o);
    if (lane == 0) Dinv[n] = (dd > 0.f) ? 1.f / dd : 0.f;
    int P = deg * H;
    float mx = -3.0e38f;
    for (int p = lane; p < P; p += 64) {
      int i = s + ((H == 4) ? (p >> 2) : p);
      float v = leaky(dx + dota[em_n[i] * H + h]);
      mx = fmaxf(mx, v);
    }
#pragma unroll
    for (int o = H; o < 64; o <<= 1) mx = fmaxf(mx, __shfl_xor(mx, o));
    float sm = 0.f;
    for (int p = lane; p < P; p += 64) {
      int i = s + ((H == 4) ? (p >> 2) : p);
      float v = leaky(dx + dota[em_n[i] * H + h]);
      sm += __expf(v - mx);
    }
#pragma unroll
    for (int o = H; o < 64; o <<= 1) sm += __shfl_xor(sm, o);
    float inv = 1.f / (sm + 1e-16f);
    for (int p = lane; p < P; p += 64) {
      int i = s + ((H == 4) ? (p >> 2) : p);
      float v = leaky(dx + dota[em_n[i] * H + h]);
      alpha[s * H + p] = __expf(v - mx) * inv;
    }
  }
}

// ---------------------------------------------------------------------------
// T[h][m][c] = sc_c * (sum alpha * raw[node,c]) + sh_c * (sum alpha)
// BN factored out of the gather loop; packed LDS stage of {rowofs, alpha}.
// 8 slots x 32 lanes, block per edge m.
// ---------------------------------------------------------------------------
template <int H>
__global__ __launch_bounds__(256) void k_T(const float4* __restrict__ h4raw,
                                           const int* __restrict__ eoff,
                                           const int2* __restrict__ npos_e,
                                           const float* __restrict__ alpha,
                                           const float* __restrict__ st,
                                           const float* __restrict__ g,
                                           const float* __restrict__ be, float ninv,
                                           float4* __restrict__ T4) {
  int m = blockIdx.x;
  int slot = threadIdx.x >> 5, c = threadIdx.x & 31;
  int wv = threadIdx.x >> 6;
  int s = eoff[m], t = eoff[m + 1];
  __shared__ int sofs[256];
  __shared__ float sal[256 * H];
  __shared__ float4 red[4][H][32];
  __shared__ float4 redA[4];
  __shared__ float sAsum[4];
  float4 acc[H];
#pragma unroll
  for (int hh = 0; hh < H; hh++) acc[hh] = make_float4(0.f, 0.f, 0.f, 0.f);
  float4 asum = make_float4(0.f, 0.f, 0.f, 0.f);  // per-thread staged-alpha sum

  for (int c0 = s; c0 < t; c0 += 256) {
    int cnt = min(256, t - c0);
    __syncthreads();
    if (threadIdx.x < cnt) {
      int2 np = npos_e[c0 + threadIdx.x];
      sofs[threadIdx.x] = np.x * 32;
      if (H == 4) {
        float4 a4 = ((const float4*)alpha)[np.y];
        ((float4*)sal)[threadIdx.x] = a4;
        asum = f4add(asum, a4);
      } else {
        float a = alpha[np.y];
        sal[threadIdx.x] = a;
        asum.x += a;
      }
    }
    __syncthreads();
#pragma unroll 4
    for (int j = slot; j < cnt; j += 8) {
      int ofs = sofs[j];
      float4 v = h4raw[(size_t)ofs + c];
      if (H == 4) {
        float4 a4 = ((const float4*)sal)[j];
        acc[0] = f4fma(a4.x, v, acc[0]);
        acc[1 % H] = f4fma(a4.y, v, acc[1 % H]);
        acc[2 % H] = f4fma(a4.z, v, acc[2 % H]);
        acc[3 % H] = f4fma(a4.w, v, acc[3 % H]);
      } else {
        acc[0] = f4fma(sal[j], v, acc[0]);
      }
    }
  }
  // reduce acc over slots: pair via shfl, cross-wave via LDS
#pragma unroll
  for (int hh = 0; hh < H; hh++) {
    float4 a = acc[hh];
    a.x += __shfl_xor(a.x, 32); a.y += __shfl_xor(a.y, 32);
    a.z += __shfl_xor(a.z, 32); a.w += __shfl_xor(a.w, 32);
    acc[hh] = a;
  }
  // reduce asum over all 64 lanes of each wave
#pragma unroll
  for (int o = 32; o >= 1; o >>= 1) {
    asum.x += __shfl_xor(asum.x, o); asum.y += __shfl_xor(asum.y, o);
    asum.z += __shfl_xor(asum.z, o); asum.w += __shfl_xor(asum.w, o);
  }
  if ((threadIdx.x & 63) < 32) {
#pragma unroll
    for (int hh = 0; hh < H; hh++) red[wv][hh][c] = acc[hh];
  }
  if ((threadIdx.x & 63) == 0) redA[wv] = asum;
  __syncthreads();
  if (threadIdx.x == 0) {
    float4 A = f4add(f4add(redA[0], redA[1]), f4add(redA[2], redA[3]));
    sAsum[0] = A.x; sAsum[1] = A.y; sAsum[2] = A.z; sAsum[3] = A.w;
  }
  __syncthreads();
  if (threadIdx.x < 32 * H) {
    int hh = threadIdx.x >> 5, cc = threadIdx.x & 31;
    float4 r = f4add(f4add(red[0][hh][cc], red[1][hh][cc]),
                     f4add(red[2][hh][cc], red[3][hh][cc]));
    float as = sAsum[hh];
    float4 sc, sh;
    bn_sc4(st, g, be, ninv, cc, sc, sh);
    r = make_float4(sc.x * r.x + sh.x * as, sc.y * r.y + sh.y * as,
                    sc.z * r.z + sh.z * as, sc.w * r.w + sh.w * as);
    T4[((size_t)hh * MM + m) * 32 + cc] = r;
  }
}

// ---------------------------------------------------------------------------
// out[n,c] = BN(hres)[n,c] + Dinv[n]/H * sum alpha*oute[m,h,c] + bias
// One WAVE per node, no LDS/barriers. Metadata in regs, shfl-distributed.
// H=4: the 4 head-rows of oute[m] are contiguous (2KB) -> 1 addr, 4 loads.
// ---------------------------------------------------------------------------
template <int H>
__global__ __launch_bounds__(256) void k_phase9(
    const int* __restrict__ noff, const int* __restrict__ em_n,
    const float* __restrict__ alpha, const float4* __restrict__ oute4,
    const float* __restrict__ Dinv, const float* __restrict__ bias,
    const float4* __restrict__ hres4, const float* __restrict__ st,
    const float* __restrict__ g, const float* __restrict__ be, float ninv,
    float4* __restrict__ out4) {
  int wv = threadIdx.x >> 6, lane = threadIdx.x & 63;
  int n = blockIdx.x * 4 + wv;
  int slot = lane >> 5, c = lane & 31;
  int s = noff[n], t = noff[n + 1];
  int deg = t - s;
  float4 acc = make_float4(0.f, 0.f, 0.f, 0.f);
  if (deg <= 64) {
    int m_l = 0;
    float4 a_l = make_float4(0.f, 0.f, 0.f, 0.f);
    if (lane < deg) {
      m_l = em_n[s + lane];
      if (H == 4)
        a_l = ((const float4*)alpha)[s + lane];
      else
        a_l.x = alpha[s + lane];
    }
    for (int i = slot; i < deg; i += 2) {
      int m = __shfl(m_l, i);
      if (H == 4) {
        float ax = __shfl(a_l.x, i), ay = __shfl(a_l.y, i);
        float az = __shfl(a_l.z, i), aw = __shfl(a_l.w, i);
        const float4* base = oute4 + (size_t)m * 128 + c;
        acc = f4fma(ax, base[0], acc);
        acc = f4fma(ay, base[32], acc);
        acc = f4fma(az, base[64], acc);
        acc = f4fma(aw, base[96], acc);
      } else {
        float a = __shfl(a_l.x, i);
        acc = f4fma(a, oute4[(size_t)m * 32 + c], acc);
      }
    }
  } else {
    for (int i = s + slot; i < t; i += 2) {
      int m = em_n[i];
      if (H == 4) {
        float4 a4 = ((const float4*)alpha)[i];
        const float4* base = oute4 + (size_t)m * 128 + c;
        acc = f4fma(a4.x, base[0], acc);
        acc = f4fma(a4.y, base[32], acc);
        acc = f4fma(a4.z, base[64], acc);
        acc = f4fma(a4.w, base[96], acc);
      } else {
        acc = f4fma(alpha[i], oute4[(size_t)m * 32 + c], acc);
      }
    }
  }
  acc.x += __shfl_xor(acc.x, 32); acc.y += __shfl_xor(acc.y, 32);
  acc.z += __shfl_xor(acc.z, 32); acc.w += __shfl_xor(acc.w, 32);
  if (slot == 0) {
    float scn = Dinv[n] * (1.f / H);
    float4 scB, shB;
    bn_sc4(st, g, be, ninv, c, scB, shB);
    float4 hr = hres4[(size_t)n * 32 + c];
    hr = make_float4(hr.x * scB.x + shB.x, hr.y * scB.y + shB.y, hr.z * scB.z + shB.z,
                     hr.w * scB.w + shB.w);
    float4 bi = ((const float4*)bias)[c];
    out4[(size_t)n * 32 + c] =
        make_float4(hr.x + scn * acc.x + bi.x, hr.y + scn * acc.y + bi.y,
                    hr.z + scn * acc.z + bi.z, hr.w + scn * acc.w + bi.w);
  }
}

// ---------------------------------------------------------------------------
// Host side
// ---------------------------------------------------------------------------
static inline size_t alignup(size_t x) { return (x + 255) & ~(size_t)255; }

extern "C" void kernel_launch(void* const* d_in, const int* in_sizes, int n_in,
                              void* d_out, int out_size, void* d_ws, size_t ws_size,
                              hipStream_t stream) {
  const float* x = (const float*)d_in[0];
  const int* node_idx = (const int*)d_in[1];
  const int* edge_idx = (const int*)d_in[2];
  const float* wedge = (const float*)d_in[3];
  const float* W1 = (const float*)d_in[4];
  const float* b1 = (const float*)d_in[5];
  const float* g1 = (const float*)d_in[6];
  const float* be1 = (const float*)d_in[7];
  const float* linw1 = (const float*)d_in[8];
  const float* att1 = (const float*)d_in[9];
  const float* bias1 = (const float*)d_in[10];
  const float* g2 = (const float*)d_in[11];
  const float* be2 = (const float*)d_in[12];
  const float* linw2 = (const float*)d_in[13];
  const float* att2 = (const float*)d_in[14];
  const float* bias2 = (const float*)d_in[15];
  const float* g3 = (const float*)d_in[16];
  const float* be3 = (const float*)d_in[17];
  const float* W2 = (const float*)d_in[18];
  const float* b2 = (const float*)d_in[19];
  const float* g4 = (const float*)d_in[20];
  const float* be4 = (const float*)d_in[21];
  float* out = (float*)d_out;

  char* ws = (char*)d_ws;
  size_t off = 0;
  auto alloc = [&](size_t bytes) -> void* {
    void* p = ws + off;
    off = alignup(off + bytes);
    return p;
  };
  float* buf0 = (float*)alloc((size_t)NN * 128 * 4);
  float* buf1 = (float*)alloc((size_t)NN * 128 * 4);
  float* Tbuf = (float*)alloc((size_t)4 * MM * 128 * 4);
  float* oute = (float*)alloc((size_t)MM * 4 * 128 * 4);
  float* alpha = (float*)alloc((size_t)EE * 4 * 4);
  float* dotx = (float*)alloc((size_t)NN * 4 * 4);
  float* hv = (float*)alloc((size_t)NN * 4 * 4);
  float* dota = (float*)alloc((size_t)MM * 4 * 4);
  float* UVT = (float*)alloc(128 * 8 * 4);
  float* Dinv = (float*)alloc((size_t)NN * 4);
  int* noff = (int*)alloc((size_t)(NN + 1) * 4);
  int* eoff = (int*)alloc((size_t)(MM + 1) * 4);
  int* em_n = (int*)alloc((size_t)EE * 4);
  int2* npos_e = (int2*)alloc((size_t)EE * 8);
  int* rank_n = (int*)alloc((size_t)EE * 4);
  int* rank_e = (int*)alloc((size_t)EE * 4);
  // zero region: ncnt, ecnt, bnst(4x256)
  size_t zero_bytes = ((size_t)(NN + MM) + 4 * 256) * 4;
  int* zero_region = (int*)alloc(zero_bytes);
  int* ncnt = zero_region;
  int* ecnt = ncnt + NN;
  float* bnst = (float*)(ecnt + MM);
  (void)ws_size;
  (void)in_sizes;
  (void)n_in;
  (void)out_size;

  (void)hipMemsetAsync(zero_region, 0, zero_bytes, stream);

  // CSR build
  k_count<<<(EE + 255) / 256, 256, 0, stream>>>(node_idx, edge_idx, ncnt, ecnt,
                                                rank_n, rank_e);
  k_scan<<<1, 1024, 0, stream>>>(ncnt, noff, NN);
  k_scan<<<1, 1024, 0, stream>>>(ecnt, eoff, MM);
  k_fill<<<(EE + 255) / 256, 256, 0, stream>>>(node_idx, edge_idx, noff, eoff, rank_n,
                                               rank_e, em_n, npos_e);

  const float ninv = 1.f / (float)NN;
  const int gemm_grid = (NN + 63) / 64;
  const int cs_grid = (NN + 255) / 256;
  float* st0 = bnst + 0 * 256;
  float* st1 = bnst + 1 * 256;
  float* st2 = bnst + 2 * 256;
  float* st3 = bnst + 3 * 256;

  // buf0 = leaky(x@W1+b1) (raw pre-BN1), fused stats -> st0
  k_gemm128<<<gemm_grid, 256, 0, stream>>>(x, W1, b1, nullptr, nullptr, nullptr,
                                           nullptr, 0.f, buf0, st0, NN);

  // ---- hconv1 (H=4): h1 = BN1(buf0) applied inline ----
  k_uv<4><<<2, 256, 0, stream>>>(linw1, att1, UVT);
  k_dots<4><<<(NN * 8 + 255) / 256, 256, 0, stream>>>((const float4*)buf0, NN, UVT,
                                                      st0, g1, be1, ninv, dotx, hv);
  k_dota<4><<<MM / 4, 256, 0, stream>>>(hv, eoff, npos_e, dota);
  k_softmax<4><<<NN / 4, 256, 0, stream>>>(noff, em_n, dotx, dota, wedge, alpha, Dinv);
  k_T<4><<<MM, 256, 0, stream>>>((const float4*)buf0, eoff, npos_e, alpha, st0, g1,
                                 be1, ninv, (float4*)Tbuf);
  {
    dim3 g((MM + 63) / 64, 4);
    k_oute64<4><<<g, 256, 0, stream>>>(Tbuf, linw1, eoff, wedge, oute);
  }
  k_phase9<4><<<NN / 4, 256, 0, stream>>>(noff, em_n, alpha, (const float4*)oute, Dinv,
                                          bias1, (const float4*)buf0, st0, g1, be1,
                                          ninv, (float4*)buf1);
  k_colstats<<<cs_grid, 256, 0, stream>>>((const float4*)buf1, NN, st1);

  // ---- hconv2 (H=1): h2 = BN2(buf1) applied inline ----
  k_uv<1><<<1, 256, 0, stream>>>(linw2, att2, UVT);
  k_dots<1><<<(NN * 2 + 255) / 256, 256, 0, stream>>>((const float4*)buf1, NN, UVT,
                                                      st1, g2, be2, ninv, dotx, hv);
  k_dota<1><<<MM / 4, 256, 0, stream>>>(hv, eoff, npos_e, dota);
  k_softmax<1><<<NN / 4, 256, 0, stream>>>(noff, em_n, dotx, dota, wedge, alpha, Dinv);
  k_T<1><<<MM, 256, 0, stream>>>((const float4*)buf1, eoff, npos_e, alpha, st1, g2,
                                 be2, ninv, (float4*)Tbuf);
  {
    dim3 g((MM + 63) / 64, 1);
    k_oute64<1><<<g, 256, 0, stream>>>(Tbuf, linw2, eoff, wedge, oute);
  }
  k_phase9<1><<<NN / 4, 256, 0, stream>>>(noff, em_n, alpha, (const float4*)oute, Dinv,
                                          bias2, (const float4*)buf1, st1, g2, be2,
                                          ninv, (float4*)buf0);
  k_colstats<<<cs_grid, 256, 0, stream>>>((const float4*)buf0, NN, st2);

  // buf1 = leaky(BN3(buf0)@W2+b2) + x  (raw pre-BN4), fused stats -> st3
  k_gemm128<<<gemm_grid, 256, 0, stream>>>(buf0, W2, b2, x, st2, g3, be3, ninv, buf1,
                                           st3, NN);
  k_bnapply_final<<<(NN * 32 + 255) / 256, 256, 0, stream>>>(
      (const float4*)buf1, st3, g4, be4, ninv, (float4*)out, NN * 32);
}

// Round 6
// 315.648 us; speedup vs baseline: 2.9623x; 1.1121x over previous
//
#include <hip/hip_runtime.h>

// Problem constants (match reference)
#define NN 20000
#define MM 2000
#define EE 320000
#define NSLICE 8
static constexpr float SLOPE = 0.2f;
static constexpr float EPSBN = 1e-5f;

__device__ inline float4 f4add(float4 a, float4 b) {
  return make_float4(a.x + b.x, a.y + b.y, a.z + b.z, a.w + b.w);
}
__device__ inline float4 f4fma(float a, float4 v, float4 c) {
  return make_float4(c.x + a * v.x, c.y + a * v.y, c.z + a * v.z, c.w + a * v.w);
}
__device__ inline float leaky(float v) { return (v > 0.f) ? v : SLOPE * v; }

// per-thread BN scale/shift for 4 channels (f4 index c4)
__device__ inline void bn_sc4(const float* __restrict__ st, const float* __restrict__ g,
                              const float* __restrict__ be, float ninv, int c4,
                              float4& sc, float4& sh) {
  float* scp = &sc.x;
  float* shp = &sh.x;
#pragma unroll
  for (int j = 0; j < 4; j++) {
    int c = c4 * 4 + j;
    float mu = st[c] * ninv;
    float var = st[128 + c] * ninv - mu * mu;
    float s = g[c] * rsqrtf(var + EPSBN);
    scp[j] = s;
    shp[j] = be[c] - mu * s;
  }
}

// ---------------------------------------------------------------------------
// CSR build, XCD-sliced counters: cnt[s][key], s = blockIdx & 7.
// Blocks of one slice land on one XCD (round-robin dispatch) -> counter lines
// stay in a single L2, no cross-XCD ping-pong.
// ---------------------------------------------------------------------------
__global__ void k_count(const int* __restrict__ ni, const int* __restrict__ ei,
                        int* cntN, int* cntE, int* __restrict__ rank_n,
                        int* __restrict__ rank_e) {
  int e = blockIdx.x * 256 + threadIdx.x;
  if (e >= EE) return;
  int s = blockIdx.x & (NSLICE - 1);
  rank_n[e] = atomicAdd(&cntN[s * NN + ni[e]], 1);
  rank_e[e] = atomicAdd(&cntE[s * MM + ei[e]], 1);
}

// per-key exclusive scan over the 8 slices; cnt[s][key] becomes slice base,
// tot[key] = total count.
__global__ void k_slicescan(int* __restrict__ cntN, int* __restrict__ totN,
                            int* __restrict__ cntE, int* __restrict__ totE) {
  int i = blockIdx.x * 256 + threadIdx.x;
  if (i < NN) {
    int run = 0;
#pragma unroll
    for (int s = 0; s < NSLICE; s++) {
      int t = cntN[s * NN + i];
      cntN[s * NN + i] = run;
      run += t;
    }
    totN[i] = run;
  } else if (i < NN + MM) {
    int m = i - NN;
    int run = 0;
#pragma unroll
    for (int s = 0; s < NSLICE; s++) {
      int t = cntE[s * MM + m];
      cntE[s * MM + m] = run;
      run += t;
    }
    totE[m] = run;
  }
}

// dual single-block exclusive scan (block 0: nodes, block 1: edges)
__global__ __launch_bounds__(1024) void k_scan2(const int* __restrict__ cntA,
                                                int* __restrict__ offA, int nA,
                                                const int* __restrict__ cntB,
                                                int* __restrict__ offB, int nB) {
  const int* cnt = blockIdx.x ? cntB : cntA;
  int* off = blockIdx.x ? offB : offA;
  int n = blockIdx.x ? nB : nA;
  __shared__ int swav[16];
  __shared__ int sCarry;
  int t = threadIdx.x;
  int lane = t & 63, wid = t >> 6;
  if (t == 0) sCarry = 0;
  __syncthreads();
  for (int base = 0; base < n; base += 1024) {
    int i = base + t;
    int v = (i < n) ? cnt[i] : 0;
    int x = v;
#pragma unroll
    for (int o = 1; o < 64; o <<= 1) {
      int y = __shfl_up(x, o);
      if (lane >= o) x += y;
    }
    if (lane == 63) swav[wid] = x;
    __syncthreads();
    if (wid == 0) {
      int s = (lane < 16) ? swav[lane] : 0;
#pragma unroll
      for (int o = 1; o < 16; o <<= 1) {
        int y = __shfl_up(s, o);
        if (lane >= o) s += y;
      }
      if (lane < 16) swav[lane] = s;
    }
    __syncthreads();
    int wpre = wid ? swav[wid - 1] : 0;
    int total = swav[15];
    if (i < n) off[i] = sCarry + wpre + x - v;
    __syncthreads();
    if (t == 0) sCarry += total;
    __syncthreads();
  }
  if (t == 0) off[n] = sCarry;
}

// atomic-free fill: position = off[key] + sliceBase[slice][key] + rank
__global__ void k_fill(const int* __restrict__ ni, const int* __restrict__ ei,
                       const int* __restrict__ noff, const int* __restrict__ eoff,
                       const int* __restrict__ cntN, const int* __restrict__ cntE,
                       const int* __restrict__ rank_n, const int* __restrict__ rank_e,
                       int* __restrict__ em_n, int2* __restrict__ npos_e) {
  int e = blockIdx.x * 256 + threadIdx.x;
  if (e >= EE) return;
  int s = blockIdx.x & (NSLICE - 1);
  int n = ni[e];
  int m = ei[e];
  int pn = noff[n] + cntN[s * NN + n] + rank_n[e];
  int pe = eoff[m] + cntE[s * MM + m] + rank_e[e];
  em_n[pn] = m;
  npos_e[pe] = make_int2(n, pn);
}

// ---------------------------------------------------------------------------
// Tiled GEMM: out = maybe_resid + leaky(BNopt(A)[rows,128] @ W[128,128] + b)
// Fused column stats (sum,sumsq) of the OUTPUT -> atomicAdd into stout.
// ---------------------------------------------------------------------------
__global__ __launch_bounds__(256) void k_gemm128(
    const float* __restrict__ A, const float* __restrict__ W,
    const float* __restrict__ bias, const float* __restrict__ resid,
    const float* __restrict__ st, const float* __restrict__ g,
    const float* __restrict__ be, float ninv, float* __restrict__ out,
    float* __restrict__ stout, int rows) {
  __shared__ float As[32][68];
  __shared__ float Ws[32][132];
  __shared__ float scs[128], shs[128];
  if (st && threadIdx.x < 128) {
    int c = threadIdx.x;
    float mu = st[c] * ninv;
    float var = st[128 + c] * ninv - mu * mu;
    float s = g[c] * rsqrtf(var + EPSBN);
    scs[c] = s;
    shs[c] = be[c] - mu * s;
  }
  if (st) __syncthreads();
  int tx = threadIdx.x & 15, ty = threadIdx.x >> 4;
  int r0 = blockIdx.x * 64;
  float4 acc[4][2];
#pragma unroll
  for (int j = 0; j < 4; j++) acc[j][0] = acc[j][1] = make_float4(0.f, 0.f, 0.f, 0.f);

  for (int k0 = 0; k0 < 128; k0 += 32) {
    __syncthreads();
    {
      int row = threadIdx.x >> 2, kq = threadIdx.x & 3;
      int rr = r0 + row;
      float4 a0 = make_float4(0.f, 0.f, 0.f, 0.f), a1 = a0;
      if (rr < rows) {
        const float* ap = A + (size_t)rr * 128 + k0 + kq * 8;
        a0 = ((const float4*)ap)[0];
        a1 = ((const float4*)ap)[1];
      }
      int kb = k0 + kq * 8;
      if (st) {
        a0.x = a0.x * scs[kb + 0] + shs[kb + 0];
        a0.y = a0.y * scs[kb + 1] + shs[kb + 1];
        a0.z = a0.z * scs[kb + 2] + shs[kb + 2];
        a0.w = a0.w * scs[kb + 3] + shs[kb + 3];
        a1.x = a1.x * scs[kb + 4] + shs[kb + 4];
        a1.y = a1.y * scs[kb + 5] + shs[kb + 5];
        a1.z = a1.z * scs[kb + 6] + shs[kb + 6];
        a1.w = a1.w * scs[kb + 7] + shs[kb + 7];
      }
      int kl = kq * 8;
      As[kl + 0][row] = a0.x;
      As[kl + 1][row] = a0.y;
      As[kl + 2][row] = a0.z;
      As[kl + 3][row] = a0.w;
      As[kl + 4][row] = a1.x;
      As[kl + 5][row] = a1.y;
      As[kl + 6][row] = a1.z;
      As[kl + 7][row] = a1.w;
    }
    {
      int kk = threadIdx.x >> 3, cq = threadIdx.x & 7;
      const float* wp = W + (size_t)(k0 + kk) * 128 + cq * 16;
#pragma unroll
      for (int f = 0; f < 4; f++)
        *(float4*)&Ws[kk][cq * 16 + f * 4] = ((const float4*)wp)[f];
    }
    __syncthreads();
#pragma unroll
    for (int kk = 0; kk < 32; kk++) {
      float4 a = *(const float4*)&As[kk][ty * 4];
      float4 w0 = *(const float4*)&Ws[kk][tx * 8];
      float4 w1 = *(const float4*)&Ws[kk][tx * 8 + 4];
      acc[0][0] = f4fma(a.x, w0, acc[0][0]);
      acc[0][1] = f4fma(a.x, w1, acc[0][1]);
      acc[1][0] = f4fma(a.y, w0, acc[1][0]);
      acc[1][1] = f4fma(a.y, w1, acc[1][1]);
      acc[2][0] = f4fma(a.z, w0, acc[2][0]);
      acc[2][1] = f4fma(a.z, w1, acc[2][1]);
      acc[3][0] = f4fma(a.w, w0, acc[3][0]);
      acc[3][1] = f4fma(a.w, w1, acc[3][1]);
    }
  }
  float4 b0 = ((const float4*)bias)[tx * 2];
  float4 b1 = ((const float4*)bias)[tx * 2 + 1];
  float4 cs0 = make_float4(0.f, 0.f, 0.f, 0.f), cs1 = cs0, cq0 = cs0, cq1 = cs0;
#pragma unroll
  for (int j = 0; j < 4; j++) {
    int r = r0 + ty * 4 + j;
    if (r < rows) {
      float4 o0 = acc[j][0], o1 = acc[j][1];
      o0 = make_float4(leaky(o0.x + b0.x), leaky(o0.y + b0.y), leaky(o0.z + b0.z),
                       leaky(o0.w + b0.w));
      o1 = make_float4(leaky(o1.x + b1.x), leaky(o1.y + b1.y), leaky(o1.z + b1.z),
                       leaky(o1.w + b1.w));
      if (resid) {
        float4 r0v = ((const float4*)resid)[(size_t)r * 32 + tx * 2];
        float4 r1v = ((const float4*)resid)[(size_t)r * 32 + tx * 2 + 1];
        o0 = f4add(o0, r0v);
        o1 = f4add(o1, r1v);
      }
      ((float4*)out)[(size_t)r * 32 + tx * 2] = o0;
      ((float4*)out)[(size_t)r * 32 + tx * 2 + 1] = o1;
      cs0 = f4add(cs0, o0);
      cs1 = f4add(cs1, o1);
      cq0 = make_float4(cq0.x + o0.x * o0.x, cq0.y + o0.y * o0.y, cq0.z + o0.z * o0.z,
                        cq0.w + o0.w * o0.w);
      cq1 = make_float4(cq1.x + o1.x * o1.x, cq1.y + o1.y * o1.y, cq1.z + o1.z * o1.z,
                        cq1.w + o1.w * o1.w);
    }
  }
  // fused column stats: reuse As (sum) / Ws (sumsq) LDS as [16][128]
  __syncthreads();
  float* sumb = &As[0][0];
  float* sqb = &Ws[0][0];
  *(float4*)&sumb[ty * 128 + tx * 8] = cs0;
  *(float4*)&sumb[ty * 128 + tx * 8 + 4] = cs1;
  *(float4*)&sqb[ty * 128 + tx * 8] = cq0;
  *(float4*)&sqb[ty * 128 + tx * 8 + 4] = cq1;
  __syncthreads();
  if (threadIdx.x < 128) {
    float S = 0.f, Q = 0.f;
#pragma unroll
    for (int w = 0; w < 16; w++) {
      S += sumb[w * 128 + threadIdx.x];
      Q += sqb[w * 128 + threadIdx.x];
    }
    atomicAdd(&stout[threadIdx.x], S);
    atomicAdd(&stout[128 + threadIdx.x], Q);
  }
}

// out_e[m][h][c] = (wedge[m]/deg) * (T[h][m][:] @ lin_w[:, h*128 + c])
template <int H>
__global__ __launch_bounds__(256) void k_oute64(const float* __restrict__ T,
                                                const float* __restrict__ linw,
                                                const int* __restrict__ eoff,
                                                const float* __restrict__ wedge,
                                                float* __restrict__ oute) {
  int h = blockIdx.y;
  __shared__ float As[32][68];
  __shared__ float Ws[32][132];
  int tx = threadIdx.x & 15, ty = threadIdx.x >> 4;
  int r0 = blockIdx.x * 64;
  const float* A = T + (size_t)h * MM * 128;
  float4 acc[4][2];
#pragma unroll
  for (int j = 0; j < 4; j++) acc[j][0] = acc[j][1] = make_float4(0.f, 0.f, 0.f, 0.f);

  for (int k0 = 0; k0 < 128; k0 += 32) {
    __syncthreads();
    {
      int row = threadIdx.x >> 2, kq = threadIdx.x & 3;
      int rr = r0 + row;
      float4 a0 = make_float4(0.f, 0.f, 0.f, 0.f), a1 = a0;
      if (rr < MM) {
        const float* ap = A + (size_t)rr * 128 + k0 + kq * 8;
        a0 = ((const float4*)ap)[0];
        a1 = ((const float4*)ap)[1];
      }
      int kb = kq * 8;
      As[kb + 0][row] = a0.x;
      As[kb + 1][row] = a0.y;
      As[kb + 2][row] = a0.z;
      As[kb + 3][row] = a0.w;
      As[kb + 4][row] = a1.x;
      As[kb + 5][row] = a1.y;
      As[kb + 6][row] = a1.z;
      As[kb + 7][row] = a1.w;
    }
    {
      int kk = threadIdx.x >> 3, cq = threadIdx.x & 7;
      const float* wp = linw + (size_t)(k0 + kk) * (128 * H) + h * 128 + cq * 16;
#pragma unroll
      for (int f = 0; f < 4; f++)
        *(float4*)&Ws[kk][cq * 16 + f * 4] = ((const float4*)wp)[f];
    }
    __syncthreads();
#pragma unroll
    for (int kk = 0; kk < 32; kk++) {
      float4 a = *(const float4*)&As[kk][ty * 4];
      float4 w0 = *(const float4*)&Ws[kk][tx * 8];
      float4 w1 = *(const float4*)&Ws[kk][tx * 8 + 4];
      acc[0][0] = f4fma(a.x, w0, acc[0][0]);
      acc[0][1] = f4fma(a.x, w1, acc[0][1]);
      acc[1][0] = f4fma(a.y, w0, acc[1][0]);
      acc[1][1] = f4fma(a.y, w1, acc[1][1]);
      acc[2][0] = f4fma(a.z, w0, acc[2][0]);
      acc[2][1] = f4fma(a.z, w1, acc[2][1]);
      acc[3][0] = f4fma(a.w, w0, acc[3][0]);
      acc[3][1] = f4fma(a.w, w1, acc[3][1]);
    }
  }
#pragma unroll
  for (int j = 0; j < 4; j++) {
    int m = r0 + ty * 4 + j;
    if (m >= MM) break;
    int d = eoff[m + 1] - eoff[m];
    float bv = (d > 0) ? wedge[m] / (float)d : 0.f;
    float4 o0 = acc[j][0], o1 = acc[j][1];
    o0 = make_float4(bv * o0.x, bv * o0.y, bv * o0.z, bv * o0.w);
    o1 = make_float4(bv * o1.x, bv * o1.y, bv * o1.z, bv * o1.w);
    ((float4*)oute)[((size_t)m * H + h) * 32 + tx * 2] = o0;
    ((float4*)oute)[((size_t)m * H + h) * 32 + tx * 2 + 1] = o1;
  }
}

// ---------------------------------------------------------------------------
// BatchNorm column stats (sum, sumsq) -- standalone (for phase9 outputs)
// ---------------------------------------------------------------------------
__global__ __launch_bounds__(256) void k_colstats(const float4* __restrict__ X4,
                                                  int rows, float* __restrict__ st) {
  int c4 = threadIdx.x & 31, rs = threadIdx.x >> 5, wid = threadIdx.x >> 6;
  int r0 = blockIdx.x * 256;
  int rend = min(r0 + 256, rows);
  float4 s = make_float4(0.f, 0.f, 0.f, 0.f), q = s;
  for (int r = r0 + rs; r < rend; r += 8) {
    float4 v = X4[(size_t)r * 32 + c4];
    s = f4add(s, v);
    q = make_float4(q.x + v.x * v.x, q.y + v.y * v.y, q.z + v.z * v.z, q.w + v.w * v.w);
  }
  s.x += __shfl_xor(s.x, 32); s.y += __shfl_xor(s.y, 32);
  s.z += __shfl_xor(s.z, 32); s.w += __shfl_xor(s.w, 32);
  q.x += __shfl_xor(q.x, 32); q.y += __shfl_xor(q.y, 32);
  q.z += __shfl_xor(q.z, 32); q.w += __shfl_xor(q.w, 32);
  __shared__ float4 red[4][32][2];
  if ((threadIdx.x & 63) < 32) {
    red[wid][c4][0] = s;
    red[wid][c4][1] = q;
  }
  __syncthreads();
  if (threadIdx.x < 32) {
    float4 S = f4add(f4add(red[0][threadIdx.x][0], red[1][threadIdx.x][0]),
                     f4add(red[2][threadIdx.x][0], red[3][threadIdx.x][0]));
    float4 Q = f4add(f4add(red[0][threadIdx.x][1], red[1][threadIdx.x][1]),
                     f4add(red[2][threadIdx.x][1], red[3][threadIdx.x][1]));
    int c = threadIdx.x * 4;
    atomicAdd(&st[c + 0], S.x);
    atomicAdd(&st[c + 1], S.y);
    atomicAdd(&st[c + 2], S.z);
    atomicAdd(&st[c + 3], S.w);
    atomicAdd(&st[128 + c + 0], Q.x);
    atomicAdd(&st[128 + c + 1], Q.y);
    atomicAdd(&st[128 + c + 2], Q.z);
    atomicAdd(&st[128 + c + 3], Q.w);
  }
}

// final: out = BN(X) computed from raw stats
__global__ void k_bnapply_final(const float4* __restrict__ X4,
                                const float* __restrict__ st,
                                const float* __restrict__ g,
                                const float* __restrict__ be, float ninv,
                                float4* __restrict__ Y4, int total4) {
  int i = blockIdx.x * 256 + threadIdx.x;
  if (i >= total4) return;
  int c4 = i & 31;
  float4 sc, sh;
  bn_sc4(st, g, be, ninv, c4, sc, sh);
  float4 v = X4[i];
  Y4[i] = make_float4(v.x * sc.x + sh.x, v.y * sc.y + sh.y, v.z * sc.z + sh.z,
                      v.w * sc.w + sh.w);
}

// ---------------------------------------------------------------------------
// Both layers' UVT in one dispatch: blocks 0,1 -> layer1 (H=4); block 2 ->
// layer2 (H=1). UVT[h][k] (U) then UVT[H+h][k] (V).
// ---------------------------------------------------------------------------
__global__ void k_uv_all(const float* __restrict__ linw1, const float* __restrict__ att1,
                         float* __restrict__ UVT1, const float* __restrict__ linw2,
                         const float* __restrict__ att2, float* __restrict__ UVT2) {
  if (blockIdx.x < 2) {
    constexpr int H = 4;
    int idx = blockIdx.x * 256 + threadIdx.x;
    int h = idx >> 7, k = idx & 127;
    float u = 0.f, v = 0.f;
    for (int c = 0; c < 128; c++) {
      float w = linw1[(size_t)k * (128 * H) + h * 128 + c];
      u += w * att1[h * 256 + c];
      v += w * att1[h * 256 + 128 + c];
    }
    UVT1[h * 128 + k] = u;
    UVT1[(H + h) * 128 + k] = v;
  } else {
    if (threadIdx.x >= 128) return;
    int k = threadIdx.x;
    float u = 0.f, v = 0.f;
    for (int c = 0; c < 128; c++) {
      float w = linw2[(size_t)k * 128 + c];
      u += w * att2[c];
      v += w * att2[128 + c];
    }
    UVT2[k] = u;
    UVT2[128 + k] = v;
  }
}

// dotx[n,h] = BN(X)[n,:] . U[:,h] ; hv[n,h] = BN(X)[n,:] . V[:,h]
template <int H>
__global__ void k_dots(const float4* __restrict__ X4, int rows,
                       const float* __restrict__ UVT, const float* __restrict__ st,
                       const float* __restrict__ g, const float* __restrict__ be,
                       float ninv, float* __restrict__ dotx, float* __restrict__ hv) {
  __shared__ float4 Ut[2 * H * 32];
  __shared__ float4 scl[32], shl[32];
  if (threadIdx.x < 32) {
    float4 sc, sh;
    bn_sc4(st, g, be, ninv, threadIdx.x, sc, sh);
    scl[threadIdx.x] = sc;
    shl[threadIdx.x] = sh;
  }
  for (int i = threadIdx.x; i < 2 * H * 32; i += 256) Ut[i] = ((const float4*)UVT)[i];
  __syncthreads();
  int idx = blockIdx.x * 256 + threadIdx.x;
  if (idx >= rows * 2 * H) return;
  int n = idx / (2 * H), h2 = idx - n * (2 * H);
  const float4* xr = X4 + (size_t)n * 32;
  const float4* ur = Ut + h2 * 32;
  float s = 0.f;
#pragma unroll 8
  for (int q = 0; q < 32; q++) {
    float4 a = xr[q], b = ur[q], c = scl[q], d = shl[q];
    float ax = a.x * c.x + d.x, ay = a.y * c.y + d.y;
    float az = a.z * c.z + d.z, aw = a.w * c.w + d.w;
    s += ax * b.x + ay * b.y + az * b.z + aw * b.w;
  }
  if (h2 < H)
    dotx[n * H + h2] = s;
  else
    hv[n * H + (h2 - H)] = s;
}

// dota[m,h] = sum over incidences of edge m of hv[node, h]
template <int H>
__global__ void k_dota(const float* __restrict__ hv, const int* __restrict__ eoff,
                       const int2* __restrict__ npos_e, float* __restrict__ dota) {
  int lane = threadIdx.x & 63;
  int m = blockIdx.x * 4 + (threadIdx.x >> 6);
  int s = eoff[m], t = eoff[m + 1];
  if (H == 4) {
    float4 acc = make_float4(0.f, 0.f, 0.f, 0.f);
    const float4* hv4 = (const float4*)hv;
    for (int j = s + lane; j < t; j += 64) acc = f4add(acc, hv4[npos_e[j].x]);
#pragma unroll
    for (int o = 32; o >= 1; o >>= 1) {
      acc.x += __shfl_xor(acc.x, o);
      acc.y += __shfl_xor(acc.y, o);
      acc.z += __shfl_xor(acc.z, o);
      acc.w += __shfl_xor(acc.w, o);
    }
    if (lane == 0) ((float4*)dota)[m] = acc;
  } else {
    float acc = 0.f;
    for (int j = s + lane; j < t; j += 64) acc += hv[npos_e[j].x];
#pragma unroll
    for (int o = 32; o >= 1; o >>= 1) acc += __shfl_xor(acc, o);
    if (lane == 0) dota[m] = acc;
  }
}

// ---------------------------------------------------------------------------
// Per-node segment softmax; alpha stored in node-CSR order.
// ---------------------------------------------------------------------------
template <int H>
__global__ void k_softmax(const int* __restrict__ noff, const int* __restrict__ em_n,
                          const float* __restrict__ dotx, const float* __restrict__ dota,
                          const float* __restrict__ wedge, float* __restrict__ alpha,
                          float* __restrict__ Dinv) {
  int lane = threadIdx.x & 63;
  int n = blockIdx.x * 4 + (threadIdx.x >> 6);
  int s = noff[n], t = noff[n + 1];
  int deg = t - s;
  int h = lane & (H - 1);
  float dx = dotx[n * H + h];
  if (deg <= 64) {
    int em0 = 0;
    float dd = 0.f;
    if (lane < deg) {
      em0 = em_n[s + lane];
      dd = wedge[em0];
    }
#pragma unroll
    for (int o = 32; o >= 1; o >>= 1) dd += __shfl_xor(dd, o);
    if (lane == 0) Dinv[n] = (dd > 0.f) ? 1.f / dd : 0.f;

    constexpr int KMAX = (H == 4) ? 4 : 1;
    int P = deg * H;
    float vc[KMAX];
    float mx = -3.0e38f;
#pragma unroll
    for (int k = 0; k < KMAX; k++) {
      int p = lane + 64 * k;
      int idx = (H == 4) ? (p >> 2) : p;
      int em = __shfl(em0, idx);
      float v = dx + dota[em * H + h];
      v = leaky(v);
      vc[k] = v;
      if (p < P) mx = fmaxf(mx, v);
    }
#pragma unroll
    for (int o = H; o < 64; o <<= 1) mx = fmaxf(mx, __shfl_xor(mx, o));
    float sm = 0.f;
#pragma unroll
    for (int k = 0; k < KMAX; k++) {
      int p = lane + 64 * k;
      float e = __expf(vc[k] - mx);
      vc[k] = e;
      if (p < P) sm += e;
    }
#pragma unroll
    for (int o = H; o < 64; o <<= 1) sm += __shfl_xor(sm, o);
    float inv = 1.f / (sm + 1e-16f);
#pragma unroll
    for (int k = 0; k < KMAX; k++) {
      int p = lane + 64 * k;
      if (p < P) alpha[s * H + p] = vc[k] * inv;
    }
  } else {
    float dd = 0.f;
    for (int i = s + lane; i < t; i += 64) dd += wedge[em_n[i]];
#pragma unroll
    for (int o = 32; o >= 1; o >>= 1) dd += __shfl_xor(dd, o);
    if (lane == 0) Dinv[n] = (dd > 0.f) ? 1.f / dd : 0.f;
    int P = deg * H;
    float mx = -3.0e38f;
    for (int p = lane; p < P; p += 64) {
      int i = s + ((H == 4) ? (p >> 2) : p);
      float v = leaky(dx + dota[em_n[i] * H + h]);
      mx = fmaxf(mx, v);
    }
#pragma unroll
    for (int o = H; o < 64; o <<= 1) mx = fmaxf(mx, __shfl_xor(mx, o));
    float sm = 0.f;
    for (int p = lane; p < P; p += 64) {
      int i = s + ((H == 4) ? (p >> 2) : p);
      float v = leaky(dx + dota[em_n[i] * H + h]);
      sm += __expf(v - mx);
    }
#pragma unroll
    for (int o = H; o < 64; o <<= 1) sm += __shfl_xor(sm, o);
    float inv = 1.f / (sm + 1e-16f);
    for (int p = lane; p < P; p += 64) {
      int i = s + ((H == 4) ? (p >> 2) : p);
      float v = leaky(dx + dota[em_n[i] * H + h]);
      alpha[s * H + p] = __expf(v - mx) * inv;
    }
  }
}

// ---------------------------------------------------------------------------
// T[h][m][c] = sc_c * (sum alpha * raw[node,c]) + sh_c * (sum alpha)
// BN factored out of the gather loop; packed LDS stage of {rowofs, alpha}.
// 8 slots x 32 lanes, block per edge m.
// ---------------------------------------------------------------------------
template <int H>
__global__ __launch_bounds__(256) void k_T(const float4* __restrict__ h4raw,
                                           const int* __restrict__ eoff,
                                           const int2* __restrict__ npos_e,
                                           const float* __restrict__ alpha,
                                           const float* __restrict__ st,
                                           const float* __restrict__ g,
                                           const float* __restrict__ be, float ninv,
                                           float4* __restrict__ T4) {
  int m = blockIdx.x;
  int slot = threadIdx.x >> 5, c = threadIdx.x & 31;
  int wv = threadIdx.x >> 6;
  int s = eoff[m], t = eoff[m + 1];
  __shared__ int sofs[256];
  __shared__ float sal[256 * H];
  __shared__ float4 red[4][H][32];
  __shared__ float4 redA[4];
  __shared__ float sAsum[4];
  float4 acc[H];
#pragma unroll
  for (int hh = 0; hh < H; hh++) acc[hh] = make_float4(0.f, 0.f, 0.f, 0.f);
  float4 asum = make_float4(0.f, 0.f, 0.f, 0.f);  // per-thread staged-alpha sum

  for (int c0 = s; c0 < t; c0 += 256) {
    int cnt = min(256, t - c0);
    __syncthreads();
    if (threadIdx.x < cnt) {
      int2 np = npos_e[c0 + threadIdx.x];
      sofs[threadIdx.x] = np.x * 32;
      if (H == 4) {
        float4 a4 = ((const float4*)alpha)[np.y];
        ((float4*)sal)[threadIdx.x] = a4;
        asum = f4add(asum, a4);
      } else {
        float a = alpha[np.y];
        sal[threadIdx.x] = a;
        asum.x += a;
      }
    }
    __syncthreads();
#pragma unroll 4
    for (int j = slot; j < cnt; j += 8) {
      int ofs = sofs[j];
      float4 v = h4raw[(size_t)ofs + c];
      if (H == 4) {
        float4 a4 = ((const float4*)sal)[j];
        acc[0] = f4fma(a4.x, v, acc[0]);
        acc[1 % H] = f4fma(a4.y, v, acc[1 % H]);
        acc[2 % H] = f4fma(a4.z, v, acc[2 % H]);
        acc[3 % H] = f4fma(a4.w, v, acc[3 % H]);
      } else {
        acc[0] = f4fma(sal[j], v, acc[0]);
      }
    }
  }
  // reduce acc over slots: pair via shfl, cross-wave via LDS
#pragma unroll
  for (int hh = 0; hh < H; hh++) {
    float4 a = acc[hh];
    a.x += __shfl_xor(a.x, 32); a.y += __shfl_xor(a.y, 32);
    a.z += __shfl_xor(a.z, 32); a.w += __shfl_xor(a.w, 32);
    acc[hh] = a;
  }
  // reduce asum over all 64 lanes of each wave
#pragma unroll
  for (int o = 32; o >= 1; o >>= 1) {
    asum.x += __shfl_xor(asum.x, o); asum.y += __shfl_xor(asum.y, o);
    asum.z += __shfl_xor(asum.z, o); asum.w += __shfl_xor(asum.w, o);
  }
  if ((threadIdx.x & 63) < 32) {
#pragma unroll
    for (int hh = 0; hh < H; hh++) red[wv][hh][c] = acc[hh];
  }
  if ((threadIdx.x & 63) == 0) redA[wv] = asum;
  __syncthreads();
  if (threadIdx.x == 0) {
    float4 A = f4add(f4add(redA[0], redA[1]), f4add(redA[2], redA[3]));
    sAsum[0] = A.x; sAsum[1] = A.y; sAsum[2] = A.z; sAsum[3] = A.w;
  }
  __syncthreads();
  if (threadIdx.x < 32 * H) {
    int hh = threadIdx.x >> 5, cc = threadIdx.x & 31;
    float4 r = f4add(f4add(red[0][hh][cc], red[1][hh][cc]),
                     f4add(red[2][hh][cc], red[3][hh][cc]));
    float as = sAsum[hh];
    float4 sc, sh;
    bn_sc4(st, g, be, ninv, cc, sc, sh);
    r = make_float4(sc.x * r.x + sh.x * as, sc.y * r.y + sh.y * as,
                    sc.z * r.z + sh.z * as, sc.w * r.w + sh.w * as);
    T4[((size_t)hh * MM + m) * 32 + cc] = r;
  }
}

// ---------------------------------------------------------------------------
// out[n,c] = BN(hres)[n,c] + Dinv[n]/H * sum alpha*oute[m,h,c] + bias
// One WAVE per node, no LDS/barriers. Metadata in regs, shfl-distributed.
// H=4: the 4 head-rows of oute[m] are contiguous (2KB) -> 1 addr, 4 loads.
// ---------------------------------------------------------------------------
template <int H>
__global__ __launch_bounds__(256) void k_phase9(
    const int* __restrict__ noff, const int* __restrict__ em_n,
    const float* __restrict__ alpha, const float4* __restrict__ oute4,
    const float* __restrict__ Dinv, const float* __restrict__ bias,
    const float4* __restrict__ hres4, const float* __restrict__ st,
    const float* __restrict__ g, const float* __restrict__ be, float ninv,
    float4* __restrict__ out4) {
  int wv = threadIdx.x >> 6, lane = threadIdx.x & 63;
  int n = blockIdx.x * 4 + wv;
  int slot = lane >> 5, c = lane & 31;
  int s = noff[n], t = noff[n + 1];
  int deg = t - s;
  float4 acc = make_float4(0.f, 0.f, 0.f, 0.f);
  if (deg <= 64) {
    int m_l = 0;
    float4 a_l = make_float4(0.f, 0.f, 0.f, 0.f);
    if (lane < deg) {
      m_l = em_n[s + lane];
      if (H == 4)
        a_l = ((const float4*)alpha)[s + lane];
      else
        a_l.x = alpha[s + lane];
    }
    for (int i = slot; i < deg; i += 2) {
      int m = __shfl(m_l, i);
      if (H == 4) {
        float ax = __shfl(a_l.x, i), ay = __shfl(a_l.y, i);
        float az = __shfl(a_l.z, i), aw = __shfl(a_l.w, i);
        const float4* base = oute4 + (size_t)m * 128 + c;
        acc = f4fma(ax, base[0], acc);
        acc = f4fma(ay, base[32], acc);
        acc = f4fma(az, base[64], acc);
        acc = f4fma(aw, base[96], acc);
      } else {
        float a = __shfl(a_l.x, i);
        acc = f4fma(a, oute4[(size_t)m * 32 + c], acc);
      }
    }
  } else {
    for (int i = s + slot; i < t; i += 2) {
      int m = em_n[i];
      if (H == 4) {
        float4 a4 = ((const float4*)alpha)[i];
        const float4* base = oute4 + (size_t)m * 128 + c;
        acc = f4fma(a4.x, base[0], acc);
        acc = f4fma(a4.y, base[32], acc);
        acc = f4fma(a4.z, base[64], acc);
        acc = f4fma(a4.w, base[96], acc);
      } else {
        acc = f4fma(alpha[i], oute4[(size_t)m * 32 + c], acc);
      }
    }
  }
  acc.x += __shfl_xor(acc.x, 32); acc.y += __shfl_xor(acc.y, 32);
  acc.z += __shfl_xor(acc.z, 32); acc.w += __shfl_xor(acc.w, 32);
  if (slot == 0) {
    float scn = Dinv[n] * (1.f / H);
    float4 scB, shB;
    bn_sc4(st, g, be, ninv, c, scB, shB);
    float4 hr = hres4[(size_t)n * 32 + c];
    hr = make_float4(hr.x * scB.x + shB.x, hr.y * scB.y + shB.y, hr.z * scB.z + shB.z,
                     hr.w * scB.w + shB.w);
    float4 bi = ((const float4*)bias)[c];
    out4[(size_t)n * 32 + c] =
        make_float4(hr.x + scn * acc.x + bi.x, hr.y + scn * acc.y + bi.y,
                    hr.z + scn * acc.z + bi.z, hr.w + scn * acc.w + bi.w);
  }
}

// ---------------------------------------------------------------------------
// Host side
// ---------------------------------------------------------------------------
static inline size_t alignup(size_t x) { return (x + 255) & ~(size_t)255; }

extern "C" void kernel_launch(void* const* d_in, const int* in_sizes, int n_in,
                              void* d_out, int out_size, void* d_ws, size_t ws_size,
                              hipStream_t stream) {
  const float* x = (const float*)d_in[0];
  const int* node_idx = (const int*)d_in[1];
  const int* edge_idx = (const int*)d_in[2];
  const float* wedge = (const float*)d_in[3];
  const float* W1 = (const float*)d_in[4];
  const float* b1 = (const float*)d_in[5];
  const float* g1 = (const float*)d_in[6];
  const float* be1 = (const float*)d_in[7];
  const float* linw1 = (const float*)d_in[8];
  const float* att1 = (const float*)d_in[9];
  const float* bias1 = (const float*)d_in[10];
  const float* g2 = (const float*)d_in[11];
  const float* be2 = (const float*)d_in[12];
  const float* linw2 = (const float*)d_in[13];
  const float* att2 = (const float*)d_in[14];
  const float* bias2 = (const float*)d_in[15];
  const float* g3 = (const float*)d_in[16];
  const float* be3 = (const float*)d_in[17];
  const float* W2 = (const float*)d_in[18];
  const float* b2 = (const float*)d_in[19];
  const float* g4 = (const float*)d_in[20];
  const float* be4 = (const float*)d_in[21];
  float* out = (float*)d_out;

  char* ws = (char*)d_ws;
  size_t off = 0;
  auto alloc = [&](size_t bytes) -> void* {
    void* p = ws + off;
    off = alignup(off + bytes);
    return p;
  };
  float* buf0 = (float*)alloc((size_t)NN * 128 * 4);
  float* buf1 = (float*)alloc((size_t)NN * 128 * 4);
  float* Tbuf = (float*)alloc((size_t)4 * MM * 128 * 4);
  float* oute = (float*)alloc((size_t)MM * 4 * 128 * 4);
  float* alpha = (float*)alloc((size_t)EE * 4 * 4);
  float* dotx = (float*)alloc((size_t)NN * 4 * 4);
  float* hv = (float*)alloc((size_t)NN * 4 * 4);
  float* dota = (float*)alloc((size_t)MM * 4 * 4);
  float* UVT1 = (float*)alloc(128 * 8 * 4);
  float* UVT2 = (float*)alloc(128 * 2 * 4);
  float* Dinv = (float*)alloc((size_t)NN * 4);
  int* noff = (int*)alloc((size_t)(NN + 1) * 4);
  int* eoff = (int*)alloc((size_t)(MM + 1) * 4);
  int* em_n = (int*)alloc((size_t)EE * 4);
  int2* npos_e = (int2*)alloc((size_t)EE * 8);
  int* rank_n = (int*)alloc((size_t)EE * 4);
  int* rank_e = (int*)alloc((size_t)EE * 4);
  int* totN = (int*)alloc((size_t)NN * 4);
  int* totE = (int*)alloc((size_t)MM * 4);
  // zero region: cntN (8*NN), cntE (8*MM), bnst(4x256)
  size_t zero_bytes = ((size_t)NSLICE * (NN + MM) + 4 * 256) * 4;
  int* zero_region = (int*)alloc(zero_bytes);
  int* cntN = zero_region;
  int* cntE = cntN + NSLICE * NN;
  float* bnst = (float*)(cntE + NSLICE * MM);
  (void)ws_size;
  (void)in_sizes;
  (void)n_in;
  (void)out_size;

  (void)hipMemsetAsync(zero_region, 0, zero_bytes, stream);

  // UVT for both layers (independent of CSR chain)
  k_uv_all<<<3, 256, 0, stream>>>(linw1, att1, UVT1, linw2, att2, UVT2);

  // CSR build with XCD-sliced counters
  k_count<<<(EE + 255) / 256, 256, 0, stream>>>(node_idx, edge_idx, cntN, cntE,
                                                rank_n, rank_e);
  k_slicescan<<<(NN + MM + 255) / 256, 256, 0, stream>>>(cntN, totN, cntE, totE);
  k_scan2<<<2, 1024, 0, stream>>>(totN, noff, NN, totE, eoff, MM);
  k_fill<<<(EE + 255) / 256, 256, 0, stream>>>(node_idx, edge_idx, noff, eoff, cntN,
                                               cntE, rank_n, rank_e, em_n, npos_e);

  const float ninv = 1.f / (float)NN;
  const int gemm_grid = (NN + 63) / 64;
  const int cs_grid = (NN + 255) / 256;
  float* st0 = bnst + 0 * 256;
  float* st1 = bnst + 1 * 256;
  float* st2 = bnst + 2 * 256;
  float* st3 = bnst + 3 * 256;

  // buf0 = leaky(x@W1+b1) (raw pre-BN1), fused stats -> st0
  k_gemm128<<<gemm_grid, 256, 0, stream>>>(x, W1, b1, nullptr, nullptr, nullptr,
                                           nullptr, 0.f, buf0, st0, NN);

  // ---- hconv1 (H=4): h1 = BN1(buf0) applied inline ----
  k_dots<4><<<(NN * 8 + 255) / 256, 256, 0, stream>>>((const float4*)buf0, NN, UVT1,
                                                      st0, g1, be1, ninv, dotx, hv);
  k_dota<4><<<MM / 4, 256, 0, stream>>>(hv, eoff, npos_e, dota);
  k_softmax<4><<<NN / 4, 256, 0, stream>>>(noff, em_n, dotx, dota, wedge, alpha, Dinv);
  k_T<4><<<MM, 256, 0, stream>>>((const float4*)buf0, eoff, npos_e, alpha, st0, g1,
                                 be1, ninv, (float4*)Tbuf);
  {
    dim3 g((MM + 63) / 64, 4);
    k_oute64<4><<<g, 256, 0, stream>>>(Tbuf, linw1, eoff, wedge, oute);
  }
  k_phase9<4><<<NN / 4, 256, 0, stream>>>(noff, em_n, alpha, (const float4*)oute, Dinv,
                                          bias1, (const float4*)buf0, st0, g1, be1,
                                          ninv, (float4*)buf1);
  k_colstats<<<cs_grid, 256, 0, stream>>>((const float4*)buf1, NN, st1);

  // ---- hconv2 (H=1): h2 = BN2(buf1) applied inline ----
  k_dots<1><<<(NN * 2 + 255) / 256, 256, 0, stream>>>((const float4*)buf1, NN, UVT2,
                                                      st1, g2, be2, ninv, dotx, hv);
  k_dota<1><<<MM / 4, 256, 0, stream>>>(hv, eoff, npos_e, dota);
  k_softmax<1><<<NN / 4, 256, 0, stream>>>(noff, em_n, dotx, dota, wedge, alpha, Dinv);
  k_T<1><<<MM, 256, 0, stream>>>((const float4*)buf1, eoff, npos_e, alpha, st1, g2,
                                 be2, ninv, (float4*)Tbuf);
  {
    dim3 g((MM + 63) / 64, 1);
    k_oute64<1><<<g, 256, 0, stream>>>(Tbuf, linw2, eoff, wedge, oute);
  }
  k_phase9<1><<<NN / 4, 256, 0, stream>>>(noff, em_n, alpha, (const float4*)oute, Dinv,
                                          bias2, (const float4*)buf1, st1, g2, be2,
                                          ninv, (float4*)buf0);
  k_colstats<<<cs_grid, 256, 0, stream>>>((const float4*)buf0, NN, st2);

  // buf1 = leaky(BN3(buf0)@W2+b2) + x  (raw pre-BN4), fused stats -> st3
  k_gemm128<<<gemm_grid, 256, 0, stream>>>(buf0, W2, b2, x, st2, g3, be3, ninv, buf1,
                                           st3, NN);
  k_bnapply_final<<<(NN * 32 + 255) / 256, 256, 0, stream>>>(
      (const float4*)buf1, st3, g4, be4, ninv, (float4*)out, NN * 32);
}